// Round 2
// baseline (12651.451 us; speedup 1.0000x reference)
//
#include <hip/hip_runtime.h>
#include <hip/hip_bf16.h>

#define B_ 8
#define C_ 256
#define H_ 128
#define W_ 128
#define N_ 16384
#define KC_ 256
#define VC_ 256
#define HID_ 1024
#define SPLITK 8

// ---------------- LN stats per pixel: mean/rstd over channel dim (layout b,c,n)
__global__ __launch_bounds__(256) void ln_stats(const float* __restrict__ in,
    float* __restrict__ meanout, float* __restrict__ rstdout) {
  int idx = blockIdx.x * 256 + threadIdx.x;   // b*N + n
  int b = idx >> 14;
  int n = idx & 16383;
  const float* p = in + (size_t)b * C_ * N_ + n;
  float s1 = 0.f, s2 = 0.f;
  for (int c = 0; c < C_; ++c) { float v = p[(size_t)c * N_]; s1 += v; s2 += v * v; }
  float m = s1 * (1.f / C_);
  float var = s2 * (1.f / C_) - m * m;
  meanout[idx] = m;
  rstdout[idx] = rsqrtf(var + 1e-5f);
}

// ---------------- Generic GEMM / shifted-tap conv with optional fused LN on X:
// out[b,m,n] (+)= bias[m] + res[b,m,n] + sum_t sum_c A[b?,m,c,t] * LN(X)[b,c,n+(t-1)*shift]
// BM=BN=128, BK=16, 256 threads, 8x8 per thread. N fixed = N_ (n-tile == one image row).
template<int TAPS, bool BIAS, bool ACCUM, bool RES, bool LNX>
__global__ __launch_bounds__(256) void gemm_conv(
    const float* __restrict__ A, const float* __restrict__ X,
    const float* __restrict__ bias, const float* __restrict__ res,
    const float* __restrict__ lnmean, const float* __restrict__ lnrstd,
    const float* __restrict__ lng, const float* __restrict__ lnbeta,
    float* __restrict__ out,
    int M, int Cin, int shift, int dimsel,
    long Abatch, long Xbatch, long Outbatch, long Resbatch)
{
  __shared__ float As[16][128];
  __shared__ float Xs[16][128];
  int tid = threadIdx.x;
  int bx = blockIdx.x;          // n tile: n0 = bx*128 == image row h=bx
  int by = blockIdx.y;          // m tile
  int bz = blockIdx.z;          // batch
  int n0 = bx * 128;
  int m0 = by * 128;
  const float* Ab = A + (size_t)bz * Abatch;
  const float* Xb = X + (size_t)bz * Xbatch;
  const float* lm = LNX ? (lnmean + (size_t)bz * N_) : nullptr;
  const float* lr = LNX ? (lnrstd + (size_t)bz * N_) : nullptr;
  float acc[8][8];
  #pragma unroll
  for (int i = 0; i < 8; i++)
    #pragma unroll
    for (int j = 0; j < 8; j++) acc[i][j] = 0.f;
  int ty = tid >> 4, tx = tid & 15;
  int am = tid >> 1;            // 0..127 (m row to load)
  int ak = (tid & 1) * 8;       // 0 or 8 (k start)

  for (int t = 0; t < TAPS; ++t) {
    int off = (TAPS == 3) ? (t - 1) * shift : 0;
    bool tile_valid = true;
    if (TAPS == 3 && dimsel == 2) {
      int h2 = bx + (t - 1);
      tile_valid = (0 <= h2 && h2 < H_);
    }
    for (int cb = 0; cb < Cin; cb += 16) {
      // A chunk -> As[k][m]
      {
        const float* ap = Ab + (size_t)(m0 + am) * Cin * TAPS + (size_t)(cb + ak) * TAPS + t;
        #pragma unroll
        for (int j = 0; j < 8; j++) As[ak + j][am] = ap[j * TAPS];
      }
      // X chunk -> Xs[k][n] with optional fused LayerNorm
      {
        #pragma unroll
        for (int l = 0; l < 8; l++) {
          int e = tid + l * 256;
          int k = e >> 7;
          int n = e & 127;
          float v = 0.f;
          bool valid = true;
          int p = n0 + n;
          if (TAPS == 3) {
            p += off;
            valid = tile_valid;
            if (dimsel == 1) { int w2 = n + (t - 1); valid = valid && (0 <= w2 && w2 < W_); }
          }
          if (valid) {
            v = Xb[(size_t)(cb + k) * N_ + p];
            if (LNX) v = (v - lm[p]) * lr[p] * lng[cb + k] + lnbeta[cb + k];
          }
          Xs[k][n] = v;
        }
      }
      __syncthreads();
      #pragma unroll
      for (int kk = 0; kk < 16; kk++) {
        float a[8], bb[8];
        float4 a0 = *(const float4*)&As[kk][ty * 8];
        float4 a1 = *(const float4*)&As[kk][ty * 8 + 4];
        float4 b0 = *(const float4*)&Xs[kk][tx * 4];
        float4 b1 = *(const float4*)&Xs[kk][64 + tx * 4];
        a[0]=a0.x; a[1]=a0.y; a[2]=a0.z; a[3]=a0.w;
        a[4]=a1.x; a[5]=a1.y; a[6]=a1.z; a[7]=a1.w;
        bb[0]=b0.x; bb[1]=b0.y; bb[2]=b0.z; bb[3]=b0.w;
        bb[4]=b1.x; bb[5]=b1.y; bb[6]=b1.z; bb[7]=b1.w;
        #pragma unroll
        for (int i = 0; i < 8; i++)
          #pragma unroll
          for (int j = 0; j < 8; j++)
            acc[i][j] += a[i] * bb[j];
      }
      __syncthreads();
    }
  }
  // epilogue: rows m0+ty*8+i ; cols n0+tx*4+j and n0+64+tx*4+j
  #pragma unroll
  for (int i = 0; i < 8; i++) {
    int m = m0 + ty * 8 + i;
    float bval = BIAS ? bias[m] : 0.f;
    float* op = out + (size_t)bz * Outbatch + (size_t)m * N_ + n0;
    const float* rp = RES ? (res + (size_t)bz * Resbatch + (size_t)m * N_ + n0) : (const float*)nullptr;
    #pragma unroll
    for (int j = 0; j < 4; j++) {
      float v = acc[i][j] + bval;
      if (RES) v += rp[tx * 4 + j];
      if (ACCUM) v += op[tx * 4 + j];
      op[tx * 4 + j] = v;
    }
    #pragma unroll
    for (int j = 0; j < 4; j++) {
      float v = acc[i][4 + j] + bval;
      if (RES) v += rp[64 + tx * 4 + j];
      if (ACCUM) v += op[64 + tx * 4 + j];
      op[64 + tx * 4 + j] = v;
    }
  }
}

// ---------------- softmax over spatial axis (one block per (b,kc) row), in place
__global__ __launch_bounds__(256) void softmax_spatial(float* __restrict__ p) {
  size_t base = (size_t)blockIdx.x * N_;
  int tid = threadIdx.x;
  __shared__ float red[256];
  float mx = -1e30f;
  for (int i = tid; i < N_; i += 256) mx = fmaxf(mx, p[base + i]);
  red[tid] = mx; __syncthreads();
  for (int s = 128; s > 0; s >>= 1) { if (tid < s) red[tid] = fmaxf(red[tid], red[tid + s]); __syncthreads(); }
  mx = red[0]; __syncthreads();
  float sum = 0.f;
  for (int i = tid; i < N_; i += 256) sum += expf(p[base + i] - mx);
  red[tid] = sum; __syncthreads();
  for (int s = 128; s > 0; s >>= 1) { if (tid < s) red[tid] += red[tid + s]; __syncthreads(); }
  float inv = 1.f / red[0];
  for (int i = tid; i < N_; i += 256) p[base + i] = expf(p[base + i] - mx) * inv;
}

// ---------------- softmax over channel axis (per (b,n) pixel), in place
__global__ __launch_bounds__(256) void softmax_channel(float* __restrict__ p) {
  int idx = blockIdx.x * 256 + threadIdx.x;
  int b = idx >> 14;
  int n = idx & 16383;
  float* q = p + (size_t)b * KC_ * N_ + n;
  float mx = -1e30f;
  for (int c = 0; c < KC_; c++) mx = fmaxf(mx, q[(size_t)c * N_]);
  float s = 0.f;
  for (int c = 0; c < KC_; c++) s += expf(q[(size_t)c * N_] - mx);
  float inv = 1.f / s;
  for (int c = 0; c < KC_; c++) q[(size_t)c * N_] = expf(q[(size_t)c * N_] - mx) * inv;
}

// ---------------- amap accumulation: amap[b,n] (+)= (1/(2*KC)) * sum_kc key_s[b,kc,n]
template<bool STORE>
__global__ __launch_bounds__(256) void amap_kernel(const float* __restrict__ ks, float* __restrict__ amap) {
  int idx = blockIdx.x * 256 + threadIdx.x;
  int b = idx >> 14;
  int n = idx & 16383;
  const float* p = ks + (size_t)b * KC_ * N_ + n;
  float s = 0.f;
  for (int c = 0; c < KC_; c++) s += p[(size_t)c * N_];
  s *= (1.f / (2.f * KC_));
  if (STORE) amap[idx] = s; else amap[idx] += s;
}

// ---------------- ctx[b,kc,vc] = sum_n key_s[b,kc,n]*val[b,vc,n], split-K over n
__global__ __launch_bounds__(256) void ctx_kernel(const float* __restrict__ ks,
    const float* __restrict__ val, float* __restrict__ part) {
  __shared__ float Ks[128][36];
  __shared__ float Vs[128][36];
  int tid = threadIdx.x;
  int bx = blockIdx.x;   // vc tile (0..1)
  int by = blockIdx.y;   // kc tile (0..1)
  int bz = blockIdx.z;   // b*SPLITK + s
  int b = bz / SPLITK, s = bz % SPLITK;
  const float* kb = ks + (size_t)b * KC_ * N_ + (size_t)by * 128 * N_ + (size_t)s * (N_ / SPLITK);
  const float* vb = val + (size_t)b * VC_ * N_ + (size_t)bx * 128 * N_ + (size_t)s * (N_ / SPLITK);
  float acc[8][8];
  #pragma unroll
  for (int i = 0; i < 8; i++)
    #pragma unroll
    for (int j = 0; j < 8; j++) acc[i][j] = 0.f;
  int ty = tid >> 4, tx = tid & 15;
  for (int nb = 0; nb < N_ / SPLITK; nb += 32) {
    #pragma unroll
    for (int l = 0; l < 4; l++) {
      int e = (tid + l * 256) * 4;
      int r = e >> 5;
      int cc = e & 31;
      float4 kv = *(const float4*)&kb[(size_t)r * N_ + nb + cc];
      float4 vv = *(const float4*)&vb[(size_t)r * N_ + nb + cc];
      *(float4*)&Ks[r][cc] = kv;
      *(float4*)&Vs[r][cc] = vv;
    }
    __syncthreads();
    #pragma unroll
    for (int nn = 0; nn < 32; nn += 4) {
      float4 a4[8], b4[8];
      #pragma unroll
      for (int i = 0; i < 8; i++) a4[i] = *(const float4*)&Ks[ty + 16 * i][nn];
      #pragma unroll
      for (int j = 0; j < 8; j++) b4[j] = *(const float4*)&Vs[tx + 16 * j][nn];
      #pragma unroll
      for (int i = 0; i < 8; i++)
        #pragma unroll
        for (int j = 0; j < 8; j++)
          acc[i][j] += a4[i].x * b4[j].x + a4[i].y * b4[j].y + a4[i].z * b4[j].z + a4[i].w * b4[j].w;
    }
    __syncthreads();
  }
  #pragma unroll
  for (int i = 0; i < 8; i++)
    #pragma unroll
    for (int j = 0; j < 8; j++)
      part[(size_t)bz * KC_ * VC_ + (size_t)(by * 128 + ty + 16 * i) * VC_ + bx * 128 + tx + 16 * j] = acc[i][j];
}

__global__ __launch_bounds__(256) void ctx_reduce(const float* __restrict__ part, float* __restrict__ out) {
  int idx = blockIdx.x * 256 + threadIdx.x;   // b*KC*VC
  int b = idx >> 16;
  int r = idx & 65535;
  float s = 0.f;
  for (int k = 0; k < SPLITK; k++) s += part[((size_t)(b * SPLITK + k)) * KC_ * VC_ + r];
  out[idx] = s;
}

// ---------------- M[b,c,kc] = sum_v wr[c, dsel*VC+v] * ctx[b,kc,v]
__global__ __launch_bounds__(256) void mk_kernel(const float* __restrict__ wr,
    const float* __restrict__ ctx, int dsel, float* __restrict__ Mout) {
  int b = blockIdx.x >> 8;
  int c = blockIdx.x & 255;
  int kc = threadIdx.x;
  __shared__ float wrow[VC_];
  wrow[threadIdx.x] = wr[(size_t)c * (2 * VC_) + dsel * VC_ + threadIdx.x];
  __syncthreads();
  const float* cp = ctx + (size_t)b * KC_ * VC_ + (size_t)kc * VC_;
  float s = 0.f;
  for (int v = 0; v < VC_; v++) s += wrow[v] * cp[v];
  Mout[(size_t)b * C_ * KC_ + (size_t)c * KC_ + kc] = s;
}

// ---------------- depthwise 3x3 conv + exact GELU (per batch chunk)
__global__ __launch_bounds__(256) void dwgelu_kernel(const float* __restrict__ h1,
    const float* __restrict__ wdw, const float* __restrict__ bdw, float* __restrict__ out) {
  int c = blockIdx.y;
  int n = blockIdx.x * 256 + threadIdx.x;
  int h = n >> 7, w = n & 127;
  const float* p = h1 + (size_t)c * N_;
  const float* wp = wdw + c * 9;
  float s = bdw[c];
  #pragma unroll
  for (int di = -1; di <= 1; ++di) {
    int h2 = h + di;
    if ((unsigned)h2 >= H_) continue;
    #pragma unroll
    for (int dj = -1; dj <= 1; ++dj) {
      int w2 = w + dj;
      if ((unsigned)w2 >= W_) continue;
      s += wp[(di + 1) * 3 + (dj + 1)] * p[h2 * W_ + w2];
    }
  }
  float gl = 0.5f * s * (1.f + erff(s * 0.70710678118654752f));
  out[(size_t)c * N_ + n] = gl;
}

extern "C" void kernel_launch(void* const* d_in, const int* in_sizes, int n_in,
                              void* d_out, int out_size, void* d_ws, size_t ws_size,
                              hipStream_t stream) {
  const float* x    = (const float*)d_in[0];
  const float* wk1  = (const float*)d_in[3];
  const float* bk1  = (const float*)d_in[4];
  const float* wk2  = (const float*)d_in[5];
  const float* bk2  = (const float*)d_in[6];
  const float* wq1  = (const float*)d_in[7];
  const float* bq1  = (const float*)d_in[8];
  const float* wq2  = (const float*)d_in[9];
  const float* bq2  = (const float*)d_in[10];
  const float* wv   = (const float*)d_in[11];
  const float* bv   = (const float*)d_in[12];
  const float* wr   = (const float*)d_in[13];
  const float* br   = (const float*)d_in[14];
  const float* g1   = (const float*)d_in[15];
  const float* b1   = (const float*)d_in[16];
  const float* g2   = (const float*)d_in[17];
  const float* b2   = (const float*)d_in[18];
  const float* wfc1 = (const float*)d_in[19];
  const float* bfc1 = (const float*)d_in[20];
  const float* wdw  = (const float*)d_in[21];
  const float* bdw  = (const float*)d_in[22];
  const float* wfc2 = (const float*)d_in[23];
  const float* bfc2 = (const float*)d_in[24];

  const size_t big = (size_t)B_ * C_ * N_;        // 33,554,432 floats
  float* ws    = (float*)d_ws;
  float* kq    = ws;                                            // k or q buffer (B,KC,N)
  float* part  = kq + big;                                      // SPLITK*B*KC*VC
  float* ctx0  = part + (size_t)SPLITK * B_ * KC_ * VC_;
  float* Mbuf  = ctx0 + (size_t)B_ * KC_ * VC_;
  float* mean1 = Mbuf + (size_t)B_ * C_ * KC_;
  float* rstd1 = mean1 + (size_t)B_ * N_;
  float* mean2 = rstd1 + (size_t)B_ * N_;
  float* rstd2 = mean2 + (size_t)B_ * N_;
  float* wsend = rstd2 + (size_t)B_ * N_;
  if (ws_size < (size_t)(wsend - ws) * sizeof(float)) return;   // ~158 MB needed

  float* mx_out   = (float*)d_out;
  float* ctx_out  = mx_out + big;
  float* amap_out = ctx_out + (size_t)B_ * KC_ * VC_;

  // val lives in d_out's mx region during phase 1 (mx region is first written in phase 2)
  float* val = mx_out;
  // FFN overlays: h1 + act exactly fill the kq buffer (2 * HID*N == C*N*B/... == 33.5M floats)
  float* h1c = kq;
  float* ac  = kq + (size_t)HID_ * N_;

  dim3 blk(256);
  long CN = (long)C_ * N_;

  // LN1 stats
  ln_stats<<<B_ * N_ / 256, blk, 0, stream>>>(x, mean1, rstd1);

  // val = wv @ LN1(x) + bv   -> d_out mx region
  gemm_conv<1, true, false, false, true><<<dim3(128, VC_ / 128, B_), blk, 0, stream>>>(
      wv, x, bv, nullptr, mean1, rstd1, g1, b1, val, VC_, C_, 0, 0, 0L, CN, CN, 0L);

  // Phase 1: K path + ctx for both directions (val alive)
  for (int d = 0; d < 2; ++d) {
    const float* wk = d ? wk2 : wk1; const float* bk = d ? bk2 : bk1;
    int shift = d ? W_ : 1;
    int dimsel = d ? 2 : 1;
    gemm_conv<3, true, false, false, true><<<dim3(128, KC_ / 128, B_), blk, 0, stream>>>(
        wk, x, bk, nullptr, mean1, rstd1, g1, b1, kq, KC_, C_, shift, dimsel, 0L, CN, CN, 0L);
    softmax_spatial<<<B_ * KC_, blk, 0, stream>>>(kq);
    if (d == 0) amap_kernel<true><<<B_ * N_ / 256, blk, 0, stream>>>(kq, amap_out);
    else        amap_kernel<false><<<B_ * N_ / 256, blk, 0, stream>>>(kq, amap_out);
    ctx_kernel<<<dim3(2, 2, B_ * SPLITK), blk, 0, stream>>>(kq, val, part);
    ctx_reduce<<<B_ * KC_ * VC_ / 256, blk, 0, stream>>>(part, d ? ctx_out : ctx0);
  }

  // Phase 2: Q path + attention output for both directions (val dead; mx region reused)
  for (int d = 0; d < 2; ++d) {
    const float* wq = d ? wq2 : wq1; const float* bq = d ? bq2 : bq1;
    int shift = d ? W_ : 1;
    int dimsel = d ? 2 : 1;
    gemm_conv<3, true, false, false, true><<<dim3(128, KC_ / 128, B_), blk, 0, stream>>>(
        wq, x, bq, nullptr, mean1, rstd1, g1, b1, kq, KC_, C_, shift, dimsel, 0L, CN, CN, 0L);
    softmax_channel<<<B_ * N_ / 256, blk, 0, stream>>>(kq);
    mk_kernel<<<B_ * C_, blk, 0, stream>>>(wr, d ? ctx_out : ctx0, d, Mbuf);
    if (d == 0)   // mx = attn0 + br
      gemm_conv<1, true, false, false, false><<<dim3(128, C_ / 128, B_), blk, 0, stream>>>(
          Mbuf, kq, br, nullptr, nullptr, nullptr, nullptr, nullptr, mx_out,
          C_, KC_, 0, 0, (long)C_ * KC_, (long)KC_ * N_, CN, 0L);
    else          // mx += attn1 + x  (tx complete)
      gemm_conv<1, false, true, true, false><<<dim3(128, C_ / 128, B_), blk, 0, stream>>>(
          Mbuf, kq, nullptr, x, nullptr, nullptr, nullptr, nullptr, mx_out,
          C_, KC_, 0, 0, (long)C_ * KC_, (long)KC_ * N_, CN, CN);
  }

  // LN2 stats on tx (in mx_out)
  ln_stats<<<B_ * N_ / 256, blk, 0, stream>>>(mx_out, mean2, rstd2);

  // FFN per batch: fc1(LN2 fused) -> dw+gelu -> fc2 (+bias, += tx in place) -> mx
  for (int b = 0; b < B_; ++b) {
    const float* txb = mx_out + (size_t)b * C_ * N_;
    gemm_conv<1, true, false, false, true><<<dim3(128, HID_ / 128, 1), blk, 0, stream>>>(
        wfc1, txb, bfc1, nullptr, mean2 + (size_t)b * N_, rstd2 + (size_t)b * N_, g2, b2,
        h1c, HID_, C_, 0, 0, 0L, 0L, 0L, 0L);
    dwgelu_kernel<<<dim3(64, HID_), blk, 0, stream>>>(h1c, wdw, bdw, ac);
    gemm_conv<1, true, true, false, false><<<dim3(128, C_ / 128, 1), blk, 0, stream>>>(
        wfc2, ac, bfc2, nullptr, nullptr, nullptr, nullptr, nullptr,
        mx_out + (size_t)b * C_ * N_, C_, HID_, 0, 0, 0L, 0L, 0L, 0L);
  }
}

// Round 4
// 2385.274 us; speedup vs baseline: 5.3040x; 5.3040x over previous
//
#include <hip/hip_runtime.h>
#include <hip/hip_bf16.h>

#define B_ 8
#define C_ 256
#define H_ 128
#define W_ 128
#define N_ 16384
#define KC_ 256
#define VC_ 256
#define HID_ 1024
#define CTX_SPLIT 4

typedef unsigned short ushort_t;
typedef __bf16 bf16x8 __attribute__((ext_vector_type(8)));
typedef float f32x4 __attribute__((ext_vector_type(4)));
typedef ushort_t u16x8 __attribute__((ext_vector_type(8)));

static __device__ __forceinline__ ushort_t f2bu(float f) {
  __hip_bfloat16 h = __float2bfloat16(f);
  return *reinterpret_cast<ushort_t*>(&h);
}
static __device__ __forceinline__ float bu2f(ushort_t u) {
  __hip_bfloat16 h;
  *reinterpret_cast<ushort_t*>(&h) = u;
  return __bfloat162float(h);
}

#define GLD16(gp, lp) __builtin_amdgcn_global_load_lds( \
    (const __attribute__((address_space(1))) void*)(gp), \
    (__attribute__((address_space(3))) void*)(lp), 16, 0, 0)

// ---------------- tiny utility kernels ----------------
__global__ __launch_bounds__(64) void zero_kernel(ushort_t* p) {
  p[threadIdx.x] = 0;
}

// [M][C][3] fp32 -> [3][M][C] bf16
__global__ __launch_bounds__(256) void pack3_kernel(const float* __restrict__ in,
                                                    ushort_t* __restrict__ out, int MC) {
  int idx = blockIdx.x * 256 + threadIdx.x;
  if (idx >= MC) return;
  #pragma unroll
  for (int t = 0; t < 3; ++t) out[t * MC + idx] = f2bu(in[idx * 3 + t]);
}

// flat fp32 -> bf16
__global__ __launch_bounds__(256) void pack1_kernel(const float* __restrict__ in,
                                                    ushort_t* __restrict__ out, int n) {
  int idx = blockIdx.x * 256 + threadIdx.x;
  if (idx < n) out[idx] = f2bu(in[idx]);
}

// ---------------- LN stats per pixel over channel dim (layout b,c,n)
__global__ __launch_bounds__(256) void ln_stats(const float* __restrict__ in,
    float* __restrict__ meanout, float* __restrict__ rstdout) {
  int idx = blockIdx.x * 256 + threadIdx.x;   // b*N + n
  int b = idx >> 14;
  int n = idx & 16383;
  const float* p = in + (size_t)b * C_ * N_ + n;
  float s1 = 0.f, s2 = 0.f;
  for (int c = 0; c < C_; ++c) { float v = p[(size_t)c * N_]; s1 += v; s2 += v * v; }
  float m = s1 * (1.f / C_);
  float var = s2 * (1.f / C_) - m * m;
  meanout[idx] = m;
  rstdout[idx] = rsqrtf(var + 1e-5f);
}

// ---------------- LN + transpose + bf16: in fp32 [c][n] -> out bf16 [n][c]
__global__ __launch_bounds__(256) void lnt_kernel(
    const float* __restrict__ in, long inBatch,
    const float* __restrict__ mean, const float* __restrict__ rstd, long statBatch,
    const float* __restrict__ g, const float* __restrict__ beta,
    ushort_t* __restrict__ out, long outBatch) {
  __shared__ ushort_t T[64][72];
  int z = blockIdx.z;
  int n0 = blockIdx.x * 64, c0 = blockIdx.y * 64;
  const float* inb = in + (size_t)z * inBatch;
  const float* mb = mean + (size_t)z * statBatch;
  const float* rb = rstd + (size_t)z * statBatch;
  ushort_t* ob = out + (size_t)z * outBatch;
  int t = threadIdx.x;
  {
    int cr = t >> 2, nc = (t & 3) * 16;
    const float* p = inb + (size_t)(c0 + cr) * N_ + n0 + nc;
    float gg = g[c0 + cr], bb = beta[c0 + cr];
    #pragma unroll
    for (int j = 0; j < 16; j += 4) {
      float4 v = *(const float4*)&p[j];
      float4 m4 = *(const float4*)&mb[n0 + nc + j];
      float4 r4 = *(const float4*)&rb[n0 + nc + j];
      T[cr][nc + j + 0] = f2bu((v.x - m4.x) * r4.x * gg + bb);
      T[cr][nc + j + 1] = f2bu((v.y - m4.y) * r4.y * gg + bb);
      T[cr][nc + j + 2] = f2bu((v.z - m4.z) * r4.z * gg + bb);
      T[cr][nc + j + 3] = f2bu((v.w - m4.w) * r4.w * gg + bb);
    }
  }
  __syncthreads();
  {
    int nr = t >> 2, cc = (t & 3) * 16;
    u16x8 w0, w1;
    #pragma unroll
    for (int j = 0; j < 8; j++) w0[j] = T[cc + j][nr];
    #pragma unroll
    for (int j = 0; j < 8; j++) w1[j] = T[cc + 8 + j][nr];
    ushort_t* po = &ob[(size_t)(n0 + nr) * C_ + c0 + cc];
    *(u16x8*)po = w0;
    *(u16x8*)(po + 8) = w1;
  }
}

// ---------------- bf16 transpose: in [R][N_] -> out [N_][R]
__global__ __launch_bounds__(256) void transpose_bf16(const ushort_t* __restrict__ in,
                                                      ushort_t* __restrict__ out, int R) {
  __shared__ ushort_t T[64][72];
  int n0 = blockIdx.x * 64, r0 = blockIdx.y * 64;
  int t = threadIdx.x;
  {
    int rr = t >> 2, nc = (t & 3) * 16;
    const ushort_t* p = in + (size_t)(r0 + rr) * N_ + n0 + nc;
    *(u16x8*)&T[rr][nc] = *(const u16x8*)p;
    *(u16x8*)&T[rr][nc + 8] = *(const u16x8*)(p + 8);
  }
  __syncthreads();
  {
    int nr = t >> 2, cc = (t & 3) * 16;
    u16x8 w0, w1;
    #pragma unroll
    for (int j = 0; j < 8; j++) w0[j] = T[cc + j][nr];
    #pragma unroll
    for (int j = 0; j < 8; j++) w1[j] = T[cc + 8 + j][nr];
    ushort_t* po = &out[(size_t)(n0 + nr) * R + r0 + cc];
    *(u16x8*)po = w0;
    *(u16x8*)(po + 8) = w1;
  }
}

// =======================================================================
// MFMA GEMM template.  out[m][n] (+)= sum_t sum_k A[t][m][k] * Bx[t-shifted row n][k]
// A bf16 [m][k] k-contig (lda), B bf16 [row][k] k-contig (ldb), 128x128 tile, BK=64.
// DIMSEL: 0 none, 1 w-shift taps, 2 h-shift taps.
// OMODE: 1 bf16 [m][n]+bias; 2 bf16 [n][m]+bias; 3 fp32 [m][n]=acc+bias;
//        4 fp32 [m][n]+=acc+res; 5 fp32 [m][n]+=acc+bias; 6 fp32 [m][n]=acc (part)
// =======================================================================
template<int TAPS, int DIMSEL, int OMODE, int SPLIT>
__global__ __launch_bounds__(256) void mfma_gemm(
    const ushort_t* __restrict__ A, long Abatch, int lda, long Aplane,
    const ushort_t* __restrict__ B, long Bbatch, int ldb,
    const float* __restrict__ bias,
    const float* __restrict__ res, long Resbatch,
    float* __restrict__ outF, ushort_t* __restrict__ outB, long Outbatch, int ldo,
    int Ksteps, const ushort_t* __restrict__ zbuf) {
  __shared__ ushort_t sm[16384];       // A tile [128][64] @0, B tile [128][64] @8192
  int tid = threadIdx.x;
  int bx = blockIdx.x, by = blockIdx.y, bz = blockIdx.z;
  int b = bz / SPLIT, sK = bz % SPLIT;
  long koff = (long)sK * Ksteps * 64;
  const ushort_t* Ab = A + (size_t)b * Abatch + koff;
  const ushort_t* Bb = B + (size_t)b * Bbatch + koff;
  int n0 = bx * 128, m0 = by * 128;
  int lane = tid & 63, wid = tid >> 6, wm = wid >> 1, wn = wid & 1;

  f32x4 acc[4][4];
  #pragma unroll
  for (int i = 0; i < 4; i++)
    #pragma unroll
    for (int j = 0; j < 4; j++) acc[i][j] = (f32x4)0.f;

  for (int t = 0; t < TAPS; ++t) {
    if (DIMSEL == 2) {
      if ((bx == 0 && t == 0) || (bx == H_ - 1 && t == 2)) continue;
    }
    const ushort_t* At = Ab + (long)t * Aplane;
    for (int ks = 0; ks < Ksteps; ++ks) {
      int k0 = ks * 64;
      // stage A: 1024 slots of 16B
      #pragma unroll
      for (int i = 0; i < 4; i++) {
        int s = tid + i * 256;
        int row = s >> 3, pc = s & 7;
        int lc = pc ^ (row & 7);
        const ushort_t* g = At + (long)(m0 + row) * lda + k0 + lc * 8;
        GLD16(g, &sm[s * 8]);
      }
      // stage B
      #pragma unroll
      for (int i = 0; i < 4; i++) {
        int s = tid + i * 256;
        int row = s >> 3, pc = s & 7;
        int lc = pc ^ (row & 7);
        const ushort_t* g;
        if (TAPS == 3 && DIMSEL == 1) {
          int wpos = row + (t - 1);
          if (0 <= wpos && wpos < W_)
            g = Bb + (long)(n0 + row + (t - 1)) * ldb + k0 + lc * 8;
          else
            g = zbuf;
        } else if (TAPS == 3 && DIMSEL == 2) {
          g = Bb + (long)(n0 + row + (t - 1) * W_) * ldb + k0 + lc * 8;
        } else {
          g = Bb + (long)(n0 + row) * ldb + k0 + lc * 8;
        }
        GLD16(g, &sm[8192 + s * 8]);
      }
      __syncthreads();
      #pragma unroll
      for (int kk = 0; kk < 2; kk++) {
        bf16x8 av[4], bv[4];
        int r16 = lane & 15;
        int sl = (lane >> 4) + kk * 4;
        #pragma unroll
        for (int fm = 0; fm < 4; fm++) {
          int row = wm * 64 + fm * 16 + r16;
          av[fm] = *(const bf16x8*)&sm[row * 64 + ((sl ^ (row & 7)) * 8)];
        }
        #pragma unroll
        for (int fn = 0; fn < 4; fn++) {
          int row = wn * 64 + fn * 16 + r16;
          bv[fn] = *(const bf16x8*)&sm[8192 + row * 64 + ((sl ^ (row & 7)) * 8)];
        }
        #pragma unroll
        for (int fm = 0; fm < 4; fm++)
          #pragma unroll
          for (int fn = 0; fn < 4; fn++)
            acc[fm][fn] = __builtin_amdgcn_mfma_f32_16x16x32_bf16(av[fm], bv[fn], acc[fm][fn], 0, 0, 0);
      }
      __syncthreads();
    }
  }

  // epilogue
  int r16 = lane & 15, rq = lane >> 4;
  #pragma unroll
  for (int fm = 0; fm < 4; fm++) {
    #pragma unroll
    for (int fn = 0; fn < 4; fn++) {
      int mrow = m0 + wm * 64 + fm * 16 + rq * 4;
      int ncol = n0 + wn * 64 + fn * 16 + r16;
      f32x4 a = acc[fm][fn];
      if (OMODE == 1) {
        ushort_t* ob = outB + (size_t)bz * Outbatch;
        #pragma unroll
        for (int r = 0; r < 4; r++)
          ob[(size_t)(mrow + r) * ldo + ncol] = f2bu(a[r] + bias[mrow + r]);
      } else if (OMODE == 2) {
        ushort_t* ob = outB + (size_t)bz * Outbatch;
        uint2 pk;
        pk.x = (unsigned)f2bu(a[0] + bias[mrow + 0]) | ((unsigned)f2bu(a[1] + bias[mrow + 1]) << 16);
        pk.y = (unsigned)f2bu(a[2] + bias[mrow + 2]) | ((unsigned)f2bu(a[3] + bias[mrow + 3]) << 16);
        *(uint2*)&ob[(size_t)ncol * ldo + mrow] = pk;
      } else if (OMODE == 3) {
        float* of = outF + (size_t)bz * Outbatch;
        #pragma unroll
        for (int r = 0; r < 4; r++)
          of[(size_t)(mrow + r) * ldo + ncol] = a[r] + bias[mrow + r];
      } else if (OMODE == 4) {
        float* of = outF + (size_t)bz * Outbatch;
        const float* rp = res + (size_t)bz * Resbatch;
        #pragma unroll
        for (int r = 0; r < 4; r++) {
          size_t o = (size_t)(mrow + r) * ldo + ncol;
          of[o] = of[o] + a[r] + rp[o];
        }
      } else if (OMODE == 5) {
        float* of = outF + (size_t)bz * Outbatch;
        #pragma unroll
        for (int r = 0; r < 4; r++) {
          size_t o = (size_t)(mrow + r) * ldo + ncol;
          of[o] = of[o] + a[r] + bias[mrow + r];
        }
      } else if (OMODE == 6) {
        float* of = outF + (size_t)bz * Outbatch;
        #pragma unroll
        for (int r = 0; r < 4; r++)
          of[(size_t)(mrow + r) * ldo + ncol] = a[r];
      }
    }
  }
}

// ---------------- softmax over spatial axis, bf16 in-place, one block per (b,kc)
__global__ __launch_bounds__(256) void softmax_spatial_bf16(ushort_t* __restrict__ p) {
  size_t base = (size_t)blockIdx.x * N_;
  int tid = threadIdx.x;
  __shared__ float red[256];
  float mx = -1e30f;
  for (int i = tid * 8; i < N_; i += 2048) {
    u16x8 v = *(const u16x8*)&p[base + i];
    #pragma unroll
    for (int j = 0; j < 8; j++) mx = fmaxf(mx, bu2f(v[j]));
  }
  red[tid] = mx; __syncthreads();
  for (int s = 128; s > 0; s >>= 1) { if (tid < s) red[tid] = fmaxf(red[tid], red[tid + s]); __syncthreads(); }
  mx = red[0]; __syncthreads();
  float sum = 0.f;
  for (int i = tid * 8; i < N_; i += 2048) {
    u16x8 v = *(const u16x8*)&p[base + i];
    #pragma unroll
    for (int j = 0; j < 8; j++) sum += __expf(bu2f(v[j]) - mx);
  }
  red[tid] = sum; __syncthreads();
  for (int s = 128; s > 0; s >>= 1) { if (tid < s) red[tid] += red[tid + s]; __syncthreads(); }
  float inv = 1.f / red[0];
  for (int i = tid * 8; i < N_; i += 2048) {
    u16x8 v = *(const u16x8*)&p[base + i];
    u16x8 o;
    #pragma unroll
    for (int j = 0; j < 8; j++) o[j] = f2bu(__expf(bu2f(v[j]) - mx) * inv);
    *(u16x8*)&p[base + i] = o;
  }
}

// ---------------- softmax over channel axis on transposed qt [b*n][kc], in place
__global__ __launch_bounds__(256) void softmax_channel_t(ushort_t* __restrict__ p) {
  size_t idx = (size_t)blockIdx.x * 256 + threadIdx.x;
  ushort_t* q = p + idx * KC_;
  float mx = -1e30f;
  for (int i = 0; i < KC_; i += 8) {
    u16x8 v = *(const u16x8*)&q[i];
    #pragma unroll
    for (int j = 0; j < 8; j++) mx = fmaxf(mx, bu2f(v[j]));
  }
  float sum = 0.f;
  for (int i = 0; i < KC_; i += 8) {
    u16x8 v = *(const u16x8*)&q[i];
    #pragma unroll
    for (int j = 0; j < 8; j++) sum += __expf(bu2f(v[j]) - mx);
  }
  float inv = 1.f / sum;
  for (int i = 0; i < KC_; i += 8) {
    u16x8 v = *(const u16x8*)&q[i];
    u16x8 o;
    #pragma unroll
    for (int j = 0; j < 8; j++) o[j] = f2bu(__expf(bu2f(v[j]) - mx) * inv);
    *(u16x8*)&q[i] = o;
  }
}

// ---------------- amap: amap[b,n] (+)= (1/(2*KC)) * sum_kc key_s[b,kc,n]
template<bool STORE>
__global__ __launch_bounds__(256) void amap_kernel(const ushort_t* __restrict__ ks,
                                                   float* __restrict__ amap) {
  int idx = blockIdx.x * 256 + threadIdx.x;
  int b = idx >> 14;
  int n = idx & 16383;
  const ushort_t* p = ks + (size_t)b * KC_ * N_ + n;
  float s = 0.f;
  for (int c = 0; c < KC_; c++) s += bu2f(p[(size_t)c * N_]);
  s *= (1.f / (2.f * KC_));
  if (STORE) amap[idx] = s; else amap[idx] += s;
}

// ---------------- ctx split-K reduce: part fp32 -> out fp32
__global__ __launch_bounds__(256) void ctx_reduce(const float* __restrict__ part,
                                                  float* __restrict__ out) {
  int idx = blockIdx.x * 256 + threadIdx.x;   // b*KC*VC
  int b = idx >> 16;
  int r = idx & 65535;
  float s = 0.f;
  #pragma unroll
  for (int k = 0; k < CTX_SPLIT; k++)
    s += part[((size_t)(b * CTX_SPLIT + k)) * KC_ * VC_ + r];
  out[idx] = s;
}

// ---------------- M[b,c,kc] = sum_v wr[c, dsel*VC+v] * ctx[b,kc,v]  (bf16 out)
__global__ __launch_bounds__(256) void mk_kernel(const float* __restrict__ wr,
    const float* __restrict__ ctx, int dsel, ushort_t* __restrict__ Mout) {
  int b = blockIdx.x >> 8;
  int c = blockIdx.x & 255;
  int kc = threadIdx.x;
  __shared__ float wrow[VC_];
  wrow[threadIdx.x] = wr[(size_t)c * (2 * VC_) + dsel * VC_ + threadIdx.x];
  __syncthreads();
  const float* cp = ctx + (size_t)b * KC_ * VC_ + (size_t)kc * VC_;
  float s = 0.f;
  for (int v = 0; v < VC_; v++) s += wrow[v] * cp[v];
  Mout[(size_t)b * C_ * KC_ + (size_t)c * KC_ + kc] = f2bu(s);
}

// ---------------- depthwise 3x3 + exact GELU, bf16 [hid][n] -> bf16 [hid][n]
__global__ __launch_bounds__(256) void dwgelu_kernel(const ushort_t* __restrict__ h1,
    const float* __restrict__ wdw, const float* __restrict__ bdw,
    ushort_t* __restrict__ act) {
  int c = blockIdx.y;
  int n = blockIdx.x * 256 + threadIdx.x;
  int h = n >> 7, w = n & 127;
  const ushort_t* p = h1 + (size_t)c * N_;
  const float* wp = wdw + c * 9;
  float s = bdw[c];
  #pragma unroll
  for (int di = -1; di <= 1; ++di) {
    int h2 = h + di;
    if ((unsigned)h2 >= H_) continue;
    #pragma unroll
    for (int dj = -1; dj <= 1; ++dj) {
      int w2 = w + dj;
      if ((unsigned)w2 >= W_) continue;
      s += wp[(di + 1) * 3 + (dj + 1)] * bu2f(p[h2 * W_ + w2]);
    }
  }
  float gl = 0.5f * s * (1.f + erff(s * 0.70710678118654752f));
  act[(size_t)c * N_ + n] = f2bu(gl);
}

extern "C" void kernel_launch(void* const* d_in, const int* in_sizes, int n_in,
                              void* d_out, int out_size, void* d_ws, size_t ws_size,
                              hipStream_t stream) {
  const float* x    = (const float*)d_in[0];
  const float* wk1  = (const float*)d_in[3];
  const float* bk1  = (const float*)d_in[4];
  const float* wk2  = (const float*)d_in[5];
  const float* bk2  = (const float*)d_in[6];
  const float* wq1  = (const float*)d_in[7];
  const float* bq1  = (const float*)d_in[8];
  const float* wq2  = (const float*)d_in[9];
  const float* bq2  = (const float*)d_in[10];
  const float* wv   = (const float*)d_in[11];
  const float* bv   = (const float*)d_in[12];
  const float* wr   = (const float*)d_in[13];
  const float* br   = (const float*)d_in[14];
  const float* g1   = (const float*)d_in[15];
  const float* b1   = (const float*)d_in[16];
  const float* g2   = (const float*)d_in[17];
  const float* b2   = (const float*)d_in[18];
  const float* wfc1 = (const float*)d_in[19];
  const float* bfc1 = (const float*)d_in[20];
  const float* wdw  = (const float*)d_in[21];
  const float* bdw  = (const float*)d_in[22];
  const float* wfc2 = (const float*)d_in[23];
  const float* bfc2 = (const float*)d_in[24];

  const size_t big = (size_t)B_ * C_ * N_;
  const long  CN  = (long)C_ * N_;
  const long  NC2 = (long)N_ * C_;      // elements per batch of [n][c]

  uint8_t* w8 = (uint8_t*)d_ws;
  size_t off = 0;
  ushort_t* xnt = (ushort_t*)(w8 + off); off += 67108864;   // [b][n][c] bf16
  ushort_t* kq  = (ushort_t*)(w8 + off); off += 67108864;   // k: [b][kc][n] / q: [b][n][kc]
  float*  part  = (float*)(w8 + off);    off += (size_t)CTX_SPLIT * B_ * KC_ * VC_ * 4;  // 8.4MB
  float*  ctx0  = (float*)(w8 + off);    off += (size_t)B_ * KC_ * VC_ * 4;              // 2MB
  ushort_t* Mbuf= (ushort_t*)(w8 + off); off += (size_t)B_ * C_ * KC_ * 2;               // 1MB
  float* mean1  = (float*)(w8 + off);    off += (size_t)B_ * N_ * 4;
  float* rstd1  = (float*)(w8 + off);    off += (size_t)B_ * N_ * 4;
  float* mean2  = (float*)(w8 + off);    off += (size_t)B_ * N_ * 4;
  float* rstd2  = (float*)(w8 + off);    off += (size_t)B_ * N_ * 4;
  ushort_t* wk1p = (ushort_t*)(w8 + off); off += 3 * KC_ * C_ * 2;
  ushort_t* wk2p = (ushort_t*)(w8 + off); off += 3 * KC_ * C_ * 2;
  ushort_t* wq1p = (ushort_t*)(w8 + off); off += 3 * KC_ * C_ * 2;
  ushort_t* wq2p = (ushort_t*)(w8 + off); off += 3 * KC_ * C_ * 2;
  ushort_t* wvp  = (ushort_t*)(w8 + off); off += VC_ * C_ * 2;
  ushort_t* wfc1p= (ushort_t*)(w8 + off); off += HID_ * C_ * 2;
  ushort_t* wfc2p= (ushort_t*)(w8 + off); off += C_ * HID_ * 2;
  ushort_t* zbuf = (ushort_t*)(w8 + off); off += 512;
  if (ws_size < off) return;

  // FFN-phase overlays (xnt/kq dead by then)
  ushort_t* txn  = xnt;                                     // [n][c] per batch, 8.4MB
  ushort_t* h1B  = (ushort_t*)((uint8_t*)xnt + 8388608);    // [hid][n] bf16, 33.5MB
  ushort_t* act  = kq;                                      // [hid][n] bf16, 33.5MB
  ushort_t* actT = (ushort_t*)((uint8_t*)kq + 33554432);    // [n][hid] bf16, 33.5MB

  float* mx_out   = (float*)d_out;
  float* ctx_out  = mx_out + big;
  float* amap_out = ctx_out + (size_t)B_ * KC_ * VC_;
  ushort_t* valB  = (ushort_t*)d_out;    // val bf16 [b][vc][n] lives in mx region (phase 1)

  dim3 blk(256);

  zero_kernel<<<1, 64, 0, stream>>>(zbuf);
  pack3_kernel<<<KC_ * C_ / 256, blk, 0, stream>>>(wk1, wk1p, KC_ * C_);
  pack3_kernel<<<KC_ * C_ / 256, blk, 0, stream>>>(wk2, wk2p, KC_ * C_);
  pack3_kernel<<<KC_ * C_ / 256, blk, 0, stream>>>(wq1, wq1p, KC_ * C_);
  pack3_kernel<<<KC_ * C_ / 256, blk, 0, stream>>>(wq2, wq2p, KC_ * C_);
  pack1_kernel<<<VC_ * C_ / 256, blk, 0, stream>>>(wv, wvp, VC_ * C_);
  pack1_kernel<<<HID_ * C_ / 256, blk, 0, stream>>>(wfc1, wfc1p, HID_ * C_);
  pack1_kernel<<<C_ * HID_ / 256, blk, 0, stream>>>(wfc2, wfc2p, C_ * HID_);

  // LN1 stats + xnt = LN1(x) transposed bf16
  ln_stats<<<B_ * N_ / 256, blk, 0, stream>>>(x, mean1, rstd1);
  lnt_kernel<<<dim3(N_ / 64, C_ / 64, B_), blk, 0, stream>>>(
      x, CN, mean1, rstd1, (long)N_, g1, b1, xnt, NC2);

  // val = wv @ xn + bv  -> bf16 [b][vc][n] in d_out mx region
  mfma_gemm<1, 0, 1, 1><<<dim3(N_ / 128, VC_ / 128, B_), blk, 0, stream>>>(
      wvp, 0, C_, 0, xnt, NC2, C_, bv, nullptr, 0,
      nullptr, valB, (long)VC_ * N_, N_, C_ / 64, zbuf);

  // Phase 1: K path + ctx (val alive in mx region)
  for (int d = 0; d < 2; ++d) {
    const ushort_t* wkp = d ? wk2p : wk1p;
    const float* bk = d ? bk2 : bk1;
    if (d == 0)
      mfma_gemm<3, 1, 1, 1><<<dim3(N_ / 128, KC_ / 128, B_), blk, 0, stream>>>(
          wkp, 0, C_, (long)KC_ * C_, xnt, NC2, C_, bk, nullptr, 0,
          nullptr, kq, (long)KC_ * N_, N_, C_ / 64, zbuf);
    else
      mfma_gemm<3, 2, 1, 1><<<dim3(N_ / 128, KC_ / 128, B_), blk, 0, stream>>>(
          wkp, 0, C_, (long)KC_ * C_, xnt, NC2, C_, bk, nullptr, 0,
          nullptr, kq, (long)KC_ * N_, N_, C_ / 64, zbuf);
    softmax_spatial_bf16<<<B_ * KC_, blk, 0, stream>>>(kq);
    if (d == 0) amap_kernel<true><<<B_ * N_ / 256, blk, 0, stream>>>(kq, amap_out);
    else        amap_kernel<false><<<B_ * N_ / 256, blk, 0, stream>>>(kq, amap_out);
    // ctx: A=key_s [kc][n], B=val [vc][n], K=16384 split 4
    mfma_gemm<1, 0, 6, CTX_SPLIT><<<dim3(VC_ / 128, KC_ / 128, B_ * CTX_SPLIT), blk, 0, stream>>>(
        kq, (long)KC_ * N_, N_, 0, valB, (long)VC_ * N_, N_, nullptr, nullptr, 0,
        part, nullptr, (long)KC_ * VC_, VC_, (N_ / CTX_SPLIT) / 64, zbuf);
    ctx_reduce<<<B_ * KC_ * VC_ / 256, blk, 0, stream>>>(part, d ? ctx_out : ctx0);
  }

  // Phase 2: Q path + attention (val dead; mx region becomes tx)
  for (int d = 0; d < 2; ++d) {
    const ushort_t* wqp = d ? wq2p : wq1p;
    const float* bq = d ? bq2 : bq1;
    if (d == 0)
      mfma_gemm<3, 1, 2, 1><<<dim3(N_ / 128, KC_ / 128, B_), blk, 0, stream>>>(
          wqp, 0, C_, (long)KC_ * C_, xnt, NC2, C_, bq, nullptr, 0,
          nullptr, kq, (long)N_ * KC_, KC_, C_ / 64, zbuf);
    else
      mfma_gemm<3, 2, 2, 1><<<dim3(N_ / 128, KC_ / 128, B_), blk, 0, stream>>>(
          wqp, 0, C_, (long)KC_ * C_, xnt, NC2, C_, bq, nullptr, 0,
          nullptr, kq, (long)N_ * KC_, KC_, C_ / 64, zbuf);
    softmax_channel_t<<<B_ * N_ / 256, blk, 0, stream>>>(kq);
    mk_kernel<<<B_ * C_, blk, 0, stream>>>(wr, d ? ctx_out : ctx0, d, Mbuf);
    if (d == 0)
      mfma_gemm<1, 0, 3, 1><<<dim3(N_ / 128, C_ / 128, B_), blk, 0, stream>>>(
          Mbuf, (long)C_ * KC_, KC_, 0, kq, (long)N_ * KC_, KC_, br, nullptr, 0,
          mx_out, nullptr, CN, N_, KC_ / 64, zbuf);
    else
      mfma_gemm<1, 0, 4, 1><<<dim3(N_ / 128, C_ / 128, B_), blk, 0, stream>>>(
          Mbuf, (long)C_ * KC_, KC_, 0, kq, (long)N_ * KC_, KC_, nullptr, x, CN,
          mx_out, nullptr, CN, N_, KC_ / 64, zbuf);
  }

  // LN2 stats on tx (in mx_out)
  ln_stats<<<B_ * N_ / 256, blk, 0, stream>>>(mx_out, mean2, rstd2);

  // FFN per batch
  for (int b = 0; b < B_; ++b) {
    lnt_kernel<<<dim3(N_ / 64, C_ / 64, 1), blk, 0, stream>>>(
        mx_out + (size_t)b * CN, 0, mean2 + (size_t)b * N_, rstd2 + (size_t)b * N_, 0,
        g2, b2, txn, 0);
    mfma_gemm<1, 0, 1, 1><<<dim3(N_ / 128, HID_ / 128, 1), blk, 0, stream>>>(
        wfc1p, 0, C_, 0, txn, 0, C_, bfc1, nullptr, 0,
        nullptr, h1B, 0, N_, C_ / 64, zbuf);
    dwgelu_kernel<<<dim3(N_ / 256, HID_), blk, 0, stream>>>(h1B, wdw, bdw, act);
    transpose_bf16<<<dim3(N_ / 64, HID_ / 64), blk, 0, stream>>>(act, actT, HID_);
    mfma_gemm<1, 0, 5, 1><<<dim3(N_ / 128, C_ / 128, 1), blk, 0, stream>>>(
        wfc2p, 0, HID_, 0, actT, 0, HID_, bfc2, nullptr, 0,
        mx_out + (size_t)b * CN, nullptr, 0, N_, HID_ / 64, zbuf);
  }
}

// Round 5
// 1915.378 us; speedup vs baseline: 6.6052x; 1.2453x over previous
//
#include <hip/hip_runtime.h>
#include <hip/hip_bf16.h>

#define B_ 8
#define C_ 256
#define H_ 128
#define W_ 128
#define N_ 16384
#define KC_ 256
#define VC_ 256
#define HID_ 1024

typedef unsigned short ushort_t;
typedef __bf16 bf16x8 __attribute__((ext_vector_type(8)));
typedef float f32x4 __attribute__((ext_vector_type(4)));
typedef ushort_t u16x8 __attribute__((ext_vector_type(8)));
typedef ushort_t u16x4 __attribute__((ext_vector_type(4)));

static __device__ __forceinline__ ushort_t f2bu(float f) {
  __hip_bfloat16 h = __float2bfloat16(f);
  return *reinterpret_cast<ushort_t*>(&h);
}
static __device__ __forceinline__ float bu2f(ushort_t u) {
  __hip_bfloat16 h;
  *reinterpret_cast<ushort_t*>(&h) = u;
  return __bfloat162float(h);
}

#define GLD16(gp, lp) __builtin_amdgcn_global_load_lds( \
    (const __attribute__((address_space(1))) void*)(gp), \
    (__attribute__((address_space(3))) void*)(lp), 16, 0, 0)

// ---------------- tiny utility kernels ----------------
__global__ __launch_bounds__(64) void zero_kernel(ushort_t* p) {
  p[threadIdx.x] = 0;
}

// [M][C][3] fp32 -> [3][M][C] bf16
__global__ __launch_bounds__(256) void pack3_kernel(const float* __restrict__ in,
                                                    ushort_t* __restrict__ out, int MC) {
  int idx = blockIdx.x * 256 + threadIdx.x;
  if (idx >= MC) return;
  #pragma unroll
  for (int t = 0; t < 3; ++t) out[t * MC + idx] = f2bu(in[idx * 3 + t]);
}

// flat fp32 -> bf16
__global__ __launch_bounds__(256) void pack1_kernel(const float* __restrict__ in,
                                                    ushort_t* __restrict__ out, int n) {
  int idx = blockIdx.x * 256 + threadIdx.x;
  if (idx < n) out[idx] = f2bu(in[idx]);
}

// dw weights [hid][9] fp32 -> [9][hid] fp32
__global__ __launch_bounds__(256) void packdw_kernel(const float* __restrict__ in,
                                                     float* __restrict__ out) {
  int idx = blockIdx.x * 256 + threadIdx.x;
  if (idx < HID_ * 9) {
    int c = idx / 9, t = idx % 9;
    out[t * HID_ + c] = in[idx];
  }
}

// ---------------- LN stats per pixel over channel dim (layout b,c,n)
__global__ __launch_bounds__(256) void ln_stats(const float* __restrict__ in,
    float* __restrict__ meanout, float* __restrict__ rstdout) {
  int idx = blockIdx.x * 256 + threadIdx.x;   // b*N + n
  int b = idx >> 14;
  int n = idx & 16383;
  const float* p = in + (size_t)b * C_ * N_ + n;
  float s1 = 0.f, s2 = 0.f;
  for (int c = 0; c < C_; ++c) { float v = p[(size_t)c * N_]; s1 += v; s2 += v * v; }
  float m = s1 * (1.f / C_);
  float var = s2 * (1.f / C_) - m * m;
  meanout[idx] = m;
  rstdout[idx] = rsqrtf(var + 1e-5f);
}

// ---------------- LN + transpose + bf16: in fp32 [c][n] -> out bf16 [n][c]
__global__ __launch_bounds__(256) void lnt_kernel(
    const float* __restrict__ in, long inBatch,
    const float* __restrict__ mean, const float* __restrict__ rstd, long statBatch,
    const float* __restrict__ g, const float* __restrict__ beta,
    ushort_t* __restrict__ out, long outBatch) {
  __shared__ ushort_t T[64][72];
  int z = blockIdx.z;
  int n0 = blockIdx.x * 64, c0 = blockIdx.y * 64;
  const float* inb = in + (size_t)z * inBatch;
  const float* mb = mean + (size_t)z * statBatch;
  const float* rb = rstd + (size_t)z * statBatch;
  ushort_t* ob = out + (size_t)z * outBatch;
  int t = threadIdx.x;
  {
    int cr = t >> 2, nc = (t & 3) * 16;
    const float* p = inb + (size_t)(c0 + cr) * N_ + n0 + nc;
    float gg = g[c0 + cr], bb = beta[c0 + cr];
    #pragma unroll
    for (int j = 0; j < 16; j += 4) {
      float4 v = *(const float4*)&p[j];
      float4 m4 = *(const float4*)&mb[n0 + nc + j];
      float4 r4 = *(const float4*)&rb[n0 + nc + j];
      T[cr][nc + j + 0] = f2bu((v.x - m4.x) * r4.x * gg + bb);
      T[cr][nc + j + 1] = f2bu((v.y - m4.y) * r4.y * gg + bb);
      T[cr][nc + j + 2] = f2bu((v.z - m4.z) * r4.z * gg + bb);
      T[cr][nc + j + 3] = f2bu((v.w - m4.w) * r4.w * gg + bb);
    }
  }
  __syncthreads();
  {
    int nr = t >> 2, cc = (t & 3) * 16;
    u16x8 w0, w1;
    #pragma unroll
    for (int j = 0; j < 8; j++) w0[j] = T[cc + j][nr];
    #pragma unroll
    for (int j = 0; j < 8; j++) w1[j] = T[cc + 8 + j][nr];
    ushort_t* po = &ob[(size_t)(n0 + nr) * C_ + c0 + cc];
    *(u16x8*)po = w0;
    *(u16x8*)(po + 8) = w1;
  }
}

// =======================================================================
// MFMA GEMM template.  out[m][n] (+)= sum_t sum_k A[t][m][k] * Bx[t-shifted row n][k]
// A bf16 [m][k] k-contig (lda), B bf16 [row][k] k-contig (ldb), 128x128 tile, BK=64.
// DIMSEL: 0 none, 1 w-shift taps, 2 h-shift taps.
// OMODE: 1 bf16 [m][n]+bias (LDS-coalesced); 2 bf16 [n][m]+bias (LDS-coalesced);
//        3 fp32 [m][n]=acc+bias; 4 fp32 [m][n]+=acc+res; 5 fp32 [m][n]+=acc+bias;
//        6 fp32 [m][n]=acc (split-K partial)
// blockIdx.x swizzled XCD-chunked when gridDim.x==128.
// =======================================================================
template<int TAPS, int DIMSEL, int OMODE, int SPLIT>
__global__ __launch_bounds__(256) void mfma_gemm(
    const ushort_t* __restrict__ A, long Abatch, int lda, long Aplane,
    const ushort_t* __restrict__ B, long Bbatch, int ldb,
    const float* __restrict__ bias,
    const float* __restrict__ res, long Resbatch,
    float* __restrict__ outF, ushort_t* __restrict__ outB, long Outbatch, int ldo,
    int Ksteps, const ushort_t* __restrict__ zbuf) {
  __shared__ ushort_t sm[17408];   // main loop: A[0:8192) B[8192:16384); epilogue: [128][136]
  int tid = threadIdx.x;
  int bx = blockIdx.x, by = blockIdx.y, bz = blockIdx.z;
  if (gridDim.x == 128) bx = ((bx & 7) << 4) | (bx >> 3);   // XCD-chunked swizzle
  int b = bz / SPLIT, sK = bz % SPLIT;
  long koff = (long)sK * Ksteps * 64;
  const ushort_t* Ab = A + (size_t)b * Abatch + koff;
  const ushort_t* Bb = B + (size_t)b * Bbatch + koff;
  int n0 = bx * 128, m0 = by * 128;
  int lane = tid & 63, wid = tid >> 6, wm = wid >> 1, wn = wid & 1;

  f32x4 acc[4][4];
  #pragma unroll
  for (int i = 0; i < 4; i++)
    #pragma unroll
    for (int j = 0; j < 4; j++) acc[i][j] = (f32x4)0.f;

  for (int t = 0; t < TAPS; ++t) {
    if (DIMSEL == 2) {
      if ((bx == 0 && t == 0) || (bx == H_ - 1 && t == 2)) continue;
    }
    const ushort_t* At = Ab + (long)t * Aplane;
    for (int ks = 0; ks < Ksteps; ++ks) {
      int k0 = ks * 64;
      #pragma unroll
      for (int i = 0; i < 4; i++) {
        int s = tid + i * 256;
        int row = s >> 3, pc = s & 7;
        int lc = pc ^ (row & 7);
        const ushort_t* g = At + (long)(m0 + row) * lda + k0 + lc * 8;
        GLD16(g, &sm[s * 8]);
      }
      #pragma unroll
      for (int i = 0; i < 4; i++) {
        int s = tid + i * 256;
        int row = s >> 3, pc = s & 7;
        int lc = pc ^ (row & 7);
        const ushort_t* g;
        if (TAPS == 3 && DIMSEL == 1) {
          int wpos = row + (t - 1);
          if (0 <= wpos && wpos < W_)
            g = Bb + (long)(n0 + row + (t - 1)) * ldb + k0 + lc * 8;
          else
            g = zbuf;
        } else if (TAPS == 3 && DIMSEL == 2) {
          g = Bb + (long)(n0 + row + (t - 1) * W_) * ldb + k0 + lc * 8;
        } else {
          g = Bb + (long)(n0 + row) * ldb + k0 + lc * 8;
        }
        GLD16(g, &sm[8192 + s * 8]);
      }
      __syncthreads();
      #pragma unroll
      for (int kk = 0; kk < 2; kk++) {
        bf16x8 av[4], bv[4];
        int r16 = lane & 15;
        int sl = (lane >> 4) + kk * 4;
        #pragma unroll
        for (int fm = 0; fm < 4; fm++) {
          int row = wm * 64 + fm * 16 + r16;
          av[fm] = *(const bf16x8*)&sm[row * 64 + ((sl ^ (row & 7)) * 8)];
        }
        #pragma unroll
        for (int fn = 0; fn < 4; fn++) {
          int row = wn * 64 + fn * 16 + r16;
          bv[fn] = *(const bf16x8*)&sm[8192 + row * 64 + ((sl ^ (row & 7)) * 8)];
        }
        #pragma unroll
        for (int fm = 0; fm < 4; fm++)
          #pragma unroll
          for (int fn = 0; fn < 4; fn++)
            acc[fm][fn] = __builtin_amdgcn_mfma_f32_16x16x32_bf16(av[fm], bv[fn], acc[fm][fn], 0, 0, 0);
      }
      __syncthreads();
    }
  }

  int r16 = lane & 15, rq = lane >> 4;
  if (OMODE == 1 || OMODE == 2) {
    // stage bf16 tile in LDS (pad 136), then coalesced u16x8 writeout
    ushort_t* ob = outB + (size_t)bz * Outbatch;
    #pragma unroll
    for (int fm = 0; fm < 4; fm++) {
      #pragma unroll
      for (int fn = 0; fn < 4; fn++) {
        int lm = wm * 64 + fm * 16 + rq * 4;
        int ln = wn * 64 + fn * 16 + r16;
        f32x4 a = acc[fm][fn];
        if (OMODE == 1) {
          #pragma unroll
          for (int r = 0; r < 4; r++)
            sm[(lm + r) * 136 + ln] = f2bu(a[r] + bias[m0 + lm + r]);
        } else {
          u16x4 pk;
          #pragma unroll
          for (int r = 0; r < 4; r++) pk[r] = f2bu(a[r] + bias[m0 + lm + r]);
          *(u16x4*)&sm[ln * 136 + lm] = pk;
        }
      }
    }
    __syncthreads();
    int row = tid >> 1, half = (tid & 1) * 64;
    const ushort_t* src = &sm[row * 136 + half];
    ushort_t* dst;
    if (OMODE == 1) dst = &ob[(size_t)(m0 + row) * ldo + n0 + half];
    else            dst = &ob[(size_t)(n0 + row) * ldo + m0 + half];
    #pragma unroll
    for (int j = 0; j < 8; j++)
      *(u16x8*)(dst + j * 8) = *(const u16x8*)(src + j * 8);
  } else {
    #pragma unroll
    for (int fm = 0; fm < 4; fm++) {
      #pragma unroll
      for (int fn = 0; fn < 4; fn++) {
        int mrow = m0 + wm * 64 + fm * 16 + rq * 4;
        int ncol = n0 + wn * 64 + fn * 16 + r16;
        f32x4 a = acc[fm][fn];
        if (OMODE == 3) {
          float* of = outF + (size_t)bz * Outbatch;
          #pragma unroll
          for (int r = 0; r < 4; r++)
            of[(size_t)(mrow + r) * ldo + ncol] = a[r] + bias[mrow + r];
        } else if (OMODE == 4) {
          float* of = outF + (size_t)bz * Outbatch;
          const float* rp = res + (size_t)bz * Resbatch;
          #pragma unroll
          for (int r = 0; r < 4; r++) {
            size_t o = (size_t)(mrow + r) * ldo + ncol;
            of[o] = of[o] + a[r] + rp[o];
          }
        } else if (OMODE == 5) {
          float* of = outF + (size_t)bz * Outbatch;
          #pragma unroll
          for (int r = 0; r < 4; r++) {
            size_t o = (size_t)(mrow + r) * ldo + ncol;
            of[o] = of[o] + a[r] + bias[mrow + r];
          }
        } else if (OMODE == 6) {
          float* of = outF + (size_t)bz * Outbatch;
          #pragma unroll
          for (int r = 0; r < 4; r++)
            of[(size_t)(mrow + r) * ldo + ncol] = a[r];
        }
      }
    }
  }
}

// ---------------- softmax over spatial axis, bf16 in-place, one block per (b,kc)
__global__ __launch_bounds__(256) void softmax_spatial_bf16(ushort_t* __restrict__ p) {
  size_t base = (size_t)blockIdx.x * N_;
  int tid = threadIdx.x;
  __shared__ float red[256];
  float mx = -1e30f;
  for (int i = tid * 8; i < N_; i += 2048) {
    u16x8 v = *(const u16x8*)&p[base + i];
    #pragma unroll
    for (int j = 0; j < 8; j++) mx = fmaxf(mx, bu2f(v[j]));
  }
  red[tid] = mx; __syncthreads();
  for (int s = 128; s > 0; s >>= 1) { if (tid < s) red[tid] = fmaxf(red[tid], red[tid + s]); __syncthreads(); }
  mx = red[0]; __syncthreads();
  float sum = 0.f;
  for (int i = tid * 8; i < N_; i += 2048) {
    u16x8 v = *(const u16x8*)&p[base + i];
    #pragma unroll
    for (int j = 0; j < 8; j++) sum += __expf(bu2f(v[j]) - mx);
  }
  red[tid] = sum; __syncthreads();
  for (int s = 128; s > 0; s >>= 1) { if (tid < s) red[tid] += red[tid + s]; __syncthreads(); }
  float inv = 1.f / red[0];
  for (int i = tid * 8; i < N_; i += 2048) {
    u16x8 v = *(const u16x8*)&p[base + i];
    u16x8 o;
    #pragma unroll
    for (int j = 0; j < 8; j++) o[j] = f2bu(__expf(bu2f(v[j]) - mx) * inv);
    *(u16x8*)&p[base + i] = o;
  }
}

// ---------------- softmax over channel axis on transposed qt [b*n][kc], in place
__global__ __launch_bounds__(256) void softmax_channel_t(ushort_t* __restrict__ p) {
  size_t idx = (size_t)blockIdx.x * 256 + threadIdx.x;
  ushort_t* q = p + idx * KC_;
  float mx = -1e30f;
  for (int i = 0; i < KC_; i += 8) {
    u16x8 v = *(const u16x8*)&q[i];
    #pragma unroll
    for (int j = 0; j < 8; j++) mx = fmaxf(mx, bu2f(v[j]));
  }
  float sum = 0.f;
  for (int i = 0; i < KC_; i += 8) {
    u16x8 v = *(const u16x8*)&q[i];
    #pragma unroll
    for (int j = 0; j < 8; j++) sum += __expf(bu2f(v[j]) - mx);
  }
  float inv = 1.f / sum;
  for (int i = 0; i < KC_; i += 8) {
    u16x8 v = *(const u16x8*)&q[i];
    u16x8 o;
    #pragma unroll
    for (int j = 0; j < 8; j++) o[j] = f2bu(__expf(bu2f(v[j]) - mx) * inv);
    *(u16x8*)&q[i] = o;
  }
}

// ---------------- amap: amap[b,n] (+)= (1/(2*KC)) * sum_kc key_s[b,kc,n]
template<bool STORE>
__global__ __launch_bounds__(256) void amap_kernel(const ushort_t* __restrict__ ks,
                                                   float* __restrict__ amap) {
  int idx = blockIdx.x * 256 + threadIdx.x;
  int b = idx >> 14;
  int n = idx & 16383;
  const ushort_t* p = ks + (size_t)b * KC_ * N_ + n;
  float s = 0.f;
  for (int c = 0; c < KC_; c++) s += bu2f(p[(size_t)c * N_]);
  s *= (1.f / (2.f * KC_));
  if (STORE) amap[idx] = s; else amap[idx] += s;
}

// ---------------- ctx split-K reduce: part fp32 -> out fp32 (runtime split)
__global__ __launch_bounds__(256) void ctx_reduce(const float* __restrict__ part,
                                                  float* __restrict__ out, int split) {
  int idx = blockIdx.x * 256 + threadIdx.x;   // b*KC*VC
  int b = idx >> 16;
  int r = idx & 65535;
  float s = 0.f;
  for (int k = 0; k < split; k++)
    s += part[((size_t)(b * split + k)) * KC_ * VC_ + r];
  out[idx] = s;
}

// ---------------- M[b,c,kc] = sum_v wr[c, dsel*VC+v] * ctx[b,kc,v]  (bf16 out)
__global__ __launch_bounds__(256) void mk_kernel(const float* __restrict__ wr,
    const float* __restrict__ ctx, int dsel, ushort_t* __restrict__ Mout) {
  int b = blockIdx.x >> 8;
  int c = blockIdx.x & 255;
  int kc = threadIdx.x;
  __shared__ float wrow[VC_];
  wrow[threadIdx.x] = wr[(size_t)c * (2 * VC_) + dsel * VC_ + threadIdx.x];
  __syncthreads();
  const float* cp = ctx + (size_t)b * KC_ * VC_ + (size_t)kc * VC_;
  float s = 0.f;
  for (int v = 0; v < VC_; v++) s += wrow[v] * cp[v];
  Mout[(size_t)b * C_ * KC_ + (size_t)c * KC_ + kc] = f2bu(s);
}

// ---------------- depthwise 3x3 + exact GELU in [n][hid] layout
// h1t [n][hid] bf16 -> actT [n][hid] bf16. 2 pixels per block, 8 channels/thread.
__global__ __launch_bounds__(256) void dwgelu_t(const ushort_t* __restrict__ h1t,
    const float* __restrict__ wdwT, const float* __restrict__ bdw,
    ushort_t* __restrict__ actT) {
  int pix = blockIdx.x * 2 + (threadIdx.x >> 7);
  int c = (threadIdx.x & 127) * 8;
  int h = pix >> 7, w = pix & 127;
  float s[8];
  {
    float4 b0 = *(const float4*)&bdw[c];
    float4 b1 = *(const float4*)&bdw[c + 4];
    s[0]=b0.x; s[1]=b0.y; s[2]=b0.z; s[3]=b0.w;
    s[4]=b1.x; s[5]=b1.y; s[6]=b1.z; s[7]=b1.w;
  }
  #pragma unroll
  for (int di = -1; di <= 1; ++di) {
    int h2 = h + di;
    if ((unsigned)h2 >= H_) continue;
    #pragma unroll
    for (int dj = -1; dj <= 1; ++dj) {
      int w2 = w + dj;
      if ((unsigned)w2 >= W_) continue;
      int tap = (di + 1) * 3 + (dj + 1);
      u16x8 v = *(const u16x8*)&h1t[(size_t)(h2 * W_ + w2) * HID_ + c];
      const float* wp = &wdwT[tap * HID_ + c];
      float4 w0 = *(const float4*)wp, w1 = *(const float4*)(wp + 4);
      s[0] += w0.x * bu2f(v[0]); s[1] += w0.y * bu2f(v[1]);
      s[2] += w0.z * bu2f(v[2]); s[3] += w0.w * bu2f(v[3]);
      s[4] += w1.x * bu2f(v[4]); s[5] += w1.y * bu2f(v[5]);
      s[6] += w1.z * bu2f(v[6]); s[7] += w1.w * bu2f(v[7]);
    }
  }
  u16x8 o;
  #pragma unroll
  for (int j = 0; j < 8; j++) {
    float gl = 0.5f * s[j] * (1.f + erff(s[j] * 0.70710678118654752f));
    o[j] = f2bu(gl);
  }
  *(u16x8*)&actT[(size_t)pix * HID_ + c] = o;
}

extern "C" void kernel_launch(void* const* d_in, const int* in_sizes, int n_in,
                              void* d_out, int out_size, void* d_ws, size_t ws_size,
                              hipStream_t stream) {
  const float* x    = (const float*)d_in[0];
  const float* wk1  = (const float*)d_in[3];
  const float* bk1  = (const float*)d_in[4];
  const float* wk2  = (const float*)d_in[5];
  const float* bk2  = (const float*)d_in[6];
  const float* wq1  = (const float*)d_in[7];
  const float* bq1  = (const float*)d_in[8];
  const float* wq2  = (const float*)d_in[9];
  const float* bq2  = (const float*)d_in[10];
  const float* wv   = (const float*)d_in[11];
  const float* bv   = (const float*)d_in[12];
  const float* wr   = (const float*)d_in[13];
  const float* br   = (const float*)d_in[14];
  const float* g1   = (const float*)d_in[15];
  const float* b1   = (const float*)d_in[16];
  const float* g2   = (const float*)d_in[17];
  const float* b2   = (const float*)d_in[18];
  const float* wfc1 = (const float*)d_in[19];
  const float* bfc1 = (const float*)d_in[20];
  const float* wdw  = (const float*)d_in[21];
  const float* bdw  = (const float*)d_in[22];
  const float* wfc2 = (const float*)d_in[23];
  const float* bfc2 = (const float*)d_in[24];

  const size_t big = (size_t)B_ * C_ * N_;
  const long  CN  = (long)C_ * N_;
  const long  NC2 = (long)N_ * C_;

  uint8_t* w8 = (uint8_t*)d_ws;
  size_t off = 0;
  ushort_t* xnt = (ushort_t*)(w8 + off); off += 67108864;   // [b][n][c] bf16
  ushort_t* kq  = (ushort_t*)(w8 + off); off += 67108864;   // k: [b][kc][n] / q: [b][n][kc]
  float*  ctx0  = (float*)(w8 + off);    off += (size_t)B_ * KC_ * VC_ * 4;
  ushort_t* Mbuf= (ushort_t*)(w8 + off); off += (size_t)B_ * C_ * KC_ * 2;
  float* mean1  = (float*)(w8 + off);    off += (size_t)B_ * N_ * 4;
  float* rstd1  = (float*)(w8 + off);    off += (size_t)B_ * N_ * 4;
  ushort_t* wk1p = (ushort_t*)(w8 + off); off += 3 * KC_ * C_ * 2;
  ushort_t* wk2p = (ushort_t*)(w8 + off); off += 3 * KC_ * C_ * 2;
  ushort_t* wq1p = (ushort_t*)(w8 + off); off += 3 * KC_ * C_ * 2;
  ushort_t* wq2p = (ushort_t*)(w8 + off); off += 3 * KC_ * C_ * 2;
  ushort_t* wvp  = (ushort_t*)(w8 + off); off += VC_ * C_ * 2;
  ushort_t* wfc1p= (ushort_t*)(w8 + off); off += HID_ * C_ * 2;
  ushort_t* wfc2p= (ushort_t*)(w8 + off); off += C_ * HID_ * 2;
  float* wdwT    = (float*)(w8 + off);    off += 9 * HID_ * 4;
  ushort_t* zbuf = (ushort_t*)(w8 + off); off += 512;
  float* part    = (float*)(w8 + off);                      // split-K partials, LAST
  size_t need4 = off + (size_t)4 * B_ * KC_ * VC_ * 4;
  size_t need8 = off + (size_t)8 * B_ * KC_ * VC_ * 4;
  int csplit;
  if (ws_size >= need8) csplit = 8;
  else if (ws_size >= need4) csplit = 4;
  else return;

  // LN2 stats reuse mean1/rstd1 (LN1 stats dead after phase 2 q-convs)
  float* mean2 = mean1;
  float* rstd2 = rstd1;

  // FFN-phase overlays (xnt/kq dead by then)
  ushort_t* txn  = xnt;                        // [n][c] per batch, 8.4MB
  ushort_t* h1t  = xnt + (size_t)4194304;      // [n][hid] bf16, 33.5MB
  ushort_t* actT = kq;                         // [n][hid] bf16, 33.5MB

  float* mx_out   = (float*)d_out;
  float* ctx_out  = mx_out + big;
  float* amap_out = ctx_out + (size_t)B_ * KC_ * VC_;
  ushort_t* valB  = (ushort_t*)d_out;    // val bf16 [b][vc][n] in mx region (phase 1)

  dim3 blk(256);

  zero_kernel<<<1, 64, 0, stream>>>(zbuf);
  pack3_kernel<<<KC_ * C_ / 256, blk, 0, stream>>>(wk1, wk1p, KC_ * C_);
  pack3_kernel<<<KC_ * C_ / 256, blk, 0, stream>>>(wk2, wk2p, KC_ * C_);
  pack3_kernel<<<KC_ * C_ / 256, blk, 0, stream>>>(wq1, wq1p, KC_ * C_);
  pack3_kernel<<<KC_ * C_ / 256, blk, 0, stream>>>(wq2, wq2p, KC_ * C_);
  pack1_kernel<<<VC_ * C_ / 256, blk, 0, stream>>>(wv, wvp, VC_ * C_);
  pack1_kernel<<<HID_ * C_ / 256, blk, 0, stream>>>(wfc1, wfc1p, HID_ * C_);
  pack1_kernel<<<C_ * HID_ / 256, blk, 0, stream>>>(wfc2, wfc2p, C_ * HID_);
  packdw_kernel<<<36, blk, 0, stream>>>(wdw, wdwT);

  // LN1 stats + xnt = LN1(x) transposed bf16
  ln_stats<<<B_ * N_ / 256, blk, 0, stream>>>(x, mean1, rstd1);
  lnt_kernel<<<dim3(N_ / 64, C_ / 64, B_), blk, 0, stream>>>(
      x, CN, mean1, rstd1, (long)N_, g1, b1, xnt, NC2);

  // val = wv @ xn + bv  -> bf16 [b][vc][n] in d_out mx region
  mfma_gemm<1, 0, 1, 1><<<dim3(N_ / 128, VC_ / 128, B_), blk, 0, stream>>>(
      wvp, 0, C_, 0, xnt, NC2, C_, bv, nullptr, 0,
      nullptr, valB, (long)VC_ * N_, N_, C_ / 64, zbuf);

  // Phase 1: K path + ctx (val alive in mx region)
  for (int d = 0; d < 2; ++d) {
    const ushort_t* wkp = d ? wk2p : wk1p;
    const float* bk = d ? bk2 : bk1;
    if (d == 0)
      mfma_gemm<3, 1, 1, 1><<<dim3(N_ / 128, KC_ / 128, B_), blk, 0, stream>>>(
          wkp, 0, C_, (long)KC_ * C_, xnt, NC2, C_, bk, nullptr, 0,
          nullptr, kq, (long)KC_ * N_, N_, C_ / 64, zbuf);
    else
      mfma_gemm<3, 2, 1, 1><<<dim3(N_ / 128, KC_ / 128, B_), blk, 0, stream>>>(
          wkp, 0, C_, (long)KC_ * C_, xnt, NC2, C_, bk, nullptr, 0,
          nullptr, kq, (long)KC_ * N_, N_, C_ / 64, zbuf);
    softmax_spatial_bf16<<<B_ * KC_, blk, 0, stream>>>(kq);
    if (d == 0) amap_kernel<true><<<B_ * N_ / 256, blk, 0, stream>>>(kq, amap_out);
    else        amap_kernel<false><<<B_ * N_ / 256, blk, 0, stream>>>(kq, amap_out);
    // ctx: A=key_s [kc][n], B=val [vc][n], K=16384 split-K
    if (csplit == 8)
      mfma_gemm<1, 0, 6, 8><<<dim3(VC_ / 128, KC_ / 128, B_ * 8), blk, 0, stream>>>(
          kq, (long)KC_ * N_, N_, 0, valB, (long)VC_ * N_, N_, nullptr, nullptr, 0,
          part, nullptr, (long)KC_ * VC_, VC_, (N_ / 8) / 64, zbuf);
    else
      mfma_gemm<1, 0, 6, 4><<<dim3(VC_ / 128, KC_ / 128, B_ * 4), blk, 0, stream>>>(
          kq, (long)KC_ * N_, N_, 0, valB, (long)VC_ * N_, N_, nullptr, nullptr, 0,
          part, nullptr, (long)KC_ * VC_, VC_, (N_ / 4) / 64, zbuf);
    ctx_reduce<<<B_ * KC_ * VC_ / 256, blk, 0, stream>>>(part, d ? ctx_out : ctx0, csplit);
  }

  // Phase 2: Q path + attention (val dead; mx region becomes tx)
  for (int d = 0; d < 2; ++d) {
    const ushort_t* wqp = d ? wq2p : wq1p;
    const float* bq = d ? bq2 : bq1;
    if (d == 0)
      mfma_gemm<3, 1, 2, 1><<<dim3(N_ / 128, KC_ / 128, B_), blk, 0, stream>>>(
          wqp, 0, C_, (long)KC_ * C_, xnt, NC2, C_, bq, nullptr, 0,
          nullptr, kq, (long)N_ * KC_, KC_, C_ / 64, zbuf);
    else
      mfma_gemm<3, 2, 2, 1><<<dim3(N_ / 128, KC_ / 128, B_), blk, 0, stream>>>(
          wqp, 0, C_, (long)KC_ * C_, xnt, NC2, C_, bq, nullptr, 0,
          nullptr, kq, (long)N_ * KC_, KC_, C_ / 64, zbuf);
    softmax_channel_t<<<B_ * N_ / 256, blk, 0, stream>>>(kq);
    mk_kernel<<<B_ * C_, blk, 0, stream>>>(wr, d ? ctx_out : ctx0, d, Mbuf);
    if (d == 0)
      mfma_gemm<1, 0, 3, 1><<<dim3(N_ / 128, C_ / 128, B_), blk, 0, stream>>>(
          Mbuf, (long)C_ * KC_, KC_, 0, kq, (long)N_ * KC_, KC_, br, nullptr, 0,
          mx_out, nullptr, CN, N_, KC_ / 64, zbuf);
    else
      mfma_gemm<1, 0, 4, 1><<<dim3(N_ / 128, C_ / 128, B_), blk, 0, stream>>>(
          Mbuf, (long)C_ * KC_, KC_, 0, kq, (long)N_ * KC_, KC_, nullptr, x, CN,
          mx_out, nullptr, CN, N_, KC_ / 64, zbuf);
  }

  // LN2 stats on tx (in mx_out)
  ln_stats<<<B_ * N_ / 256, blk, 0, stream>>>(mx_out, mean2, rstd2);

  // FFN per batch: fc1 -> h1t [n][hid] -> dwgelu_t -> actT [n][hid] -> fc2 += tx
  for (int b = 0; b < B_; ++b) {
    lnt_kernel<<<dim3(N_ / 64, C_ / 64, 1), blk, 0, stream>>>(
        mx_out + (size_t)b * CN, 0, mean2 + (size_t)b * N_, rstd2 + (size_t)b * N_, 0,
        g2, b2, txn, 0);
    mfma_gemm<1, 0, 2, 1><<<dim3(N_ / 128, HID_ / 128, 1), blk, 0, stream>>>(
        wfc1p, 0, C_, 0, txn, 0, C_, bfc1, nullptr, 0,
        nullptr, h1t, 0, HID_, C_ / 64, zbuf);
    dwgelu_t<<<N_ / 2, blk, 0, stream>>>(h1t, wdwT, bdw, actT);
    mfma_gemm<1, 0, 5, 1><<<dim3(N_ / 128, C_ / 128, 1), blk, 0, stream>>>(
        wfc2p, 0, HID_, 0, actT, 0, HID_, bfc2, nullptr, 0,
        mx_out + (size_t)b * CN, nullptr, 0, N_, HID_ / 64, zbuf);
  }
}

// Round 6
// 1808.301 us; speedup vs baseline: 6.9963x; 1.0592x over previous
//
#include <hip/hip_runtime.h>
#include <hip/hip_bf16.h>

#define B_ 8
#define C_ 256
#define H_ 128
#define W_ 128
#define N_ 16384
#define KC_ 256
#define VC_ 256
#define HID_ 1024

typedef unsigned short ushort_t;
typedef __bf16 bf16x8 __attribute__((ext_vector_type(8)));
typedef float f32x4 __attribute__((ext_vector_type(4)));
typedef ushort_t u16x8 __attribute__((ext_vector_type(8)));

static __device__ __forceinline__ ushort_t f2bu(float f) {
  __hip_bfloat16 h = __float2bfloat16(f);
  return *reinterpret_cast<ushort_t*>(&h);
}
static __device__ __forceinline__ float bu2f(ushort_t u) {
  __hip_bfloat16 h;
  *reinterpret_cast<ushort_t*>(&h) = u;
  return __bfloat162float(h);
}

#define GLD16(gp, lp) __builtin_amdgcn_global_load_lds( \
    (const __attribute__((address_space(1))) void*)(gp), \
    (__attribute__((address_space(3))) void*)(lp), 16, 0, 0)

__global__ __launch_bounds__(64) void zero_kernel(ushort_t* p) {
  p[threadIdx.x] = 0;
}

__global__ __launch_bounds__(256) void pack3_kernel(const float* __restrict__ in,
                                                    ushort_t* __restrict__ out, int MC) {
  int idx = blockIdx.x * 256 + threadIdx.x;
  if (idx >= MC) return;
  #pragma unroll
  for (int t = 0; t < 3; ++t) out[t * MC + idx] = f2bu(in[idx * 3 + t]);
}

__global__ __launch_bounds__(256) void pack1_kernel(const float* __restrict__ in,
                                                    ushort_t* __restrict__ out, int n) {
  int idx = blockIdx.x * 256 + threadIdx.x;
  if (idx < n) out[idx] = f2bu(in[idx]);
}

__global__ __launch_bounds__(256) void packdw_kernel(const float* __restrict__ in,
                                                     float* __restrict__ out) {
  int idx = blockIdx.x * 256 + threadIdx.x;
  if (idx < HID_ * 9) {
    int c = idx / 9, t = idx % 9;
    out[t * HID_ + c] = in[idx];
  }
}

// concat two [256] fp32 bias vectors into [512]
__global__ __launch_bounds__(256) void bcat_kernel(const float* __restrict__ a,
                                                   const float* __restrict__ b,
                                                   float* __restrict__ out) {
  int t = threadIdx.x;
  out[t] = a[t];
  out[256 + t] = b[t];
}

// ---------------- fused LN1: x fp32 [c][n] -> bf16 [n][c]
__global__ __launch_bounds__(256) void ln1t_kernel(const float* __restrict__ x,
    const float* __restrict__ g, const float* __restrict__ beta,
    ushort_t* __restrict__ out) {
  __shared__ float T[256][67];
  __shared__ float st[2][4][64];
  __shared__ float mr[64], rs[64];
  int z = blockIdx.z;
  int n0 = blockIdx.x * 64;
  int t = threadIdx.x;
  const float* xb = x + (size_t)z * C_ * N_;
  #pragma unroll
  for (int j = 0; j < 16; ++j) {
    int e = (j * 256 + t) * 4;
    int c = e >> 6, n = e & 63;
    float4 v = *(const float4*)&xb[(size_t)c * N_ + n0 + n];
    T[c][n] = v.x; T[c][n + 1] = v.y; T[c][n + 2] = v.z; T[c][n + 3] = v.w;
  }
  __syncthreads();
  {
    int n = t & 63, part = t >> 6;
    float s1 = 0.f, s2 = 0.f;
    for (int c = part * 64; c < part * 64 + 64; ++c) { float v = T[c][n]; s1 += v; s2 += v * v; }
    st[0][part][n] = s1; st[1][part][n] = s2;
  }
  __syncthreads();
  if (t < 64) {
    float s1 = st[0][0][t] + st[0][1][t] + st[0][2][t] + st[0][3][t];
    float s2 = st[1][0][t] + st[1][1][t] + st[1][2][t] + st[1][3][t];
    float m = s1 * (1.f / C_);
    float v = s2 * (1.f / C_) - m * m;
    mr[t] = m; rs[t] = rsqrtf(v + 1e-5f);
  }
  __syncthreads();
  {
    int n = t >> 2, cc = (t & 3) * 64;
    float m = mr[n], r = rs[n];
    ushort_t* po = out + (size_t)z * N_ * C_ + (size_t)(n0 + n) * C_ + cc;
    #pragma unroll
    for (int j0 = 0; j0 < 64; j0 += 8) {
      u16x8 o;
      #pragma unroll
      for (int j = 0; j < 8; ++j) {
        int c = cc + j0 + j;
        o[j] = f2bu((T[c][n] - m) * r * g[c] + beta[c]);
      }
      *(u16x8*)(po + j0) = o;
    }
  }
}

// ---------------- fused LN2: tx bf16 [c][n] -> bf16 [n][c]
__global__ __launch_bounds__(256) void ln2t_kernel(const ushort_t* __restrict__ x,
    const float* __restrict__ g, const float* __restrict__ beta,
    ushort_t* __restrict__ out) {
  __shared__ ushort_t T[256][72];
  __shared__ float st[2][4][64];
  __shared__ float mr[64], rs[64];
  int z = blockIdx.z;
  int n0 = blockIdx.x * 64;
  int t = threadIdx.x;
  const ushort_t* xb = x + (size_t)z * C_ * N_;
  #pragma unroll
  for (int j = 0; j < 8; ++j) {
    int e = (j * 256 + t) * 8;
    int c = e >> 6, n = e & 63;
    *(u16x8*)&T[c][n] = *(const u16x8*)&xb[(size_t)c * N_ + n0 + n];
  }
  __syncthreads();
  {
    int n = t & 63, part = t >> 6;
    float s1 = 0.f, s2 = 0.f;
    for (int c = part * 64; c < part * 64 + 64; ++c) { float v = bu2f(T[c][n]); s1 += v; s2 += v * v; }
    st[0][part][n] = s1; st[1][part][n] = s2;
  }
  __syncthreads();
  if (t < 64) {
    float s1 = st[0][0][t] + st[0][1][t] + st[0][2][t] + st[0][3][t];
    float s2 = st[1][0][t] + st[1][1][t] + st[1][2][t] + st[1][3][t];
    float m = s1 * (1.f / C_);
    float v = s2 * (1.f / C_) - m * m;
    mr[t] = m; rs[t] = rsqrtf(v + 1e-5f);
  }
  __syncthreads();
  {
    int n = t >> 2, cc = (t & 3) * 64;
    float m = mr[n], r = rs[n];
    ushort_t* po = out + (size_t)z * N_ * C_ + (size_t)(n0 + n) * C_ + cc;
    #pragma unroll
    for (int j0 = 0; j0 < 64; j0 += 8) {
      u16x8 o;
      #pragma unroll
      for (int j = 0; j < 8; ++j) {
        int c = cc + j0 + j;
        o[j] = f2bu((bu2f(T[c][n]) - m) * r * g[c] + beta[c]);
      }
      *(u16x8*)(po + j0) = o;
    }
  }
}

// ======================= MFMA GEMM template (see round-6 notes) =======================
template<int TAPS, int DIMSEL, int OMODE, int SPLIT, bool BDUAL>
__global__ __launch_bounds__(256) void mfma_gemm(
    const ushort_t* __restrict__ A, long Abatch, int lda, long Aplane, long Adirstride,
    const ushort_t* __restrict__ B, const ushort_t* __restrict__ B2, long Bbatch, int ldb,
    const float* __restrict__ bias,
    const float* __restrict__ resF, const ushort_t* __restrict__ resB, long Resbatch,
    float* __restrict__ outF, ushort_t* __restrict__ outB, ushort_t* __restrict__ outB2,
    long Outbatch, int ldo, int Ksteps, const ushort_t* __restrict__ zbuf) {
  __shared__ ushort_t sm[17408];
  int tid = threadIdx.x;
  int bx = blockIdx.x, by = blockIdx.y, bz = blockIdx.z;
  if (gridDim.x == 128) bx = ((bx & 7) << 4) | (bx >> 3);
  int b = bz / SPLIT, sK = bz % SPLIT;
  long koff = (long)sK * Ksteps * 64;
  int dsel = (DIMSEL == 3) ? (by < 2 ? 1 : 2) : DIMSEL;
  int m0 = (DIMSEL == 3) ? ((by & 1) * 128) : (by * 128);
  int bofs = (DIMSEL == 3) ? ((by >> 1) * 256) : 0;   // bias offset for fused dual-dir
  const ushort_t* Ab = A + (size_t)b * Abatch + koff + ((DIMSEL == 3) ? (long)(by >> 1) * Adirstride : 0L);
  const ushort_t* Bb = B + (size_t)b * Bbatch + (BDUAL ? 0 : koff);
  const ushort_t* B2b = BDUAL ? (B2 + (size_t)b * Bbatch) : nullptr;
  int n0 = bx * 128;
  int lane = tid & 63, wid = tid >> 6, wm = wid >> 1, wn = wid & 1;

  f32x4 acc[4][4];
  #pragma unroll
  for (int i = 0; i < 4; i++)
    #pragma unroll
    for (int j = 0; j < 4; j++) acc[i][j] = (f32x4)0.f;

  for (int t = 0; t < TAPS; ++t) {
    if (TAPS == 3 && dsel == 2) {
      if ((bx == 0 && t == 0) || (bx == H_ - 1 && t == 2)) continue;
    }
    const ushort_t* At = Ab + (long)t * Aplane;
    for (int ks = 0; ks < Ksteps; ++ks) {
      int k0 = ks * 64;
      #pragma unroll
      for (int i = 0; i < 4; i++) {
        int s = tid + i * 256;
        int row = s >> 3, pc = s & 7;
        int lc = pc ^ (row & 7);
        const ushort_t* g = At + (long)(m0 + row) * lda + k0 + lc * 8;
        GLD16(g, &sm[s * 8]);
      }
      #pragma unroll
      for (int i = 0; i < 4; i++) {
        int s = tid + i * 256;
        int row = s >> 3, pc = s & 7;
        int lc = pc ^ (row & 7);
        const ushort_t* g;
        if (BDUAL) {
          const ushort_t* Bsel = (ks < Ksteps / 2) ? Bb : B2b;
          int kb = ((ks < Ksteps / 2) ? ks : ks - Ksteps / 2) * 64;
          g = Bsel + (long)(n0 + row) * ldb + kb + lc * 8;
        } else if (TAPS == 3 && dsel == 1) {
          int wpos = row + (t - 1);
          if (0 <= wpos && wpos < W_)
            g = Bb + (long)(n0 + row + (t - 1)) * ldb + k0 + lc * 8;
          else
            g = zbuf;
        } else if (TAPS == 3 && dsel == 2) {
          g = Bb + (long)(n0 + row + (t - 1) * W_) * ldb + k0 + lc * 8;
        } else {
          g = Bb + (long)(n0 + row) * ldb + k0 + lc * 8;
        }
        GLD16(g, &sm[8192 + s * 8]);
      }
      __syncthreads();
      #pragma unroll
      for (int kk = 0; kk < 2; kk++) {
        bf16x8 av[4], bv[4];
        int r16 = lane & 15;
        int sl = (lane >> 4) + kk * 4;
        #pragma unroll
        for (int fm = 0; fm < 4; fm++) {
          int row = wm * 64 + fm * 16 + r16;
          av[fm] = *(const bf16x8*)&sm[row * 64 + ((sl ^ (row & 7)) * 8)];
        }
        #pragma unroll
        for (int fn = 0; fn < 4; fn++) {
          int row = wn * 64 + fn * 16 + r16;
          bv[fn] = *(const bf16x8*)&sm[8192 + row * 64 + ((sl ^ (row & 7)) * 8)];
        }
        #pragma unroll
        for (int fm = 0; fm < 4; fm++)
          #pragma unroll
          for (int fn = 0; fn < 4; fn++)
            acc[fm][fn] = __builtin_amdgcn_mfma_f32_16x16x32_bf16(av[fm], bv[fn], acc[fm][fn], 0, 0, 0);
      }
      __syncthreads();
    }
  }

  int r16 = lane & 15, rq = lane >> 4;
  if (OMODE == 1 || OMODE == 2 || OMODE == 7) {
    ushort_t* obase = (DIMSEL == 3 && blockIdx.y >= 2) ? outB2 : outB;
    ushort_t* ob = obase + (size_t)bz * Outbatch;
    #pragma unroll
    for (int fm = 0; fm < 4; fm++) {
      #pragma unroll
      for (int fn = 0; fn < 4; fn++) {
        int lm = wm * 64 + fm * 16 + rq * 4;
        int ln = wn * 64 + fn * 16 + r16;
        f32x4 a = acc[fm][fn];
        if (OMODE == 2) {
          #pragma unroll
          for (int r = 0; r < 4; r++)
            sm[ln * 136 + lm + r] = f2bu(a[r] + bias[bofs + m0 + lm + r]);
        } else {
          #pragma unroll
          for (int r = 0; r < 4; r++)
            sm[(lm + r) * 136 + ln] = f2bu(a[r] + bias[bofs + m0 + lm + r]);
        }
      }
    }
    __syncthreads();
    int row = tid >> 1, half = (tid & 1) * 64;
    const ushort_t* src = &sm[row * 136 + half];
    if (OMODE == 7) {
      const float* xb = resF + (size_t)bz * Resbatch + (size_t)(m0 + row) * ldo + n0 + half;
      ushort_t* dst = &ob[(size_t)(m0 + row) * ldo + n0 + half];
      #pragma unroll
      for (int j = 0; j < 8; j++) {
        u16x8 v = *(const u16x8*)(src + j * 8);
        float4 x0 = *(const float4*)(xb + j * 8);
        float4 x1 = *(const float4*)(xb + j * 8 + 4);
        u16x8 o;
        o[0] = f2bu(bu2f(v[0]) + x0.x); o[1] = f2bu(bu2f(v[1]) + x0.y);
        o[2] = f2bu(bu2f(v[2]) + x0.z); o[3] = f2bu(bu2f(v[3]) + x0.w);
        o[4] = f2bu(bu2f(v[4]) + x1.x); o[5] = f2bu(bu2f(v[5]) + x1.y);
        o[6] = f2bu(bu2f(v[6]) + x1.z); o[7] = f2bu(bu2f(v[7]) + x1.w);
        *(u16x8*)(dst + j * 8) = o;
      }
    } else {
      ushort_t* dst;
      if (OMODE == 1) dst = &ob[(size_t)(m0 + row) * ldo + n0 + half];
      else            dst = &ob[(size_t)(n0 + row) * ldo + m0 + half];
      #pragma unroll
      for (int j = 0; j < 8; j++)
        *(u16x8*)(dst + j * 8) = *(const u16x8*)(src + j * 8);
    }
  } else {
    #pragma unroll
    for (int fm = 0; fm < 4; fm++) {
      #pragma unroll
      for (int fn = 0; fn < 4; fn++) {
        int mrow = m0 + wm * 64 + fm * 16 + rq * 4;
        int ncol = n0 + wn * 64 + fn * 16 + r16;
        f32x4 a = acc[fm][fn];
        if (OMODE == 6) {
          float* of = outF + (size_t)bz * Outbatch;
          #pragma unroll
          for (int r = 0; r < 4; r++)
            of[(size_t)(mrow + r) * ldo + ncol] = a[r];
        } else if (OMODE == 8) {
          float* of = outF + (size_t)bz * Outbatch;
          const ushort_t* rp = resB + (size_t)bz * Resbatch;
          #pragma unroll
          for (int r = 0; r < 4; r++) {
            size_t o = (size_t)(mrow + r) * ldo + ncol;
            of[o] = a[r] + bias[mrow + r] + bu2f(rp[o]);
          }
        }
      }
    }
  }
}

__global__ __launch_bounds__(256) void softmax_spatial2(ushort_t* __restrict__ p0,
                                                        ushort_t* __restrict__ p1) {
  int r = blockIdx.x;
  ushort_t* p = (r < B_ * KC_) ? (p0 + (size_t)r * N_) : (p1 + (size_t)(r - B_ * KC_) * N_);
  int tid = threadIdx.x;
  __shared__ float red[256];
  float mx = -1e30f;
  for (int i = tid * 8; i < N_; i += 2048) {
    u16x8 v = *(const u16x8*)&p[i];
    #pragma unroll
    for (int j = 0; j < 8; j++) mx = fmaxf(mx, bu2f(v[j]));
  }
  red[tid] = mx; __syncthreads();
  for (int s = 128; s > 0; s >>= 1) { if (tid < s) red[tid] = fmaxf(red[tid], red[tid + s]); __syncthreads(); }
  mx = red[0]; __syncthreads();
  float sum = 0.f;
  for (int i = tid * 8; i < N_; i += 2048) {
    u16x8 v = *(const u16x8*)&p[i];
    #pragma unroll
    for (int j = 0; j < 8; j++) sum += __expf(bu2f(v[j]) - mx);
  }
  red[tid] = sum; __syncthreads();
  for (int s = 128; s > 0; s >>= 1) { if (tid < s) red[tid] += red[tid + s]; __syncthreads(); }
  float inv = 1.f / red[0];
  for (int i = tid * 8; i < N_; i += 2048) {
    u16x8 v = *(const u16x8*)&p[i];
    u16x8 o;
    #pragma unroll
    for (int j = 0; j < 8; j++) o[j] = f2bu(__expf(bu2f(v[j]) - mx) * inv);
    *(u16x8*)&p[i] = o;
  }
}

__global__ __launch_bounds__(256) void softmax_channel2(ushort_t* __restrict__ p0,
                                                        ushort_t* __restrict__ p1) {
  size_t idx = (size_t)blockIdx.x * 256 + threadIdx.x;
  ushort_t* q = (idx < (size_t)B_ * N_) ? (p0 + idx * KC_)
                                        : (p1 + (idx - (size_t)B_ * N_) * KC_);
  float mx = -1e30f;
  for (int i = 0; i < KC_; i += 8) {
    u16x8 v = *(const u16x8*)&q[i];
    #pragma unroll
    for (int j = 0; j < 8; j++) mx = fmaxf(mx, bu2f(v[j]));
  }
  float sum = 0.f;
  for (int i = 0; i < KC_; i += 8) {
    u16x8 v = *(const u16x8*)&q[i];
    #pragma unroll
    for (int j = 0; j < 8; j++) sum += __expf(bu2f(v[j]) - mx);
  }
  float inv = 1.f / sum;
  for (int i = 0; i < KC_; i += 8) {
    u16x8 v = *(const u16x8*)&q[i];
    u16x8 o;
    #pragma unroll
    for (int j = 0; j < 8; j++) o[j] = f2bu(__expf(bu2f(v[j]) - mx) * inv);
    *(u16x8*)&q[i] = o;
  }
}

__global__ __launch_bounds__(256) void amap2_kernel(const ushort_t* __restrict__ k0,
    const ushort_t* __restrict__ k1, float* __restrict__ amap) {
  int idx = blockIdx.x * 256 + threadIdx.x;
  int b = idx >> 14;
  int n = idx & 16383;
  const ushort_t* p0 = k0 + (size_t)b * KC_ * N_ + n;
  const ushort_t* p1 = k1 + (size_t)b * KC_ * N_ + n;
  float s = 0.f;
  for (int c = 0; c < KC_; c++) s += bu2f(p0[(size_t)c * N_]) + bu2f(p1[(size_t)c * N_]);
  amap[idx] = s * (1.f / (2.f * KC_));
}

__global__ __launch_bounds__(256) void ctx_reduce(const float* __restrict__ part,
                                                  float* __restrict__ out, int split) {
  int idx = blockIdx.x * 256 + threadIdx.x;
  int b = idx >> 16;
  int r = idx & 65535;
  float s = 0.f;
  for (int k = 0; k < split; k++)
    s += part[((size_t)(b * split + k)) * KC_ * VC_ + r];
  out[idx] = s;
}

__global__ __launch_bounds__(256) void mk2_kernel(const float* __restrict__ wr,
    const float* __restrict__ ctx0, const float* __restrict__ ctx1,
    ushort_t* __restrict__ Mout) {
  int b = blockIdx.x >> 8;
  int c = blockIdx.x & 255;
  int kc = threadIdx.x;
  __shared__ float wlo[256], whi[256];
  wlo[kc] = wr[(size_t)c * 512 + kc];
  whi[kc] = wr[(size_t)c * 512 + 256 + kc];
  __syncthreads();
  const float* c0 = ctx0 + (size_t)b * 65536 + (size_t)kc * 256;
  const float* c1 = ctx1 + (size_t)b * 65536 + (size_t)kc * 256;
  float s0 = 0.f, s1 = 0.f;
  for (int v = 0; v < 256; ++v) { s0 += wlo[v] * c0[v]; s1 += whi[v] * c1[v]; }
  ushort_t* mo = Mout + (size_t)b * C_ * 512 + (size_t)c * 512;
  mo[kc] = f2bu(s0);
  mo[256 + kc] = f2bu(s1);
}

__global__ __launch_bounds__(256) void dwgelu_t(const ushort_t* __restrict__ h1t,
    const float* __restrict__ wdwT, const float* __restrict__ bdw,
    ushort_t* __restrict__ actT) {
  int pix = blockIdx.x * 2 + (threadIdx.x >> 7);
  int c = (threadIdx.x & 127) * 8;
  int h = pix >> 7, w = pix & 127;
  float s[8];
  {
    float4 b0 = *(const float4*)&bdw[c];
    float4 b1 = *(const float4*)&bdw[c + 4];
    s[0]=b0.x; s[1]=b0.y; s[2]=b0.z; s[3]=b0.w;
    s[4]=b1.x; s[5]=b1.y; s[6]=b1.z; s[7]=b1.w;
  }
  #pragma unroll
  for (int di = -1; di <= 1; ++di) {
    int h2 = h + di;
    if ((unsigned)h2 >= H_) continue;
    #pragma unroll
    for (int dj = -1; dj <= 1; ++dj) {
      int w2 = w + dj;
      if ((unsigned)w2 >= W_) continue;
      int tap = (di + 1) * 3 + (dj + 1);
      u16x8 v = *(const u16x8*)&h1t[(size_t)(h2 * W_ + w2) * HID_ + c];
      const float* wp = &wdwT[tap * HID_ + c];
      float4 w0 = *(const float4*)wp, w1 = *(const float4*)(wp + 4);
      s[0] += w0.x * bu2f(v[0]); s[1] += w0.y * bu2f(v[1]);
      s[2] += w0.z * bu2f(v[2]); s[3] += w0.w * bu2f(v[3]);
      s[4] += w1.x * bu2f(v[4]); s[5] += w1.y * bu2f(v[5]);
      s[6] += w1.z * bu2f(v[6]); s[7] += w1.w * bu2f(v[7]);
    }
  }
  u16x8 o;
  #pragma unroll
  for (int j = 0; j < 8; j++) {
    float gl = 0.5f * s[j] * (1.f + erff(s[j] * 0.70710678118654752f));
    o[j] = f2bu(gl);
  }
  *(u16x8*)&actT[(size_t)pix * HID_ + c] = o;
}

extern "C" void kernel_launch(void* const* d_in, const int* in_sizes, int n_in,
                              void* d_out, int out_size, void* d_ws, size_t ws_size,
                              hipStream_t stream) {
  const float* x    = (const float*)d_in[0];
  const float* wk1  = (const float*)d_in[3];
  const float* bk1  = (const float*)d_in[4];
  const float* wk2  = (const float*)d_in[5];
  const float* bk2  = (const float*)d_in[6];
  const float* wq1  = (const float*)d_in[7];
  const float* bq1  = (const float*)d_in[8];
  const float* wq2  = (const float*)d_in[9];
  const float* bq2  = (const float*)d_in[10];
  const float* wv   = (const float*)d_in[11];
  const float* bv   = (const float*)d_in[12];
  const float* wr   = (const float*)d_in[13];
  const float* br   = (const float*)d_in[14];
  const float* g1   = (const float*)d_in[15];
  const float* b1   = (const float*)d_in[16];
  const float* g2   = (const float*)d_in[17];
  const float* b2   = (const float*)d_in[18];
  const float* wfc1 = (const float*)d_in[19];
  const float* bfc1 = (const float*)d_in[20];
  const float* wdw  = (const float*)d_in[21];
  const float* bdw  = (const float*)d_in[22];
  const float* wfc2 = (const float*)d_in[23];
  const float* bfc2 = (const float*)d_in[24];

  const size_t big = (size_t)B_ * C_ * N_;
  const long  CN  = (long)C_ * N_;
  const long  NC2 = (long)N_ * C_;

  uint8_t* w8 = (uint8_t*)d_ws;
  size_t off = 0;
  ushort_t* xnt = (ushort_t*)(w8 + off); off += 67108864;
  ushort_t* kq  = (ushort_t*)(w8 + off); off += 67108864;
  float*  ctx0  = (float*)(w8 + off);    off += (size_t)B_ * KC_ * VC_ * 4;
  ushort_t* Mbuf= (ushort_t*)(w8 + off); off += (size_t)B_ * C_ * 512 * 2;
  ushort_t* wkkp = (ushort_t*)(w8 + off); off += 6 * KC_ * C_ * 2;
  ushort_t* wqqp = (ushort_t*)(w8 + off); off += 6 * KC_ * C_ * 2;
  ushort_t* wvp  = (ushort_t*)(w8 + off); off += VC_ * C_ * 2;
  ushort_t* wfc1p= (ushort_t*)(w8 + off); off += HID_ * C_ * 2;
  ushort_t* wfc2p= (ushort_t*)(w8 + off); off += C_ * HID_ * 2;
  float* wdwT    = (float*)(w8 + off);    off += 9 * HID_ * 4;
  float* bK      = (float*)(w8 + off);    off += 512 * 4;
  float* bQ      = (float*)(w8 + off);    off += 512 * 4;
  ushort_t* zbuf = (ushort_t*)(w8 + off); off += 512;
  float* part    = (float*)(w8 + off);
  size_t need4 = off + (size_t)4 * B_ * KC_ * VC_ * 4;
  size_t need8 = off + (size_t)8 * B_ * KC_ * VC_ * 4;
  int csplit;
  if (ws_size >= need8) csplit = 8;
  else if (ws_size >= need4) csplit = 4;
  else return;

  float* mx_out   = (float*)d_out;
  float* ctx_out  = mx_out + big;
  float* amap_out = ctx_out + (size_t)B_ * KC_ * VC_;

  ushort_t* mxlo = (ushort_t*)d_out;            // val -> q1
  ushort_t* mxhi = (ushort_t*)d_out + big;      // K1 -> tx

  ushort_t* txn  = xnt;
  ushort_t* h1t  = kq;
  ushort_t* actT = kq + (size_t)N_ * HID_;

  dim3 blk(256);

  zero_kernel<<<1, 64, 0, stream>>>(zbuf);
  pack3_kernel<<<KC_ * C_ / 256, blk, 0, stream>>>(wk1, wkkp, KC_ * C_);
  pack3_kernel<<<KC_ * C_ / 256, blk, 0, stream>>>(wk2, wkkp + 3 * KC_ * C_, KC_ * C_);
  pack3_kernel<<<KC_ * C_ / 256, blk, 0, stream>>>(wq1, wqqp, KC_ * C_);
  pack3_kernel<<<KC_ * C_ / 256, blk, 0, stream>>>(wq2, wqqp + 3 * KC_ * C_, KC_ * C_);
  pack1_kernel<<<VC_ * C_ / 256, blk, 0, stream>>>(wv, wvp, VC_ * C_);
  pack1_kernel<<<HID_ * C_ / 256, blk, 0, stream>>>(wfc1, wfc1p, HID_ * C_);
  pack1_kernel<<<C_ * HID_ / 256, blk, 0, stream>>>(wfc2, wfc2p, C_ * HID_);
  packdw_kernel<<<36, blk, 0, stream>>>(wdw, wdwT);
  bcat_kernel<<<1, blk, 0, stream>>>(bk1, bk2, bK);
  bcat_kernel<<<1, blk, 0, stream>>>(bq1, bq2, bQ);

  // LN1 fused
  ln1t_kernel<<<dim3(N_ / 64, 1, B_), blk, 0, stream>>>(x, g1, b1, xnt);

  // val -> mxlo
  mfma_gemm<1, 0, 1, 1, false><<<dim3(N_ / 128, VC_ / 128, B_), blk, 0, stream>>>(
      wvp, 0, C_, 0, 0, xnt, nullptr, NC2, C_, bv, nullptr, nullptr, 0,
      nullptr, mxlo, nullptr, (long)VC_ * N_, N_, C_ / 64, zbuf);

  // fused KK: K0 -> kq, K1 -> mxhi
  mfma_gemm<3, 3, 1, 1, false><<<dim3(N_ / 128, 4, B_), blk, 0, stream>>>(
      wkkp, 0, C_, (long)KC_ * C_, (long)3 * KC_ * C_, xnt, nullptr, NC2, C_,
      bK, nullptr, nullptr, 0,
      nullptr, kq, mxhi, (long)KC_ * N_, N_, C_ / 64, zbuf);

  softmax_spatial2<<<2 * B_ * KC_, blk, 0, stream>>>(kq, mxhi);
  amap2_kernel<<<B_ * N_ / 256, blk, 0, stream>>>(kq, mxhi, amap_out);

  for (int d = 0; d < 2; ++d) {
    const ushort_t* Ksrc = d ? mxhi : kq;
    if (csplit == 8)
      mfma_gemm<1, 0, 6, 8, false><<<dim3(VC_ / 128, KC_ / 128, B_ * 8), blk, 0, stream>>>(
          Ksrc, (long)KC_ * N_, N_, 0, 0, mxlo, nullptr, (long)VC_ * N_, N_,
          nullptr, nullptr, nullptr, 0,
          part, nullptr, nullptr, (long)KC_ * VC_, VC_, (N_ / 8) / 64, zbuf);
    else
      mfma_gemm<1, 0, 6, 4, false><<<dim3(VC_ / 128, KC_ / 128, B_ * 4), blk, 0, stream>>>(
          Ksrc, (long)KC_ * N_, N_, 0, 0, mxlo, nullptr, (long)VC_ * N_, N_,
          nullptr, nullptr, nullptr, 0,
          part, nullptr, nullptr, (long)KC_ * VC_, VC_, (N_ / 4) / 64, zbuf);
    ctx_reduce<<<B_ * KC_ * VC_ / 256, blk, 0, stream>>>(part, d ? ctx_out : ctx0, csplit);
  }

  // fused QQ: q0 -> kq [n][kc], q1 -> mxlo
  mfma_gemm<3, 3, 2, 1, false><<<dim3(N_ / 128, 4, B_), blk, 0, stream>>>(
      wqqp, 0, C_, (long)KC_ * C_, (long)3 * KC_ * C_, xnt, nullptr, NC2, C_,
      bQ, nullptr, nullptr, 0,
      nullptr, kq, mxlo, (long)N_ * KC_, KC_, C_ / 64, zbuf);

  softmax_channel2<<<2 * B_ * N_ / 256, blk, 0, stream>>>(kq, mxlo);

  mk2_kernel<<<B_ * C_, blk, 0, stream>>>(wr, ctx0, ctx_out, Mbuf);

  // fused attention -> tx bf16 @ mxhi
  mfma_gemm<1, 0, 7, 1, true><<<dim3(N_ / 128, C_ / 128, B_), blk, 0, stream>>>(
      Mbuf, (long)C_ * 512, 512, 0, 0, kq, mxlo, (long)N_ * KC_, KC_,
      br, x, nullptr, CN,
      nullptr, mxhi, nullptr, CN, N_, 8, zbuf);

  // LN2 fused: tx -> txn
  ln2t_kernel<<<dim3(N_ / 64, 1, B_), blk, 0, stream>>>(mxhi, g2, b2, txn);

  // preserve tx batch 7 (fc2 b7 writes clobber it)
  hipMemcpyAsync(part, mxhi + (size_t)7 * CN, (size_t)CN * 2,
                 hipMemcpyDeviceToDevice, stream);

  for (int b = 0; b < B_; ++b) {
    mfma_gemm<1, 0, 2, 1, false><<<dim3(N_ / 128, HID_ / 128, 1), blk, 0, stream>>>(
        wfc1p, 0, C_, 0, 0, txn + (size_t)b * NC2, nullptr, 0, C_,
        bfc1, nullptr, nullptr, 0,
        nullptr, h1t, nullptr, 0, HID_, C_ / 64, zbuf);
    dwgelu_t<<<N_ / 2, blk, 0, stream>>>(h1t, wdwT, bdw, actT);
    const ushort_t* txb = (b == 7) ? (const ushort_t*)part : (mxhi + (size_t)b * CN);
    mfma_gemm<1, 0, 8, 1, false><<<dim3(N_ / 128, C_ / 128, 1), blk, 0, stream>>>(
        wfc2p, 0, HID_, 0, 0, actT, nullptr, 0, HID_,
        bfc2, nullptr, txb, 0,
        mx_out + (size_t)b * CN, nullptr, nullptr, 0, N_, HID_ / 64, zbuf);
  }
}

// Round 7
// 1632.866 us; speedup vs baseline: 7.7480x; 1.1074x over previous
//
#include <hip/hip_runtime.h>
#include <hip/hip_bf16.h>

#define B_ 8
#define C_ 256
#define H_ 128
#define W_ 128
#define N_ 16384
#define KC_ 256
#define VC_ 256
#define HID_ 1024

typedef unsigned short ushort_t;
typedef __bf16 bf16x8 __attribute__((ext_vector_type(8)));
typedef float f32x4 __attribute__((ext_vector_type(4)));
typedef ushort_t u16x8 __attribute__((ext_vector_type(8)));

static __device__ __forceinline__ ushort_t f2bu(float f) {
  __hip_bfloat16 h = __float2bfloat16(f);
  return *reinterpret_cast<ushort_t*>(&h);
}
static __device__ __forceinline__ float bu2f(ushort_t u) {
  __hip_bfloat16 h;
  *reinterpret_cast<ushort_t*>(&h) = u;
  return __bfloat162float(h);
}

#define GLD16(gp, lp) __builtin_amdgcn_global_load_lds( \
    (const __attribute__((address_space(1))) void*)(gp), \
    (__attribute__((address_space(3))) void*)(lp), 16, 0, 0)

__global__ __launch_bounds__(64) void zero_kernel(ushort_t* p) {
  p[threadIdx.x] = 0;
}

__global__ __launch_bounds__(256) void pack3_kernel(const float* __restrict__ in,
                                                    ushort_t* __restrict__ out, int MC) {
  int idx = blockIdx.x * 256 + threadIdx.x;
  if (idx >= MC) return;
  #pragma unroll
  for (int t = 0; t < 3; ++t) out[t * MC + idx] = f2bu(in[idx * 3 + t]);
}

__global__ __launch_bounds__(256) void pack1_kernel(const float* __restrict__ in,
                                                    ushort_t* __restrict__ out, int n) {
  int idx = blockIdx.x * 256 + threadIdx.x;
  if (idx < n) out[idx] = f2bu(in[idx]);
}

__global__ __launch_bounds__(256) void packdw_kernel(const float* __restrict__ in,
                                                     float* __restrict__ out) {
  int idx = blockIdx.x * 256 + threadIdx.x;
  if (idx < HID_ * 9) {
    int c = idx / 9, t = idx % 9;
    out[t * HID_ + c] = in[idx];
  }
}

__global__ __launch_bounds__(256) void bcat_kernel(const float* __restrict__ a,
                                                   const float* __restrict__ b,
                                                   float* __restrict__ out) {
  int t = threadIdx.x;
  out[t] = a[t];
  out[256 + t] = b[t];
}

// ---------------- fused LN1: x fp32 [c][n] -> bf16 [n][c]
__global__ __launch_bounds__(256) void ln1t_kernel(const float* __restrict__ x,
    const float* __restrict__ g, const float* __restrict__ beta,
    ushort_t* __restrict__ out) {
  __shared__ float T[256][67];
  __shared__ float st[2][4][64];
  __shared__ float mr[64], rs[64];
  int z = blockIdx.z;
  int n0 = blockIdx.x * 64;
  int t = threadIdx.x;
  const float* xb = x + (size_t)z * C_ * N_;
  #pragma unroll
  for (int j = 0; j < 16; ++j) {
    int e = (j * 256 + t) * 4;
    int c = e >> 6, n = e & 63;
    float4 v = *(const float4*)&xb[(size_t)c * N_ + n0 + n];
    T[c][n] = v.x; T[c][n + 1] = v.y; T[c][n + 2] = v.z; T[c][n + 3] = v.w;
  }
  __syncthreads();
  {
    int n = t & 63, part = t >> 6;
    float s1 = 0.f, s2 = 0.f;
    for (int c = part * 64; c < part * 64 + 64; ++c) { float v = T[c][n]; s1 += v; s2 += v * v; }
    st[0][part][n] = s1; st[1][part][n] = s2;
  }
  __syncthreads();
  if (t < 64) {
    float s1 = st[0][0][t] + st[0][1][t] + st[0][2][t] + st[0][3][t];
    float s2 = st[1][0][t] + st[1][1][t] + st[1][2][t] + st[1][3][t];
    float m = s1 * (1.f / C_);
    float v = s2 * (1.f / C_) - m * m;
    mr[t] = m; rs[t] = rsqrtf(v + 1e-5f);
  }
  __syncthreads();
  {
    int n = t >> 2, cc = (t & 3) * 64;
    float m = mr[n], r = rs[n];
    ushort_t* po = out + (size_t)z * N_ * C_ + (size_t)(n0 + n) * C_ + cc;
    #pragma unroll
    for (int j0 = 0; j0 < 64; j0 += 8) {
      u16x8 o;
      #pragma unroll
      for (int j = 0; j < 8; ++j) {
        int c = cc + j0 + j;
        o[j] = f2bu((T[c][n] - m) * r * g[c] + beta[c]);
      }
      *(u16x8*)(po + j0) = o;
    }
  }
}

// ---------------- fused LN2: tx bf16 [c][n] -> bf16 [n][c]
__global__ __launch_bounds__(256) void ln2t_kernel(const ushort_t* __restrict__ x,
    const float* __restrict__ g, const float* __restrict__ beta,
    ushort_t* __restrict__ out) {
  __shared__ ushort_t T[256][72];
  __shared__ float st[2][4][64];
  __shared__ float mr[64], rs[64];
  int z = blockIdx.z;
  int n0 = blockIdx.x * 64;
  int t = threadIdx.x;
  const ushort_t* xb = x + (size_t)z * C_ * N_;
  #pragma unroll
  for (int j = 0; j < 8; ++j) {
    int e = (j * 256 + t) * 8;
    int c = e >> 6, n = e & 63;
    *(u16x8*)&T[c][n] = *(const u16x8*)&xb[(size_t)c * N_ + n0 + n];
  }
  __syncthreads();
  {
    int n = t & 63, part = t >> 6;
    float s1 = 0.f, s2 = 0.f;
    for (int c = part * 64; c < part * 64 + 64; ++c) { float v = bu2f(T[c][n]); s1 += v; s2 += v * v; }
    st[0][part][n] = s1; st[1][part][n] = s2;
  }
  __syncthreads();
  if (t < 64) {
    float s1 = st[0][0][t] + st[0][1][t] + st[0][2][t] + st[0][3][t];
    float s2 = st[1][0][t] + st[1][1][t] + st[1][2][t] + st[1][3][t];
    float m = s1 * (1.f / C_);
    float v = s2 * (1.f / C_) - m * m;
    mr[t] = m; rs[t] = rsqrtf(v + 1e-5f);
  }
  __syncthreads();
  {
    int n = t >> 2, cc = (t & 3) * 64;
    float m = mr[n], r = rs[n];
    ushort_t* po = out + (size_t)z * N_ * C_ + (size_t)(n0 + n) * C_ + cc;
    #pragma unroll
    for (int j0 = 0; j0 < 64; j0 += 8) {
      u16x8 o;
      #pragma unroll
      for (int j = 0; j < 8; ++j) {
        int c = cc + j0 + j;
        o[j] = f2bu((bu2f(T[c][n]) - m) * r * g[c] + beta[c]);
      }
      *(u16x8*)(po + j0) = o;
    }
  }
}

// ======================= MFMA GEMM template =======================
template<int TAPS, int DIMSEL, int OMODE, int SPLIT, bool BDUAL>
__global__ __launch_bounds__(256) void mfma_gemm(
    const ushort_t* __restrict__ A, long Abatch, int lda, long Aplane, long Adirstride,
    const ushort_t* __restrict__ B, const ushort_t* __restrict__ B2, long Bbatch, int ldb,
    const float* __restrict__ bias,
    const float* __restrict__ resF, const ushort_t* __restrict__ resB, long Resbatch,
    float* __restrict__ outF, ushort_t* __restrict__ outB, ushort_t* __restrict__ outB2,
    long Outbatch, int ldo, int Ksteps, const ushort_t* __restrict__ zbuf) {
  __shared__ ushort_t sm[17408];
  int tid = threadIdx.x;
  int bx = blockIdx.x, by = blockIdx.y, bz = blockIdx.z;
  if (gridDim.x == 128) bx = ((bx & 7) << 4) | (bx >> 3);
  int b = bz / SPLIT, sK = bz % SPLIT;
  long koff = (long)sK * Ksteps * 64;
  int dsel = (DIMSEL == 3) ? (by < 2 ? 1 : 2) : DIMSEL;
  int m0 = (DIMSEL == 3) ? ((by & 1) * 128) : (by * 128);
  int bofs = (DIMSEL == 3) ? ((by >> 1) * 256) : 0;
  const ushort_t* Ab = A + (size_t)b * Abatch + koff + ((DIMSEL == 3) ? (long)(by >> 1) * Adirstride : 0L);
  const ushort_t* Bb = B + (size_t)b * Bbatch + (BDUAL ? 0 : koff);
  const ushort_t* B2b = BDUAL ? (B2 + (size_t)b * Bbatch) : nullptr;
  int n0 = bx * 128;
  int lane = tid & 63, wid = tid >> 6, wm = wid >> 1, wn = wid & 1;

  f32x4 acc[4][4];
  #pragma unroll
  for (int i = 0; i < 4; i++)
    #pragma unroll
    for (int j = 0; j < 4; j++) acc[i][j] = (f32x4)0.f;

  for (int t = 0; t < TAPS; ++t) {
    if (TAPS == 3 && dsel == 2) {
      if ((bx == 0 && t == 0) || (bx == H_ - 1 && t == 2)) continue;
    }
    const ushort_t* At = Ab + (long)t * Aplane;
    for (int ks = 0; ks < Ksteps; ++ks) {
      int k0 = ks * 64;
      #pragma unroll
      for (int i = 0; i < 4; i++) {
        int s = tid + i * 256;
        int row = s >> 3, pc = s & 7;
        int lc = pc ^ (row & 7);
        const ushort_t* g = At + (long)(m0 + row) * lda + k0 + lc * 8;
        GLD16(g, &sm[s * 8]);
      }
      #pragma unroll
      for (int i = 0; i < 4; i++) {
        int s = tid + i * 256;
        int row = s >> 3, pc = s & 7;
        int lc = pc ^ (row & 7);
        const ushort_t* g;
        if (BDUAL) {
          const ushort_t* Bsel = (ks < Ksteps / 2) ? Bb : B2b;
          int kb = ((ks < Ksteps / 2) ? ks : ks - Ksteps / 2) * 64;
          g = Bsel + (long)(n0 + row) * ldb + kb + lc * 8;
        } else if (TAPS == 3 && dsel == 1) {
          int wpos = row + (t - 1);
          if (0 <= wpos && wpos < W_)
            g = Bb + (long)(n0 + row + (t - 1)) * ldb + k0 + lc * 8;
          else
            g = zbuf;
        } else if (TAPS == 3 && dsel == 2) {
          g = Bb + (long)(n0 + row + (t - 1) * W_) * ldb + k0 + lc * 8;
        } else {
          g = Bb + (long)(n0 + row) * ldb + k0 + lc * 8;
        }
        GLD16(g, &sm[8192 + s * 8]);
      }
      __syncthreads();
      #pragma unroll
      for (int kk = 0; kk < 2; kk++) {
        bf16x8 av[4], bv[4];
        int r16 = lane & 15;
        int sl = (lane >> 4) + kk * 4;
        #pragma unroll
        for (int fm = 0; fm < 4; fm++) {
          int row = wm * 64 + fm * 16 + r16;
          av[fm] = *(const bf16x8*)&sm[row * 64 + ((sl ^ (row & 7)) * 8)];
        }
        #pragma unroll
        for (int fn = 0; fn < 4; fn++) {
          int row = wn * 64 + fn * 16 + r16;
          bv[fn] = *(const bf16x8*)&sm[8192 + row * 64 + ((sl ^ (row & 7)) * 8)];
        }
        #pragma unroll
        for (int fm = 0; fm < 4; fm++)
          #pragma unroll
          for (int fn = 0; fn < 4; fn++)
            acc[fm][fn] = __builtin_amdgcn_mfma_f32_16x16x32_bf16(av[fm], bv[fn], acc[fm][fn], 0, 0, 0);
      }
      __syncthreads();
    }
  }

  int r16 = lane & 15, rq = lane >> 4;
  if (OMODE == 1 || OMODE == 2 || OMODE == 7) {
    ushort_t* obase = (DIMSEL == 3 && blockIdx.y >= 2) ? outB2 : outB;
    ushort_t* ob = obase + (size_t)bz * Outbatch;
    #pragma unroll
    for (int fm = 0; fm < 4; fm++) {
      #pragma unroll
      for (int fn = 0; fn < 4; fn++) {
        int lm = wm * 64 + fm * 16 + rq * 4;
        int ln = wn * 64 + fn * 16 + r16;
        f32x4 a = acc[fm][fn];
        if (OMODE == 2) {
          #pragma unroll
          for (int r = 0; r < 4; r++)
            sm[ln * 136 + lm + r] = f2bu(a[r] + bias[bofs + m0 + lm + r]);
        } else {
          #pragma unroll
          for (int r = 0; r < 4; r++)
            sm[(lm + r) * 136 + ln] = f2bu(a[r] + bias[bofs + m0 + lm + r]);
        }
      }
    }
    __syncthreads();
    int row = tid >> 1, half = (tid & 1) * 64;
    const ushort_t* src = &sm[row * 136 + half];
    if (OMODE == 7) {
      const float* xb = resF + (size_t)bz * Resbatch + (size_t)(m0 + row) * ldo + n0 + half;
      ushort_t* dst = &ob[(size_t)(m0 + row) * ldo + n0 + half];
      #pragma unroll
      for (int j = 0; j < 8; j++) {
        u16x8 v = *(const u16x8*)(src + j * 8);
        float4 x0 = *(const float4*)(xb + j * 8);
        float4 x1 = *(const float4*)(xb + j * 8 + 4);
        u16x8 o;
        o[0] = f2bu(bu2f(v[0]) + x0.x); o[1] = f2bu(bu2f(v[1]) + x0.y);
        o[2] = f2bu(bu2f(v[2]) + x0.z); o[3] = f2bu(bu2f(v[3]) + x0.w);
        o[4] = f2bu(bu2f(v[4]) + x1.x); o[5] = f2bu(bu2f(v[5]) + x1.y);
        o[6] = f2bu(bu2f(v[6]) + x1.z); o[7] = f2bu(bu2f(v[7]) + x1.w);
        *(u16x8*)(dst + j * 8) = o;
      }
    } else {
      ushort_t* dst;
      if (OMODE == 1) dst = &ob[(size_t)(m0 + row) * ldo + n0 + half];
      else            dst = &ob[(size_t)(n0 + row) * ldo + m0 + half];
      #pragma unroll
      for (int j = 0; j < 8; j++)
        *(u16x8*)(dst + j * 8) = *(const u16x8*)(src + j * 8);
    }
  } else {
    #pragma unroll
    for (int fm = 0; fm < 4; fm++) {
      #pragma unroll
      for (int fn = 0; fn < 4; fn++) {
        int mrow = m0 + wm * 64 + fm * 16 + rq * 4;
        int ncol = n0 + wn * 64 + fn * 16 + r16;
        f32x4 a = acc[fm][fn];
        if (OMODE == 6) {
          float* of = outF + (size_t)bz * Outbatch;
          #pragma unroll
          for (int r = 0; r < 4; r++)
            of[(size_t)(mrow + r) * ldo + ncol] = a[r];
        } else if (OMODE == 8) {
          float* of = outF + (size_t)bz * Outbatch;
          const ushort_t* rp = resB + (size_t)bz * Resbatch;
          #pragma unroll
          for (int r = 0; r < 4; r++) {
            size_t o = (size_t)(mrow + r) * ldo + ncol;
            of[o] = a[r] + bias[mrow + r] + bu2f(rp[o]);
          }
        }
      }
    }
  }
}

// ---------------- single-pass spatial softmax (row of 16384 held in registers)
__global__ __launch_bounds__(256) void softmax_spatial2(ushort_t* __restrict__ p0,
                                                        ushort_t* __restrict__ p1) {
  int r = blockIdx.x;
  ushort_t* p = (r < B_ * KC_) ? (p0 + (size_t)r * N_) : (p1 + (size_t)(r - B_ * KC_) * N_);
  int tid = threadIdx.x;
  __shared__ float red[256];
  u16x8 v[8];
  #pragma unroll
  for (int j = 0; j < 8; j++) v[j] = *(const u16x8*)&p[tid * 8 + j * 2048];
  float mx = -1e30f;
  #pragma unroll
  for (int j = 0; j < 8; j++)
    #pragma unroll
    for (int e = 0; e < 8; e++) mx = fmaxf(mx, bu2f(v[j][e]));
  red[tid] = mx; __syncthreads();
  for (int s = 128; s > 0; s >>= 1) { if (tid < s) red[tid] = fmaxf(red[tid], red[tid + s]); __syncthreads(); }
  mx = red[0]; __syncthreads();
  float sum = 0.f;
  #pragma unroll
  for (int j = 0; j < 8; j++)
    #pragma unroll
    for (int e = 0; e < 8; e++) sum += __expf(bu2f(v[j][e]) - mx);
  red[tid] = sum; __syncthreads();
  for (int s = 128; s > 0; s >>= 1) { if (tid < s) red[tid] += red[tid + s]; __syncthreads(); }
  float inv = 1.f / red[0];
  #pragma unroll
  for (int j = 0; j < 8; j++) {
    u16x8 o;
    #pragma unroll
    for (int e = 0; e < 8; e++) o[e] = f2bu(__expf(bu2f(v[j][e]) - mx) * inv);
    *(u16x8*)&p[tid * 8 + j * 2048] = o;
  }
}

// ---------------- single-pass channel softmax: 4 lanes per [n][256] row, regs + quad shfl
__global__ __launch_bounds__(256) void softmax_channel2(ushort_t* __restrict__ p0,
                                                        ushort_t* __restrict__ p1) {
  int tid = threadIdx.x;
  size_t rowg = (size_t)blockIdx.x * 64 + (tid >> 2);
  int part = tid & 3;
  ushort_t* q = (rowg < (size_t)B_ * N_) ? (p0 + rowg * KC_)
                                         : (p1 + (rowg - (size_t)B_ * N_) * KC_);
  ushort_t* qp = q + part * 64;
  u16x8 v[8];
  #pragma unroll
  for (int j = 0; j < 8; j++) v[j] = *(const u16x8*)&qp[j * 8];
  float mx = -1e30f;
  #pragma unroll
  for (int j = 0; j < 8; j++)
    #pragma unroll
    for (int e = 0; e < 8; e++) mx = fmaxf(mx, bu2f(v[j][e]));
  mx = fmaxf(mx, __shfl_xor(mx, 1));
  mx = fmaxf(mx, __shfl_xor(mx, 2));
  float sum = 0.f;
  #pragma unroll
  for (int j = 0; j < 8; j++)
    #pragma unroll
    for (int e = 0; e < 8; e++) sum += __expf(bu2f(v[j][e]) - mx);
  sum += __shfl_xor(sum, 1);
  sum += __shfl_xor(sum, 2);
  float inv = 1.f / sum;
  #pragma unroll
  for (int j = 0; j < 8; j++) {
    u16x8 o;
    #pragma unroll
    for (int e = 0; e < 8; e++) o[e] = f2bu(__expf(bu2f(v[j][e]) - mx) * inv);
    *(u16x8*)&qp[j * 8] = o;
  }
}

// ---------------- amap: vectorized column sums, 4-way c-split, 512 n per block
__global__ __launch_bounds__(256) void amap2_kernel(const ushort_t* __restrict__ k0,
    const ushort_t* __restrict__ k1, float* __restrict__ amap) {
  __shared__ float red[256][8];
  int tid = threadIdx.x;
  int ngrp = tid & 63, part = tid >> 6;
  int nblock = blockIdx.x * 512;
  int b = nblock >> 14;
  int n = (nblock & 16383) + ngrp * 8;
  const ushort_t* b0 = k0 + (size_t)b * KC_ * N_ + n;
  const ushort_t* b1 = k1 + (size_t)b * KC_ * N_ + n;
  float s[8];
  #pragma unroll
  for (int j = 0; j < 8; j++) s[j] = 0.f;
  for (int c = part * 64; c < part * 64 + 64; ++c) {
    u16x8 a = *(const u16x8*)&b0[(size_t)c * N_];
    u16x8 d = *(const u16x8*)&b1[(size_t)c * N_];
    #pragma unroll
    for (int j = 0; j < 8; j++) s[j] += bu2f(a[j]) + bu2f(d[j]);
  }
  #pragma unroll
  for (int j = 0; j < 8; j++) red[tid][j] = s[j];
  __syncthreads();
  if (tid < 64) {
    float t[8];
    #pragma unroll
    for (int j = 0; j < 8; j++)
      t[j] = (red[tid][j] + red[tid + 64][j] + red[tid + 128][j] + red[tid + 192][j])
             * (1.f / (2.f * KC_));
    float* dst = amap + (size_t)nblock + tid * 8;
    *(float4*)dst = make_float4(t[0], t[1], t[2], t[3]);
    *(float4*)(dst + 4) = make_float4(t[4], t[5], t[6], t[7]);
  }
}

__global__ __launch_bounds__(256) void ctx_reduce(const float* __restrict__ part,
                                                  float* __restrict__ out, int split) {
  int idx = blockIdx.x * 256 + threadIdx.x;
  int b = idx >> 16;
  int r = idx & 65535;
  float s = 0.f;
  for (int k = 0; k < split; k++)
    s += part[((size_t)(b * split + k)) * KC_ * VC_ + r];
  out[idx] = s;
}

__global__ __launch_bounds__(256) void mk2_kernel(const float* __restrict__ wr,
    const float* __restrict__ ctx0, const float* __restrict__ ctx1,
    ushort_t* __restrict__ Mout) {
  int b = blockIdx.x >> 8;
  int c = blockIdx.x & 255;
  int kc = threadIdx.x;
  __shared__ float wlo[256], whi[256];
  wlo[kc] = wr[(size_t)c * 512 + kc];
  whi[kc] = wr[(size_t)c * 512 + 256 + kc];
  __syncthreads();
  const float* c0 = ctx0 + (size_t)b * 65536 + (size_t)kc * 256;
  const float* c1 = ctx1 + (size_t)b * 65536 + (size_t)kc * 256;
  float s0 = 0.f, s1 = 0.f;
  for (int v = 0; v < 256; ++v) { s0 += wlo[v] * c0[v]; s1 += whi[v] * c1[v]; }
  ushort_t* mo = Mout + (size_t)b * C_ * 512 + (size_t)c * 512;
  mo[kc] = f2bu(s0);
  mo[256 + kc] = f2bu(s1);
}

__global__ __launch_bounds__(256) void dwgelu_t(const ushort_t* __restrict__ h1t,
    const float* __restrict__ wdwT, const float* __restrict__ bdw,
    ushort_t* __restrict__ actT) {
  int pix = blockIdx.x * 2 + (threadIdx.x >> 7);
  int c = (threadIdx.x & 127) * 8;
  int h = pix >> 7, w = pix & 127;
  float s[8];
  {
    float4 b0 = *(const float4*)&bdw[c];
    float4 b1 = *(const float4*)&bdw[c + 4];
    s[0]=b0.x; s[1]=b0.y; s[2]=b0.z; s[3]=b0.w;
    s[4]=b1.x; s[5]=b1.y; s[6]=b1.z; s[7]=b1.w;
  }
  #pragma unroll
  for (int di = -1; di <= 1; ++di) {
    int h2 = h + di;
    if ((unsigned)h2 >= H_) continue;
    #pragma unroll
    for (int dj = -1; dj <= 1; ++dj) {
      int w2 = w + dj;
      if ((unsigned)w2 >= W_) continue;
      int tap = (di + 1) * 3 + (dj + 1);
      u16x8 v = *(const u16x8*)&h1t[(size_t)(h2 * W_ + w2) * HID_ + c];
      const float* wp = &wdwT[tap * HID_ + c];
      float4 w0 = *(const float4*)wp, w1 = *(const float4*)(wp + 4);
      s[0] += w0.x * bu2f(v[0]); s[1] += w0.y * bu2f(v[1]);
      s[2] += w0.z * bu2f(v[2]); s[3] += w0.w * bu2f(v[3]);
      s[4] += w1.x * bu2f(v[4]); s[5] += w1.y * bu2f(v[5]);
      s[6] += w1.z * bu2f(v[6]); s[7] += w1.w * bu2f(v[7]);
    }
  }
  u16x8 o;
  #pragma unroll
  for (int j = 0; j < 8; j++) {
    float gl = 0.5f * s[j] * (1.f + erff(s[j] * 0.70710678118654752f));
    o[j] = f2bu(gl);
  }
  *(u16x8*)&actT[(size_t)pix * HID_ + c] = o;
}

extern "C" void kernel_launch(void* const* d_in, const int* in_sizes, int n_in,
                              void* d_out, int out_size, void* d_ws, size_t ws_size,
                              hipStream_t stream) {
  const float* x    = (const float*)d_in[0];
  const float* wk1  = (const float*)d_in[3];
  const float* bk1  = (const float*)d_in[4];
  const float* wk2  = (const float*)d_in[5];
  const float* bk2  = (const float*)d_in[6];
  const float* wq1  = (const float*)d_in[7];
  const float* bq1  = (const float*)d_in[8];
  const float* wq2  = (const float*)d_in[9];
  const float* bq2  = (const float*)d_in[10];
  const float* wv   = (const float*)d_in[11];
  const float* bv   = (const float*)d_in[12];
  const float* wr   = (const float*)d_in[13];
  const float* br   = (const float*)d_in[14];
  const float* g1   = (const float*)d_in[15];
  const float* b1   = (const float*)d_in[16];
  const float* g2   = (const float*)d_in[17];
  const float* b2   = (const float*)d_in[18];
  const float* wfc1 = (const float*)d_in[19];
  const float* bfc1 = (const float*)d_in[20];
  const float* wdw  = (const float*)d_in[21];
  const float* bdw  = (const float*)d_in[22];
  const float* wfc2 = (const float*)d_in[23];
  const float* bfc2 = (const float*)d_in[24];

  const size_t big = (size_t)B_ * C_ * N_;
  const long  CN  = (long)C_ * N_;
  const long  NC2 = (long)N_ * C_;

  uint8_t* w8 = (uint8_t*)d_ws;
  size_t off = 0;
  ushort_t* xnt = (ushort_t*)(w8 + off); off += 67108864;
  ushort_t* kq  = (ushort_t*)(w8 + off); off += 67108864;
  float*  ctx0  = (float*)(w8 + off);    off += (size_t)B_ * KC_ * VC_ * 4;
  ushort_t* Mbuf= (ushort_t*)(w8 + off); off += (size_t)B_ * C_ * 512 * 2;
  ushort_t* wkkp = (ushort_t*)(w8 + off); off += 6 * KC_ * C_ * 2;
  ushort_t* wqqp = (ushort_t*)(w8 + off); off += 6 * KC_ * C_ * 2;
  ushort_t* wvp  = (ushort_t*)(w8 + off); off += VC_ * C_ * 2;
  ushort_t* wfc1p= (ushort_t*)(w8 + off); off += HID_ * C_ * 2;
  ushort_t* wfc2p= (ushort_t*)(w8 + off); off += C_ * HID_ * 2;
  float* wdwT    = (float*)(w8 + off);    off += 9 * HID_ * 4;
  float* bK      = (float*)(w8 + off);    off += 512 * 4;
  float* bQ      = (float*)(w8 + off);    off += 512 * 4;
  ushort_t* zbuf = (ushort_t*)(w8 + off); off += 512;
  float* part    = (float*)(w8 + off);
  size_t need4 = off + (size_t)4 * B_ * KC_ * VC_ * 4;
  size_t need8 = off + (size_t)8 * B_ * KC_ * VC_ * 4;
  int csplit;
  if (ws_size >= need8) csplit = 8;
  else if (ws_size >= need4) csplit = 4;
  else return;

  float* mx_out   = (float*)d_out;
  float* ctx_out  = mx_out + big;
  float* amap_out = ctx_out + (size_t)B_ * KC_ * VC_;

  ushort_t* mxlo = (ushort_t*)d_out;            // val -> q1
  ushort_t* mxhi = (ushort_t*)d_out + big;      // K1 -> tx

  ushort_t* txn  = xnt;
  ushort_t* h1t  = kq;
  ushort_t* actT = kq + (size_t)N_ * HID_;

  dim3 blk(256);

  zero_kernel<<<1, 64, 0, stream>>>(zbuf);
  pack3_kernel<<<KC_ * C_ / 256, blk, 0, stream>>>(wk1, wkkp, KC_ * C_);
  pack3_kernel<<<KC_ * C_ / 256, blk, 0, stream>>>(wk2, wkkp + 3 * KC_ * C_, KC_ * C_);
  pack3_kernel<<<KC_ * C_ / 256, blk, 0, stream>>>(wq1, wqqp, KC_ * C_);
  pack3_kernel<<<KC_ * C_ / 256, blk, 0, stream>>>(wq2, wqqp + 3 * KC_ * C_, KC_ * C_);
  pack1_kernel<<<VC_ * C_ / 256, blk, 0, stream>>>(wv, wvp, VC_ * C_);
  pack1_kernel<<<HID_ * C_ / 256, blk, 0, stream>>>(wfc1, wfc1p, HID_ * C_);
  pack1_kernel<<<C_ * HID_ / 256, blk, 0, stream>>>(wfc2, wfc2p, C_ * HID_);
  packdw_kernel<<<36, blk, 0, stream>>>(wdw, wdwT);
  bcat_kernel<<<1, blk, 0, stream>>>(bk1, bk2, bK);
  bcat_kernel<<<1, blk, 0, stream>>>(bq1, bq2, bQ);

  // LN1 fused
  ln1t_kernel<<<dim3(N_ / 64, 1, B_), blk, 0, stream>>>(x, g1, b1, xnt);

  // val -> mxlo
  mfma_gemm<1, 0, 1, 1, false><<<dim3(N_ / 128, VC_ / 128, B_), blk, 0, stream>>>(
      wvp, 0, C_, 0, 0, xnt, nullptr, NC2, C_, bv, nullptr, nullptr, 0,
      nullptr, mxlo, nullptr, (long)VC_ * N_, N_, C_ / 64, zbuf);

  // fused KK: K0 -> kq, K1 -> mxhi
  mfma_gemm<3, 3, 1, 1, false><<<dim3(N_ / 128, 4, B_), blk, 0, stream>>>(
      wkkp, 0, C_, (long)KC_ * C_, (long)3 * KC_ * C_, xnt, nullptr, NC2, C_,
      bK, nullptr, nullptr, 0,
      nullptr, kq, mxhi, (long)KC_ * N_, N_, C_ / 64, zbuf);

  softmax_spatial2<<<2 * B_ * KC_, blk, 0, stream>>>(kq, mxhi);
  amap2_kernel<<<B_ * N_ / 512, blk, 0, stream>>>(kq, mxhi, amap_out);

  for (int d = 0; d < 2; ++d) {
    const ushort_t* Ksrc = d ? mxhi : kq;
    if (csplit == 8)
      mfma_gemm<1, 0, 6, 8, false><<<dim3(VC_ / 128, KC_ / 128, B_ * 8), blk, 0, stream>>>(
          Ksrc, (long)KC_ * N_, N_, 0, 0, mxlo, nullptr, (long)VC_ * N_, N_,
          nullptr, nullptr, nullptr, 0,
          part, nullptr, nullptr, (long)KC_ * VC_, VC_, (N_ / 8) / 64, zbuf);
    else
      mfma_gemm<1, 0, 6, 4, false><<<dim3(VC_ / 128, KC_ / 128, B_ * 4), blk, 0, stream>>>(
          Ksrc, (long)KC_ * N_, N_, 0, 0, mxlo, nullptr, (long)VC_ * N_, N_,
          nullptr, nullptr, nullptr, 0,
          part, nullptr, nullptr, (long)KC_ * VC_, VC_, (N_ / 4) / 64, zbuf);
    ctx_reduce<<<B_ * KC_ * VC_ / 256, blk, 0, stream>>>(part, d ? ctx_out : ctx0, csplit);
  }

  // fused QQ: q0 -> kq [n][kc], q1 -> mxlo
  mfma_gemm<3, 3, 2, 1, false><<<dim3(N_ / 128, 4, B_), blk, 0, stream>>>(
      wqqp, 0, C_, (long)KC_ * C_, (long)3 * KC_ * C_, xnt, nullptr, NC2, C_,
      bQ, nullptr, nullptr, 0,
      nullptr, kq, mxlo, (long)N_ * KC_, KC_, C_ / 64, zbuf);

  softmax_channel2<<<2 * B_ * N_ / 64, blk, 0, stream>>>(kq, mxlo);

  mk2_kernel<<<B_ * C_, blk, 0, stream>>>(wr, ctx0, ctx_out, Mbuf);

  // fused attention -> tx bf16 @ mxhi
  mfma_gemm<1, 0, 7, 1, true><<<dim3(N_ / 128, C_ / 128, B_), blk, 0, stream>>>(
      Mbuf, (long)C_ * 512, 512, 0, 0, kq, mxlo, (long)N_ * KC_, KC_,
      br, x, nullptr, CN,
      nullptr, mxhi, nullptr, CN, N_, 8, zbuf);

  // LN2 fused: tx -> txn
  ln2t_kernel<<<dim3(N_ / 64, 1, B_), blk, 0, stream>>>(mxhi, g2, b2, txn);

  // preserve tx batch 7 (fc2 b7 writes clobber it)
  hipMemcpyAsync(part, mxhi + (size_t)7 * CN, (size_t)CN * 2,
                 hipMemcpyDeviceToDevice, stream);

  for (int b = 0; b < B_; ++b) {
    mfma_gemm<1, 0, 2, 1, false><<<dim3(N_ / 128, HID_ / 128, 1), blk, 0, stream>>>(
        wfc1p, 0, C_, 0, 0, txn + (size_t)b * NC2, nullptr, 0, C_,
        bfc1, nullptr, nullptr, 0,
        nullptr, h1t, nullptr, 0, HID_, C_ / 64, zbuf);
    dwgelu_t<<<N_ / 2, blk, 0, stream>>>(h1t, wdwT, bdw, actT);
    const ushort_t* txb = (b == 7) ? (const ushort_t*)part : (mxhi + (size_t)b * CN);
    mfma_gemm<1, 0, 8, 1, false><<<dim3(N_ / 128, C_ / 128, 1), blk, 0, stream>>>(
        wfc2p, 0, HID_, 0, 0, actT, nullptr, 0, HID_,
        bfc2, nullptr, txb, 0,
        mx_out + (size_t)b * CN, nullptr, nullptr, 0, N_, HID_ / 64, zbuf);
  }
}

// Round 8
// 1481.243 us; speedup vs baseline: 8.5411x; 1.1024x over previous
//
#include <hip/hip_runtime.h>
#include <hip/hip_bf16.h>

#define B_ 8
#define C_ 256
#define H_ 128
#define W_ 128
#define N_ 16384
#define KC_ 256
#define VC_ 256
#define HID_ 1024

typedef unsigned short ushort_t;
typedef __bf16 bf16x8 __attribute__((ext_vector_type(8)));
typedef float f32x4 __attribute__((ext_vector_type(4)));
typedef ushort_t u16x8 __attribute__((ext_vector_type(8)));

static __device__ __forceinline__ ushort_t f2bu(float f) {
  __hip_bfloat16 h = __float2bfloat16(f);
  return *reinterpret_cast<ushort_t*>(&h);
}
static __device__ __forceinline__ float bu2f(ushort_t u) {
  __hip_bfloat16 h;
  *reinterpret_cast<ushort_t*>(&h) = u;
  return __bfloat162float(h);
}

#define GLD16(gp, lp) __builtin_amdgcn_global_load_lds( \
    (const __attribute__((address_space(1))) void*)(gp), \
    (__attribute__((address_space(3))) void*)(lp), 16, 0, 0)

// ---------------- one-shot weight/bias packing (replaces 11 tiny dispatches)
__global__ __launch_bounds__(256) void pack_all(
    const float* __restrict__ wk1, const float* __restrict__ wk2,
    const float* __restrict__ wq1, const float* __restrict__ wq2,
    const float* __restrict__ wv, const float* __restrict__ wfc1,
    const float* __restrict__ wfc2, const float* __restrict__ wdw,
    const float* __restrict__ bk1, const float* __restrict__ bk2,
    const float* __restrict__ bq1, const float* __restrict__ bq2,
    const float* __restrict__ wr,
    ushort_t* __restrict__ zbuf, float* __restrict__ fzero,
    float* __restrict__ bK, float* __restrict__ bQ, float* __restrict__ wdwT,
    ushort_t* __restrict__ wvp, ushort_t* __restrict__ wfc1p,
    ushort_t* __restrict__ wfc2p, ushort_t* __restrict__ wrp,
    ushort_t* __restrict__ wkkp, ushort_t* __restrict__ wqqp) {
  int idx = blockIdx.x * 256 + threadIdx.x;
  const int MC = KC_ * C_;
  if (idx < 512) {
    zbuf[idx] = 0; fzero[idx] = 0.f;
    bK[idx] = (idx < 256) ? bk1[idx] : bk2[idx - 256];
    bQ[idx] = (idx < 256) ? bq1[idx] : bq2[idx - 256];
    return;
  }
  idx -= 512;
  if (idx < 9216) { int c = idx / 9, t = idx % 9; wdwT[t * HID_ + c] = wdw[idx]; return; }
  idx -= 9216;
  if (idx < VC_ * C_) { wvp[idx] = f2bu(wv[idx]); return; }
  idx -= VC_ * C_;
  if (idx < HID_ * C_) { wfc1p[idx] = f2bu(wfc1[idx]); return; }
  idx -= HID_ * C_;
  if (idx < C_ * HID_) { wfc2p[idx] = f2bu(wfc2[idx]); return; }
  idx -= C_ * HID_;
  if (idx < C_ * 512) { wrp[idx] = f2bu(wr[idx]); return; }
  idx -= C_ * 512;
  if (idx < MC) {
    #pragma unroll
    for (int t = 0; t < 3; ++t) wkkp[t * MC + idx] = f2bu(wk1[idx * 3 + t]);
    return;
  }
  idx -= MC;
  if (idx < MC) {
    #pragma unroll
    for (int t = 0; t < 3; ++t) wkkp[3 * MC + t * MC + idx] = f2bu(wk2[idx * 3 + t]);
    return;
  }
  idx -= MC;
  if (idx < MC) {
    #pragma unroll
    for (int t = 0; t < 3; ++t) wqqp[t * MC + idx] = f2bu(wq1[idx * 3 + t]);
    return;
  }
  idx -= MC;
  if (idx < MC) {
    #pragma unroll
    for (int t = 0; t < 3; ++t) wqqp[3 * MC + t * MC + idx] = f2bu(wq2[idx * 3 + t]);
    return;
  }
}

// ---------------- fused LN1: x fp32 [c][n] -> bf16 [n][c]
__global__ __launch_bounds__(256) void ln1t_kernel(const float* __restrict__ x,
    const float* __restrict__ g, const float* __restrict__ beta,
    ushort_t* __restrict__ out) {
  __shared__ float T[256][67];
  __shared__ float st[2][4][64];
  __shared__ float mr[64], rs[64];
  int z = blockIdx.z;
  int n0 = blockIdx.x * 64;
  int t = threadIdx.x;
  const float* xb = x + (size_t)z * C_ * N_;
  #pragma unroll
  for (int j = 0; j < 16; ++j) {
    int e = (j * 256 + t) * 4;
    int c = e >> 6, n = e & 63;
    float4 v = *(const float4*)&xb[(size_t)c * N_ + n0 + n];
    T[c][n] = v.x; T[c][n + 1] = v.y; T[c][n + 2] = v.z; T[c][n + 3] = v.w;
  }
  __syncthreads();
  {
    int n = t & 63, part = t >> 6;
    float s1 = 0.f, s2 = 0.f;
    for (int c = part * 64; c < part * 64 + 64; ++c) { float v = T[c][n]; s1 += v; s2 += v * v; }
    st[0][part][n] = s1; st[1][part][n] = s2;
  }
  __syncthreads();
  if (t < 64) {
    float s1 = st[0][0][t] + st[0][1][t] + st[0][2][t] + st[0][3][t];
    float s2 = st[1][0][t] + st[1][1][t] + st[1][2][t] + st[1][3][t];
    float m = s1 * (1.f / C_);
    float v = s2 * (1.f / C_) - m * m;
    mr[t] = m; rs[t] = rsqrtf(v + 1e-5f);
  }
  __syncthreads();
  {
    int n = t >> 2, cc = (t & 3) * 64;
    float m = mr[n], r = rs[n];
    ushort_t* po = out + (size_t)z * N_ * C_ + (size_t)(n0 + n) * C_ + cc;
    #pragma unroll
    for (int j0 = 0; j0 < 64; j0 += 8) {
      u16x8 o;
      #pragma unroll
      for (int j = 0; j < 8; ++j) {
        int c = cc + j0 + j;
        o[j] = f2bu((T[c][n] - m) * r * g[c] + beta[c]);
      }
      *(u16x8*)(po + j0) = o;
    }
  }
}

// ---------------- fused LN2: tx bf16 [c][n] -> bf16 [n][c]
__global__ __launch_bounds__(256) void ln2t_kernel(const ushort_t* __restrict__ x,
    const float* __restrict__ g, const float* __restrict__ beta,
    ushort_t* __restrict__ out) {
  __shared__ ushort_t T[256][72];
  __shared__ float st[2][4][64];
  __shared__ float mr[64], rs[64];
  int z = blockIdx.z;
  int n0 = blockIdx.x * 64;
  int t = threadIdx.x;
  const ushort_t* xb = x + (size_t)z * C_ * N_;
  #pragma unroll
  for (int j = 0; j < 8; ++j) {
    int e = (j * 256 + t) * 8;
    int c = e >> 6, n = e & 63;
    *(u16x8*)&T[c][n] = *(const u16x8*)&xb[(size_t)c * N_ + n0 + n];
  }
  __syncthreads();
  {
    int n = t & 63, part = t >> 6;
    float s1 = 0.f, s2 = 0.f;
    for (int c = part * 64; c < part * 64 + 64; ++c) { float v = bu2f(T[c][n]); s1 += v; s2 += v * v; }
    st[0][part][n] = s1; st[1][part][n] = s2;
  }
  __syncthreads();
  if (t < 64) {
    float s1 = st[0][0][t] + st[0][1][t] + st[0][2][t] + st[0][3][t];
    float s2 = st[1][0][t] + st[1][1][t] + st[1][2][t] + st[1][3][t];
    float m = s1 * (1.f / C_);
    float v = s2 * (1.f / C_) - m * m;
    mr[t] = m; rs[t] = rsqrtf(v + 1e-5f);
  }
  __syncthreads();
  {
    int n = t >> 2, cc = (t & 3) * 64;
    float m = mr[n], r = rs[n];
    ushort_t* po = out + (size_t)z * N_ * C_ + (size_t)(n0 + n) * C_ + cc;
    #pragma unroll
    for (int j0 = 0; j0 < 64; j0 += 8) {
      u16x8 o;
      #pragma unroll
      for (int j = 0; j < 8; ++j) {
        int c = cc + j0 + j;
        o[j] = f2bu((bu2f(T[c][n]) - m) * r * g[c] + beta[c]);
      }
      *(u16x8*)(po + j0) = o;
    }
  }
}

// ======================= MFMA GEMM template =======================
template<int TAPS, int DIMSEL, int OMODE, int SPLIT, bool BDUAL>
__global__ __launch_bounds__(256) void mfma_gemm(
    const ushort_t* __restrict__ A, long Abatch, int lda, long Aplane, long Adirstride,
    const ushort_t* __restrict__ B, const ushort_t* __restrict__ B2, long Bbatch, int ldb,
    const float* __restrict__ bias,
    const float* __restrict__ resF, const ushort_t* __restrict__ resB, long Resbatch,
    float* __restrict__ outF, ushort_t* __restrict__ outB, ushort_t* __restrict__ outB2,
    long Outbatch, int ldo, int Ksteps, const ushort_t* __restrict__ zbuf) {
  __shared__ ushort_t sm[17408];
  int tid = threadIdx.x;
  int bx = blockIdx.x, by = blockIdx.y, bz = blockIdx.z;
  if (gridDim.x == 128) bx = ((bx & 7) << 4) | (bx >> 3);
  int b = bz / SPLIT, sK = bz % SPLIT;
  long koff = (long)sK * Ksteps * 64;
  int dsel = (DIMSEL == 3) ? (by < 2 ? 1 : 2) : DIMSEL;
  int m0 = (DIMSEL == 3) ? ((by & 1) * 128) : (by * 128);
  int bofs = (DIMSEL == 3) ? ((by >> 1) * 256) : 0;
  const ushort_t* Ab = A + (size_t)b * Abatch + koff + ((DIMSEL == 3) ? (long)(by >> 1) * Adirstride : 0L);
  const ushort_t* Bb = B + (size_t)b * Bbatch + (BDUAL ? 0 : koff);
  const ushort_t* B2b = BDUAL ? (B2 + (size_t)b * Bbatch) : nullptr;
  int n0 = bx * 128;
  int lane = tid & 63, wid = tid >> 6, wm = wid >> 1, wn = wid & 1;

  f32x4 acc[4][4];
  #pragma unroll
  for (int i = 0; i < 4; i++)
    #pragma unroll
    for (int j = 0; j < 4; j++) acc[i][j] = (f32x4)0.f;

  for (int t = 0; t < TAPS; ++t) {
    if (TAPS == 3 && dsel == 2) {
      if ((bx == 0 && t == 0) || (bx == H_ - 1 && t == 2)) continue;
    }
    const ushort_t* At = Ab + (long)t * Aplane;
    for (int ks = 0; ks < Ksteps; ++ks) {
      int k0 = ks * 64;
      #pragma unroll
      for (int i = 0; i < 4; i++) {
        int s = tid + i * 256;
        int row = s >> 3, pc = s & 7;
        int lc = pc ^ (row & 7);
        const ushort_t* g = At + (long)(m0 + row) * lda + k0 + lc * 8;
        GLD16(g, &sm[s * 8]);
      }
      #pragma unroll
      for (int i = 0; i < 4; i++) {
        int s = tid + i * 256;
        int row = s >> 3, pc = s & 7;
        int lc = pc ^ (row & 7);
        const ushort_t* g;
        if (BDUAL) {
          const ushort_t* Bsel = (ks < Ksteps / 2) ? Bb : B2b;
          int kb = ((ks < Ksteps / 2) ? ks : ks - Ksteps / 2) * 64;
          g = Bsel + (long)(n0 + row) * ldb + kb + lc * 8;
        } else if (TAPS == 3 && dsel == 1) {
          int wpos = row + (t - 1);
          if (0 <= wpos && wpos < W_)
            g = Bb + (long)(n0 + row + (t - 1)) * ldb + k0 + lc * 8;
          else
            g = zbuf;
        } else if (TAPS == 3 && dsel == 2) {
          g = Bb + (long)(n0 + row + (t - 1) * W_) * ldb + k0 + lc * 8;
        } else {
          g = Bb + (long)(n0 + row) * ldb + k0 + lc * 8;
        }
        GLD16(g, &sm[8192 + s * 8]);
      }
      __syncthreads();
      #pragma unroll
      for (int kk = 0; kk < 2; kk++) {
        bf16x8 av[4], bv[4];
        int r16 = lane & 15;
        int sl = (lane >> 4) + kk * 4;
        #pragma unroll
        for (int fm = 0; fm < 4; fm++) {
          int row = wm * 64 + fm * 16 + r16;
          av[fm] = *(const bf16x8*)&sm[row * 64 + ((sl ^ (row & 7)) * 8)];
        }
        #pragma unroll
        for (int fn = 0; fn < 4; fn++) {
          int row = wn * 64 + fn * 16 + r16;
          bv[fn] = *(const bf16x8*)&sm[8192 + row * 64 + ((sl ^ (row & 7)) * 8)];
        }
        #pragma unroll
        for (int fm = 0; fm < 4; fm++)
          #pragma unroll
          for (int fn = 0; fn < 4; fn++)
            acc[fm][fn] = __builtin_amdgcn_mfma_f32_16x16x32_bf16(av[fm], bv[fn], acc[fm][fn], 0, 0, 0);
      }
      __syncthreads();
    }
  }

  int r16 = lane & 15, rq = lane >> 4;
  if (OMODE == 1 || OMODE == 2 || OMODE == 7) {
    ushort_t* obase = (DIMSEL == 3 && blockIdx.y >= 2) ? outB2 : outB;
    ushort_t* ob = obase + (size_t)bz * Outbatch;
    #pragma unroll
    for (int fm = 0; fm < 4; fm++) {
      #pragma unroll
      for (int fn = 0; fn < 4; fn++) {
        int lm = wm * 64 + fm * 16 + rq * 4;
        int ln = wn * 64 + fn * 16 + r16;
        f32x4 a = acc[fm][fn];
        if (OMODE == 2) {
          #pragma unroll
          for (int r = 0; r < 4; r++)
            sm[ln * 136 + lm + r] = f2bu(a[r] + bias[bofs + m0 + lm + r]);
        } else {
          #pragma unroll
          for (int r = 0; r < 4; r++)
            sm[(lm + r) * 136 + ln] = f2bu(a[r] + bias[bofs + m0 + lm + r]);
        }
      }
    }
    __syncthreads();
    int row = tid >> 1, half = (tid & 1) * 64;
    const ushort_t* src = &sm[row * 136 + half];
    if (OMODE == 7) {
      const float* xb = resF + (size_t)bz * Resbatch + (size_t)(m0 + row) * ldo + n0 + half;
      ushort_t* dst = &ob[(size_t)(m0 + row) * ldo + n0 + half];
      #pragma unroll
      for (int j = 0; j < 8; j++) {
        u16x8 v = *(const u16x8*)(src + j * 8);
        float4 x0 = *(const float4*)(xb + j * 8);
        float4 x1 = *(const float4*)(xb + j * 8 + 4);
        u16x8 o;
        o[0] = f2bu(bu2f(v[0]) + x0.x); o[1] = f2bu(bu2f(v[1]) + x0.y);
        o[2] = f2bu(bu2f(v[2]) + x0.z); o[3] = f2bu(bu2f(v[3]) + x0.w);
        o[4] = f2bu(bu2f(v[4]) + x1.x); o[5] = f2bu(bu2f(v[5]) + x1.y);
        o[6] = f2bu(bu2f(v[6]) + x1.z); o[7] = f2bu(bu2f(v[7]) + x1.w);
        *(u16x8*)(dst + j * 8) = o;
      }
    } else {
      ushort_t* dst;
      if (OMODE == 1) dst = &ob[(size_t)(m0 + row) * ldo + n0 + half];
      else            dst = &ob[(size_t)(n0 + row) * ldo + m0 + half];
      #pragma unroll
      for (int j = 0; j < 8; j++)
        *(u16x8*)(dst + j * 8) = *(const u16x8*)(src + j * 8);
    }
  } else {
    #pragma unroll
    for (int fm = 0; fm < 4; fm++) {
      #pragma unroll
      for (int fn = 0; fn < 4; fn++) {
        int mrow = m0 + wm * 64 + fm * 16 + rq * 4;
        int ncol = n0 + wn * 64 + fn * 16 + r16;
        f32x4 a = acc[fm][fn];
        if (OMODE == 6) {
          float* of = outF + (size_t)bz * Outbatch;
          #pragma unroll
          for (int r = 0; r < 4; r++)
            of[(size_t)(mrow + r) * ldo + ncol] = a[r];
        } else if (OMODE == 8) {
          float* of = outF + (size_t)bz * Outbatch;
          const ushort_t* rp = resB + (size_t)bz * Resbatch;
          #pragma unroll
          for (int r = 0; r < 4; r++) {
            size_t o = (size_t)(mrow + r) * ldo + ncol;
            of[o] = a[r] + bias[mrow + r] + bu2f(rp[o]);
          }
        }
      }
    }
  }
}

// ---------------- single-pass spatial softmax (row of 16384 held in registers)
__global__ __launch_bounds__(256) void softmax_spatial2(ushort_t* __restrict__ p0,
                                                        ushort_t* __restrict__ p1) {
  int r = blockIdx.x;
  ushort_t* p = (r < B_ * KC_) ? (p0 + (size_t)r * N_) : (p1 + (size_t)(r - B_ * KC_) * N_);
  int tid = threadIdx.x;
  __shared__ float red[256];
  u16x8 v[8];
  #pragma unroll
  for (int j = 0; j < 8; j++) v[j] = *(const u16x8*)&p[tid * 8 + j * 2048];
  float mx = -1e30f;
  #pragma unroll
  for (int j = 0; j < 8; j++)
    #pragma unroll
    for (int e = 0; e < 8; e++) mx = fmaxf(mx, bu2f(v[j][e]));
  red[tid] = mx; __syncthreads();
  for (int s = 128; s > 0; s >>= 1) { if (tid < s) red[tid] = fmaxf(red[tid], red[tid + s]); __syncthreads(); }
  mx = red[0]; __syncthreads();
  float sum = 0.f;
  #pragma unroll
  for (int j = 0; j < 8; j++)
    #pragma unroll
    for (int e = 0; e < 8; e++) sum += __expf(bu2f(v[j][e]) - mx);
  red[tid] = sum; __syncthreads();
  for (int s = 128; s > 0; s >>= 1) { if (tid < s) red[tid] += red[tid + s]; __syncthreads(); }
  float inv = 1.f / red[0];
  #pragma unroll
  for (int j = 0; j < 8; j++) {
    u16x8 o;
    #pragma unroll
    for (int e = 0; e < 8; e++) o[e] = f2bu(__expf(bu2f(v[j][e]) - mx) * inv);
    *(u16x8*)&p[tid * 8 + j * 2048] = o;
  }
}

// ---------------- single-pass channel softmax: 4 lanes per [n][256] row
__global__ __launch_bounds__(256) void softmax_channel2(ushort_t* __restrict__ p0,
                                                        ushort_t* __restrict__ p1) {
  int tid = threadIdx.x;
  size_t rowg = (size_t)blockIdx.x * 64 + (tid >> 2);
  int part = tid & 3;
  ushort_t* q = (rowg < (size_t)B_ * N_) ? (p0 + rowg * KC_)
                                         : (p1 + (rowg - (size_t)B_ * N_) * KC_);
  ushort_t* qp = q + part * 64;
  u16x8 v[8];
  #pragma unroll
  for (int j = 0; j < 8; j++) v[j] = *(const u16x8*)&qp[j * 8];
  float mx = -1e30f;
  #pragma unroll
  for (int j = 0; j < 8; j++)
    #pragma unroll
    for (int e = 0; e < 8; e++) mx = fmaxf(mx, bu2f(v[j][e]));
  mx = fmaxf(mx, __shfl_xor(mx, 1));
  mx = fmaxf(mx, __shfl_xor(mx, 2));
  float sum = 0.f;
  #pragma unroll
  for (int j = 0; j < 8; j++)
    #pragma unroll
    for (int e = 0; e < 8; e++) sum += __expf(bu2f(v[j][e]) - mx);
  sum += __shfl_xor(sum, 1);
  sum += __shfl_xor(sum, 2);
  float inv = 1.f / sum;
  #pragma unroll
  for (int j = 0; j < 8; j++) {
    u16x8 o;
    #pragma unroll
    for (int e = 0; e < 8; e++) o[e] = f2bu(__expf(bu2f(v[j][e]) - mx) * inv);
    *(u16x8*)&qp[j * 8] = o;
  }
}

// ---------------- amap: vectorized column sums, 4-way c-split, 512 n per block
__global__ __launch_bounds__(256) void amap2_kernel(const ushort_t* __restrict__ k0,
    const ushort_t* __restrict__ k1, float* __restrict__ amap) {
  __shared__ float red[256][8];
  int tid = threadIdx.x;
  int ngrp = tid & 63, part = tid >> 6;
  int nblock = blockIdx.x * 512;
  int b = nblock >> 14;
  int n = (nblock & 16383) + ngrp * 8;
  const ushort_t* b0 = k0 + (size_t)b * KC_ * N_ + n;
  const ushort_t* b1 = k1 + (size_t)b * KC_ * N_ + n;
  float s[8];
  #pragma unroll
  for (int j = 0; j < 8; j++) s[j] = 0.f;
  for (int c = part * 64; c < part * 64 + 64; ++c) {
    u16x8 a = *(const u16x8*)&b0[(size_t)c * N_];
    u16x8 d = *(const u16x8*)&b1[(size_t)c * N_];
    #pragma unroll
    for (int j = 0; j < 8; j++) s[j] += bu2f(a[j]) + bu2f(d[j]);
  }
  #pragma unroll
  for (int j = 0; j < 8; j++) red[tid][j] = s[j];
  __syncthreads();
  if (tid < 64) {
    float t[8];
    #pragma unroll
    for (int j = 0; j < 8; j++)
      t[j] = (red[tid][j] + red[tid + 64][j] + red[tid + 128][j] + red[tid + 192][j])
             * (1.f / (2.f * KC_));
    float* dst = amap + (size_t)nblock + tid * 8;
    *(float4*)dst = make_float4(t[0], t[1], t[2], t[3]);
    *(float4*)(dst + 4) = make_float4(t[4], t[5], t[6], t[7]);
  }
}

// ---------------- ctx split-K reduce: fp32 partials -> optional fp32 out + bf16 out
template<bool F32OUT>
__global__ __launch_bounds__(256) void ctx_reduce(const float* __restrict__ part,
                                                  float* __restrict__ outF,
                                                  ushort_t* __restrict__ outB, int split) {
  int idx = blockIdx.x * 256 + threadIdx.x;
  int b = idx >> 16;
  int r = idx & 65535;
  float s = 0.f;
  for (int k = 0; k < split; k++)
    s += part[((size_t)(b * split + k)) * KC_ * VC_ + r];
  if (F32OUT) outF[idx] = s;
  outB[idx] = f2bu(s);
}

__global__ __launch_bounds__(256) void dwgelu_t(const ushort_t* __restrict__ h1t,
    const float* __restrict__ wdwT, const float* __restrict__ bdw,
    ushort_t* __restrict__ actT) {
  int pix = blockIdx.x * 2 + (threadIdx.x >> 7);
  int c = (threadIdx.x & 127) * 8;
  int h = pix >> 7, w = pix & 127;
  float s[8];
  {
    float4 b0 = *(const float4*)&bdw[c];
    float4 b1 = *(const float4*)&bdw[c + 4];
    s[0]=b0.x; s[1]=b0.y; s[2]=b0.z; s[3]=b0.w;
    s[4]=b1.x; s[5]=b1.y; s[6]=b1.z; s[7]=b1.w;
  }
  #pragma unroll
  for (int di = -1; di <= 1; ++di) {
    int h2 = h + di;
    if ((unsigned)h2 >= H_) continue;
    #pragma unroll
    for (int dj = -1; dj <= 1; ++dj) {
      int w2 = w + dj;
      if ((unsigned)w2 >= W_) continue;
      int tap = (di + 1) * 3 + (dj + 1);
      u16x8 v = *(const u16x8*)&h1t[(size_t)(h2 * W_ + w2) * HID_ + c];
      const float* wp = &wdwT[tap * HID_ + c];
      float4 w0 = *(const float4*)wp, w1 = *(const float4*)(wp + 4);
      s[0] += w0.x * bu2f(v[0]); s[1] += w0.y * bu2f(v[1]);
      s[2] += w0.z * bu2f(v[2]); s[3] += w0.w * bu2f(v[3]);
      s[4] += w1.x * bu2f(v[4]); s[5] += w1.y * bu2f(v[5]);
      s[6] += w1.z * bu2f(v[6]); s[7] += w1.w * bu2f(v[7]);
    }
  }
  u16x8 o;
  #pragma unroll
  for (int j = 0; j < 8; j++) {
    float gl = 0.5f * s[j] * (1.f + erff(s[j] * 0.70710678118654752f));
    o[j] = f2bu(gl);
  }
  *(u16x8*)&actT[(size_t)pix * HID_ + c] = o;
}

extern "C" void kernel_launch(void* const* d_in, const int* in_sizes, int n_in,
                              void* d_out, int out_size, void* d_ws, size_t ws_size,
                              hipStream_t stream) {
  const float* x    = (const float*)d_in[0];
  const float* wk1  = (const float*)d_in[3];
  const float* bk1  = (const float*)d_in[4];
  const float* wk2  = (const float*)d_in[5];
  const float* bk2  = (const float*)d_in[6];
  const float* wq1  = (const float*)d_in[7];
  const float* bq1  = (const float*)d_in[8];
  const float* wq2  = (const float*)d_in[9];
  const float* bq2  = (const float*)d_in[10];
  const float* wv   = (const float*)d_in[11];
  const float* bv   = (const float*)d_in[12];
  const float* wr   = (const float*)d_in[13];
  const float* br   = (const float*)d_in[14];
  const float* g1   = (const float*)d_in[15];
  const float* b1   = (const float*)d_in[16];
  const float* g2   = (const float*)d_in[17];
  const float* b2   = (const float*)d_in[18];
  const float* wfc1 = (const float*)d_in[19];
  const float* bfc1 = (const float*)d_in[20];
  const float* wdw  = (const float*)d_in[21];
  const float* bdw  = (const float*)d_in[22];
  const float* wfc2 = (const float*)d_in[23];
  const float* bfc2 = (const float*)d_in[24];

  const size_t big = (size_t)B_ * C_ * N_;
  const long  CN  = (long)C_ * N_;
  const long  NC2 = (long)N_ * C_;

  uint8_t* w8 = (uint8_t*)d_ws;
  size_t off = 0;
  ushort_t* xnt  = (ushort_t*)(w8 + off); off += 67108864;
  ushort_t* kq   = (ushort_t*)(w8 + off); off += 67108864;
  ushort_t* Mbuf = (ushort_t*)(w8 + off); off += (size_t)B_ * C_ * 512 * 2;
  ushort_t* wkkp = (ushort_t*)(w8 + off); off += 6 * KC_ * C_ * 2;
  ushort_t* wqqp = (ushort_t*)(w8 + off); off += 6 * KC_ * C_ * 2;
  ushort_t* wvp  = (ushort_t*)(w8 + off); off += VC_ * C_ * 2;
  ushort_t* wfc1p= (ushort_t*)(w8 + off); off += HID_ * C_ * 2;
  ushort_t* wfc2p= (ushort_t*)(w8 + off); off += C_ * HID_ * 2;
  float* wdwT    = (float*)(w8 + off);    off += 9 * HID_ * 4;
  float* bK      = (float*)(w8 + off);    off += 512 * 4;
  float* bQ      = (float*)(w8 + off);    off += 512 * 4;
  float* fzero   = (float*)(w8 + off);    off += 512 * 4;
  ushort_t* wrp  = (ushort_t*)(w8 + off); off += C_ * 512 * 2;
  ushort_t* ctx0b= (ushort_t*)(w8 + off); off += (size_t)B_ * KC_ * VC_ * 2;
  ushort_t* ctx1b= (ushort_t*)(w8 + off); off += (size_t)B_ * KC_ * VC_ * 2;
  ushort_t* zbuf = (ushort_t*)(w8 + off); off += 1024;
  float* part    = (float*)(w8 + off);
  size_t need4 = off + (size_t)4 * B_ * KC_ * VC_ * 4;
  size_t need8 = off + (size_t)8 * B_ * KC_ * VC_ * 4;
  int csplit;
  if (ws_size >= need8) csplit = 8;
  else if (ws_size >= need4) csplit = 4;
  else return;

  float* mx_out   = (float*)d_out;
  float* ctx_out  = mx_out + big;
  float* amap_out = ctx_out + (size_t)B_ * KC_ * VC_;

  ushort_t* mxlo = (ushort_t*)d_out;            // val -> q1
  ushort_t* mxhi = (ushort_t*)d_out + big;      // K1 -> tx

  ushort_t* txn  = xnt;
  ushort_t* h1t  = kq;
  ushort_t* actT = kq + (size_t)N_ * HID_;

  dim3 blk(256);

  pack_all<<<3878, blk, 0, stream>>>(wk1, wk2, wq1, wq2, wv, wfc1, wfc2, wdw,
                                     bk1, bk2, bq1, bq2, wr,
                                     zbuf, fzero, bK, bQ, wdwT,
                                     wvp, wfc1p, wfc2p, wrp, wkkp, wqqp);

  // LN1 fused
  ln1t_kernel<<<dim3(N_ / 64, 1, B_), blk, 0, stream>>>(x, g1, b1, xnt);

  // val -> mxlo
  mfma_gemm<1, 0, 1, 1, false><<<dim3(N_ / 128, VC_ / 128, B_), blk, 0, stream>>>(
      wvp, 0, C_, 0, 0, xnt, nullptr, NC2, C_, bv, nullptr, nullptr, 0,
      nullptr, mxlo, nullptr, (long)VC_ * N_, N_, C_ / 64, zbuf);

  // fused KK: K0 -> kq, K1 -> mxhi
  mfma_gemm<3, 3, 1, 1, false><<<dim3(N_ / 128, 4, B_), blk, 0, stream>>>(
      wkkp, 0, C_, (long)KC_ * C_, (long)3 * KC_ * C_, xnt, nullptr, NC2, C_,
      bK, nullptr, nullptr, 0,
      nullptr, kq, mxhi, (long)KC_ * N_, N_, C_ / 64, zbuf);

  softmax_spatial2<<<2 * B_ * KC_, blk, 0, stream>>>(kq, mxhi);
  amap2_kernel<<<B_ * N_ / 512, blk, 0, stream>>>(kq, mxhi, amap_out);

  for (int d = 0; d < 2; ++d) {
    const ushort_t* Ksrc = d ? mxhi : kq;
    if (csplit == 8)
      mfma_gemm<1, 0, 6, 8, false><<<dim3(VC_ / 128, KC_ / 128, B_ * 8), blk, 0, stream>>>(
          Ksrc, (long)KC_ * N_, N_, 0, 0, mxlo, nullptr, (long)VC_ * N_, N_,
          nullptr, nullptr, nullptr, 0,
          part, nullptr, nullptr, (long)KC_ * VC_, VC_, (N_ / 8) / 64, zbuf);
    else
      mfma_gemm<1, 0, 6, 4, false><<<dim3(VC_ / 128, KC_ / 128, B_ * 4), blk, 0, stream>>>(
          Ksrc, (long)KC_ * N_, N_, 0, 0, mxlo, nullptr, (long)VC_ * N_, N_,
          nullptr, nullptr, nullptr, 0,
          part, nullptr, nullptr, (long)KC_ * VC_, VC_, (N_ / 4) / 64, zbuf);
    if (d == 0)
      ctx_reduce<false><<<B_ * KC_ * VC_ / 256, blk, 0, stream>>>(part, nullptr, ctx0b, csplit);
    else
      ctx_reduce<true><<<B_ * KC_ * VC_ / 256, blk, 0, stream>>>(part, ctx_out, ctx1b, csplit);
  }

  // fused QQ: q0 -> kq [n][kc], q1 -> mxlo
  mfma_gemm<3, 3, 2, 1, false><<<dim3(N_ / 128, 4, B_), blk, 0, stream>>>(
      wqqp, 0, C_, (long)KC_ * C_, (long)3 * KC_ * C_, xnt, nullptr, NC2, C_,
      bQ, nullptr, nullptr, 0,
      nullptr, kq, mxlo, (long)N_ * KC_, KC_, C_ / 64, zbuf);

  softmax_channel2<<<2 * B_ * N_ / 64, blk, 0, stream>>>(kq, mxlo);

  // Mcat via MFMA: dir0 -> Mbuf[:, 0:256], dir1 -> Mbuf[:, 256:512]
  mfma_gemm<1, 0, 1, 1, false><<<dim3(KC_ / 128, C_ / 128, B_), blk, 0, stream>>>(
      wrp, 0, 512, 0, 0, ctx0b, nullptr, (long)KC_ * VC_, VC_, fzero, nullptr, nullptr, 0,
      nullptr, Mbuf, nullptr, (long)C_ * 512, 512, VC_ / 64, zbuf);
  mfma_gemm<1, 0, 1, 1, false><<<dim3(KC_ / 128, C_ / 128, B_), blk, 0, stream>>>(
      wrp + 256, 0, 512, 0, 0, ctx1b, nullptr, (long)KC_ * VC_, VC_, fzero, nullptr, nullptr, 0,
      nullptr, Mbuf + 256, nullptr, (long)C_ * 512, 512, VC_ / 64, zbuf);

  // fused attention -> tx bf16 @ mxhi
  mfma_gemm<1, 0, 7, 1, true><<<dim3(N_ / 128, C_ / 128, B_), blk, 0, stream>>>(
      Mbuf, (long)C_ * 512, 512, 0, 0, kq, mxlo, (long)N_ * KC_, KC_,
      br, x, nullptr, CN,
      nullptr, mxhi, nullptr, CN, N_, 8, zbuf);

  // LN2 fused: tx -> txn
  ln2t_kernel<<<dim3(N_ / 64, 1, B_), blk, 0, stream>>>(mxhi, g2, b2, txn);

  // preserve tx batch 7 (fc2 b7 writes clobber it)
  hipMemcpyAsync(part, mxhi + (size_t)7 * CN, (size_t)CN * 2,
                 hipMemcpyDeviceToDevice, stream);

  for (int b = 0; b < B_; ++b) {
    mfma_gemm<1, 0, 2, 1, false><<<dim3(N_ / 128, HID_ / 128, 1), blk, 0, stream>>>(
        wfc1p, 0, C_, 0, 0, txn + (size_t)b * NC2, nullptr, 0, C_,
        bfc1, nullptr, nullptr, 0,
        nullptr, h1t, nullptr, 0, HID_, C_ / 64, zbuf);
    dwgelu_t<<<N_ / 2, blk, 0, stream>>>(h1t, wdwT, bdw, actT);
    const ushort_t* txb = (b == 7) ? (const ushort_t*)part : (mxhi + (size_t)b * CN);
    mfma_gemm<1, 0, 8, 1, false><<<dim3(N_ / 128, C_ / 128, 1), blk, 0, stream>>>(
        wfc2p, 0, HID_, 0, 0, actT, nullptr, 0, HID_,
        bfc2, nullptr, txb, 0,
        mx_out + (size_t)b * CN, nullptr, nullptr, 0, N_, HID_ / 64, zbuf);
  }
}

// Round 9
// 1437.205 us; speedup vs baseline: 8.8028x; 1.0306x over previous
//
#include <hip/hip_runtime.h>
#include <hip/hip_bf16.h>

#define B_ 8
#define C_ 256
#define H_ 128
#define W_ 128
#define N_ 16384
#define KC_ 256
#define VC_ 256
#define HID_ 1024

typedef unsigned short ushort_t;
typedef __bf16 bf16x8 __attribute__((ext_vector_type(8)));
typedef float f32x4 __attribute__((ext_vector_type(4)));
typedef ushort_t u16x8 __attribute__((ext_vector_type(8)));

static __device__ __forceinline__ ushort_t f2bu(float f) {
  __hip_bfloat16 h = __float2bfloat16(f);
  return *reinterpret_cast<ushort_t*>(&h);
}
static __device__ __forceinline__ float bu2f(ushort_t u) {
  __hip_bfloat16 h;
  *reinterpret_cast<ushort_t*>(&h) = u;
  return __bfloat162float(h);
}

#define GLD16(gp, lp) __builtin_amdgcn_global_load_lds( \
    (const __attribute__((address_space(1))) void*)(gp), \
    (__attribute__((address_space(3))) void*)(lp), 16, 0, 0)

// ---------------- one-shot weight/bias packing
__global__ __launch_bounds__(256) void pack_all(
    const float* __restrict__ wk1, const float* __restrict__ wk2,
    const float* __restrict__ wq1, const float* __restrict__ wq2,
    const float* __restrict__ wv, const float* __restrict__ wfc1,
    const float* __restrict__ wfc2, const float* __restrict__ wdw,
    const float* __restrict__ bk1, const float* __restrict__ bk2,
    const float* __restrict__ bq1, const float* __restrict__ bq2,
    const float* __restrict__ bv, const float* __restrict__ wr,
    ushort_t* __restrict__ zbuf,
    float* __restrict__ bKV, float* __restrict__ bQ, float* __restrict__ wdwT,
    ushort_t* __restrict__ wvp, ushort_t* __restrict__ wfc1p,
    ushort_t* __restrict__ wfc2p, ushort_t* __restrict__ wrp,
    ushort_t* __restrict__ wkkp, ushort_t* __restrict__ wqqp) {
  int idx = blockIdx.x * 256 + threadIdx.x;
  const int MC = KC_ * C_;
  if (idx < 512) {
    zbuf[idx] = 0;
    bQ[idx] = (idx < 256) ? bq1[idx] : bq2[idx - 256];
    return;
  }
  idx -= 512;
  if (idx < 768) {
    bKV[idx] = (idx < 256) ? bk1[idx] : (idx < 512 ? bk2[idx - 256] : bv[idx - 512]);
    return;
  }
  idx -= 768;
  if (idx < 9216) { int c = idx / 9, t = idx % 9; wdwT[t * HID_ + c] = wdw[idx]; return; }
  idx -= 9216;
  if (idx < VC_ * C_) { wvp[idx] = f2bu(wv[idx]); return; }
  idx -= VC_ * C_;
  if (idx < HID_ * C_) { wfc1p[idx] = f2bu(wfc1[idx]); return; }
  idx -= HID_ * C_;
  if (idx < C_ * HID_) { wfc2p[idx] = f2bu(wfc2[idx]); return; }
  idx -= C_ * HID_;
  if (idx < C_ * 512) { wrp[idx] = f2bu(wr[idx]); return; }
  idx -= C_ * 512;
  if (idx < MC) {
    #pragma unroll
    for (int t = 0; t < 3; ++t) wkkp[t * MC + idx] = f2bu(wk1[idx * 3 + t]);
    return;
  }
  idx -= MC;
  if (idx < MC) {
    #pragma unroll
    for (int t = 0; t < 3; ++t) wkkp[3 * MC + t * MC + idx] = f2bu(wk2[idx * 3 + t]);
    return;
  }
  idx -= MC;
  if (idx < MC) {
    #pragma unroll
    for (int t = 0; t < 3; ++t) wqqp[t * MC + idx] = f2bu(wq1[idx * 3 + t]);
    return;
  }
  idx -= MC;
  if (idx < MC) {
    #pragma unroll
    for (int t = 0; t < 3; ++t) wqqp[3 * MC + t * MC + idx] = f2bu(wq2[idx * 3 + t]);
    return;
  }
}

// ---------------- fused LN1: x fp32 [c][n] -> bf16 [n][c]
__global__ __launch_bounds__(256) void ln1t_kernel(const float* __restrict__ x,
    const float* __restrict__ g, const float* __restrict__ beta,
    ushort_t* __restrict__ out) {
  __shared__ float T[256][67];
  __shared__ float st[2][4][64];
  __shared__ float mr[64], rs[64];
  int z = blockIdx.z;
  int n0 = blockIdx.x * 64;
  int t = threadIdx.x;
  const float* xb = x + (size_t)z * C_ * N_;
  #pragma unroll
  for (int j = 0; j < 16; ++j) {
    int e = (j * 256 + t) * 4;
    int c = e >> 6, n = e & 63;
    float4 v = *(const float4*)&xb[(size_t)c * N_ + n0 + n];
    T[c][n] = v.x; T[c][n + 1] = v.y; T[c][n + 2] = v.z; T[c][n + 3] = v.w;
  }
  __syncthreads();
  {
    int n = t & 63, part = t >> 6;
    float s1 = 0.f, s2 = 0.f;
    for (int c = part * 64; c < part * 64 + 64; ++c) { float v = T[c][n]; s1 += v; s2 += v * v; }
    st[0][part][n] = s1; st[1][part][n] = s2;
  }
  __syncthreads();
  if (t < 64) {
    float s1 = st[0][0][t] + st[0][1][t] + st[0][2][t] + st[0][3][t];
    float s2 = st[1][0][t] + st[1][1][t] + st[1][2][t] + st[1][3][t];
    float m = s1 * (1.f / C_);
    float v = s2 * (1.f / C_) - m * m;
    mr[t] = m; rs[t] = rsqrtf(v + 1e-5f);
  }
  __syncthreads();
  {
    int n = t >> 2, cc = (t & 3) * 64;
    float m = mr[n], r = rs[n];
    ushort_t* po = out + (size_t)z * N_ * C_ + (size_t)(n0 + n) * C_ + cc;
    #pragma unroll
    for (int j0 = 0; j0 < 64; j0 += 8) {
      u16x8 o;
      #pragma unroll
      for (int j = 0; j < 8; ++j) {
        int c = cc + j0 + j;
        o[j] = f2bu((T[c][n] - m) * r * g[c] + beta[c]);
      }
      *(u16x8*)(po + j0) = o;
    }
  }
}

// ---------------- fused LN2: tx bf16 [c][n] -> bf16 [n][c]
__global__ __launch_bounds__(256) void ln2t_kernel(const ushort_t* __restrict__ x,
    const float* __restrict__ g, const float* __restrict__ beta,
    ushort_t* __restrict__ out) {
  __shared__ ushort_t T[256][72];
  __shared__ float st[2][4][64];
  __shared__ float mr[64], rs[64];
  int z = blockIdx.z;
  int n0 = blockIdx.x * 64;
  int t = threadIdx.x;
  const ushort_t* xb = x + (size_t)z * C_ * N_;
  #pragma unroll
  for (int j = 0; j < 8; ++j) {
    int e = (j * 256 + t) * 8;
    int c = e >> 6, n = e & 63;
    *(u16x8*)&T[c][n] = *(const u16x8*)&xb[(size_t)c * N_ + n0 + n];
  }
  __syncthreads();
  {
    int n = t & 63, part = t >> 6;
    float s1 = 0.f, s2 = 0.f;
    for (int c = part * 64; c < part * 64 + 64; ++c) { float v = bu2f(T[c][n]); s1 += v; s2 += v * v; }
    st[0][part][n] = s1; st[1][part][n] = s2;
  }
  __syncthreads();
  if (t < 64) {
    float s1 = st[0][0][t] + st[0][1][t] + st[0][2][t] + st[0][3][t];
    float s2 = st[1][0][t] + st[1][1][t] + st[1][2][t] + st[1][3][t];
    float m = s1 * (1.f / C_);
    float v = s2 * (1.f / C_) - m * m;
    mr[t] = m; rs[t] = rsqrtf(v + 1e-5f);
  }
  __syncthreads();
  {
    int n = t >> 2, cc = (t & 3) * 64;
    float m = mr[n], r = rs[n];
    ushort_t* po = out + (size_t)z * N_ * C_ + (size_t)(n0 + n) * C_ + cc;
    #pragma unroll
    for (int j0 = 0; j0 < 64; j0 += 8) {
      u16x8 o;
      #pragma unroll
      for (int j = 0; j < 8; ++j) {
        int c = cc + j0 + j;
        o[j] = f2bu((bu2f(T[c][n]) - m) * r * g[c] + beta[c]);
      }
      *(u16x8*)(po + j0) = o;
    }
  }
}

// ======================= MFMA GEMM template =======================
// DIMSEL: 0 none; 1 w-shift; 2 h-shift; 3 dual-dir (by0-1 w, by2-3 h);
//         4 triple (by0-1 K0 w, by2-3 K1 h, by4-5 val no-tap)
template<int TAPS, int DIMSEL, int OMODE, int SPLIT, bool BDUAL>
__global__ __launch_bounds__(256) void mfma_gemm(
    const ushort_t* __restrict__ A, long Abatch, int lda, long Aplane, long Adirstride,
    const ushort_t* __restrict__ B, const ushort_t* __restrict__ B2, long Bbatch, int ldb,
    const float* __restrict__ bias,
    const float* __restrict__ resF, const ushort_t* __restrict__ resB, long Resbatch,
    float* __restrict__ outF, ushort_t* __restrict__ outB, ushort_t* __restrict__ outB2,
    ushort_t* __restrict__ outB3,
    long Outbatch, int ldo, int Ksteps, const ushort_t* __restrict__ zbuf) {
  __shared__ ushort_t sm[17408];
  int tid = threadIdx.x;
  int bx = blockIdx.x, by = blockIdx.y, bz = blockIdx.z;
  if (gridDim.x == 128) bx = ((bx & 7) << 4) | (bx >> 3);
  int b = bz / SPLIT, sK = bz % SPLIT;
  long koff = (long)sK * Ksteps * 64;
  int dsel = (DIMSEL == 3) ? (by < 2 ? 1 : 2)
           : (DIMSEL == 4) ? (by < 2 ? 1 : (by < 4 ? 2 : 0))
           : DIMSEL;
  int m0 = (DIMSEL == 3 || DIMSEL == 4) ? ((by & 1) * 128) : (by * 128);
  int bofs = (DIMSEL == 3 || DIMSEL == 4) ? ((by >> 1) * 256) : 0;
  const ushort_t* Ab = A + (size_t)b * Abatch + koff
      + ((DIMSEL == 3 || DIMSEL == 4) ? (long)(by >> 1) * Adirstride : 0L);
  const ushort_t* Bb = B + (size_t)b * Bbatch + (BDUAL ? 0 : koff);
  const ushort_t* B2b = BDUAL ? (B2 + (size_t)b * Bbatch) : nullptr;
  int n0 = bx * 128;
  int lane = tid & 63, wid = tid >> 6, wm = wid >> 1, wn = wid & 1;

  f32x4 acc[4][4];
  #pragma unroll
  for (int i = 0; i < 4; i++)
    #pragma unroll
    for (int j = 0; j < 4; j++) acc[i][j] = (f32x4)0.f;

  for (int t = 0; t < TAPS; ++t) {
    if (TAPS == 3 && dsel == 2) {
      if ((bx == 0 && t == 0) || (bx == H_ - 1 && t == 2)) continue;
    }
    if (DIMSEL == 4 && dsel == 0 && t != 1) continue;
    const ushort_t* At = Ab + ((DIMSEL == 4 && dsel == 0) ? 0L : (long)t * Aplane);
    for (int ks = 0; ks < Ksteps; ++ks) {
      int k0 = ks * 64;
      #pragma unroll
      for (int i = 0; i < 4; i++) {
        int s = tid + i * 256;
        int row = s >> 3, pc = s & 7;
        int lc = pc ^ (row & 7);
        const ushort_t* g = At + (long)(m0 + row) * lda + k0 + lc * 8;
        GLD16(g, &sm[s * 8]);
      }
      #pragma unroll
      for (int i = 0; i < 4; i++) {
        int s = tid + i * 256;
        int row = s >> 3, pc = s & 7;
        int lc = pc ^ (row & 7);
        const ushort_t* g;
        if (BDUAL) {
          const ushort_t* Bsel = (ks < Ksteps / 2) ? Bb : B2b;
          int kb = ((ks < Ksteps / 2) ? ks : ks - Ksteps / 2) * 64;
          g = Bsel + (long)(n0 + row) * ldb + kb + lc * 8;
        } else if (TAPS == 3 && dsel == 1) {
          int wpos = row + (t - 1);
          if (0 <= wpos && wpos < W_)
            g = Bb + (long)(n0 + row + (t - 1)) * ldb + k0 + lc * 8;
          else
            g = zbuf;
        } else if (TAPS == 3 && dsel == 2) {
          g = Bb + (long)(n0 + row + (t - 1) * W_) * ldb + k0 + lc * 8;
        } else {
          g = Bb + (long)(n0 + row) * ldb + k0 + lc * 8;
        }
        GLD16(g, &sm[8192 + s * 8]);
      }
      __syncthreads();
      #pragma unroll
      for (int kk = 0; kk < 2; kk++) {
        bf16x8 av[4], bv[4];
        int r16 = lane & 15;
        int sl = (lane >> 4) + kk * 4;
        #pragma unroll
        for (int fm = 0; fm < 4; fm++) {
          int row = wm * 64 + fm * 16 + r16;
          av[fm] = *(const bf16x8*)&sm[row * 64 + ((sl ^ (row & 7)) * 8)];
        }
        #pragma unroll
        for (int fn = 0; fn < 4; fn++) {
          int row = wn * 64 + fn * 16 + r16;
          bv[fn] = *(const bf16x8*)&sm[8192 + row * 64 + ((sl ^ (row & 7)) * 8)];
        }
        #pragma unroll
        for (int fm = 0; fm < 4; fm++)
          #pragma unroll
          for (int fn = 0; fn < 4; fn++)
            acc[fm][fn] = __builtin_amdgcn_mfma_f32_16x16x32_bf16(av[fm], bv[fn], acc[fm][fn], 0, 0, 0);
      }
      __syncthreads();
    }
  }

  int r16 = lane & 15, rq = lane >> 4;
  if (OMODE == 1 || OMODE == 2 || OMODE == 7) {
    ushort_t* obase;
    if (DIMSEL == 3 || DIMSEL == 4)
      obase = (blockIdx.y >= 4) ? outB3 : (blockIdx.y >= 2 ? outB2 : outB);
    else
      obase = outB;
    ushort_t* ob = obase + (size_t)bz * Outbatch;
    #pragma unroll
    for (int fm = 0; fm < 4; fm++) {
      #pragma unroll
      for (int fn = 0; fn < 4; fn++) {
        int lm = wm * 64 + fm * 16 + rq * 4;
        int ln = wn * 64 + fn * 16 + r16;
        f32x4 a = acc[fm][fn];
        if (OMODE == 2) {
          #pragma unroll
          for (int r = 0; r < 4; r++)
            sm[ln * 136 + lm + r] = f2bu(a[r] + bias[bofs + m0 + lm + r]);
        } else {
          #pragma unroll
          for (int r = 0; r < 4; r++)
            sm[(lm + r) * 136 + ln] = f2bu(a[r] + bias[bofs + m0 + lm + r]);
        }
      }
    }
    __syncthreads();
    int row = tid >> 1, half = (tid & 1) * 64;
    const ushort_t* src = &sm[row * 136 + half];
    if (OMODE == 7) {
      const float* xb = resF + (size_t)bz * Resbatch + (size_t)(m0 + row) * ldo + n0 + half;
      ushort_t* dst = &ob[(size_t)(m0 + row) * ldo + n0 + half];
      #pragma unroll
      for (int j = 0; j < 8; j++) {
        u16x8 v = *(const u16x8*)(src + j * 8);
        float4 x0 = *(const float4*)(xb + j * 8);
        float4 x1 = *(const float4*)(xb + j * 8 + 4);
        u16x8 o;
        o[0] = f2bu(bu2f(v[0]) + x0.x); o[1] = f2bu(bu2f(v[1]) + x0.y);
        o[2] = f2bu(bu2f(v[2]) + x0.z); o[3] = f2bu(bu2f(v[3]) + x0.w);
        o[4] = f2bu(bu2f(v[4]) + x1.x); o[5] = f2bu(bu2f(v[5]) + x1.y);
        o[6] = f2bu(bu2f(v[6]) + x1.z); o[7] = f2bu(bu2f(v[7]) + x1.w);
        *(u16x8*)(dst + j * 8) = o;
      }
    } else {
      ushort_t* dst;
      if (OMODE == 1) dst = &ob[(size_t)(m0 + row) * ldo + n0 + half];
      else            dst = &ob[(size_t)(n0 + row) * ldo + m0 + half];
      #pragma unroll
      for (int j = 0; j < 8; j++)
        *(u16x8*)(dst + j * 8) = *(const u16x8*)(src + j * 8);
    }
  } else {
    #pragma unroll
    for (int fm = 0; fm < 4; fm++) {
      #pragma unroll
      for (int fn = 0; fn < 4; fn++) {
        int mrow = m0 + wm * 64 + fm * 16 + rq * 4;
        int ncol = n0 + wn * 64 + fn * 16 + r16;
        f32x4 a = acc[fm][fn];
        if (OMODE == 6) {
          float* of = outF + (size_t)bz * Outbatch;
          #pragma unroll
          for (int r = 0; r < 4; r++)
            of[(size_t)(mrow + r) * ldo + ncol] = a[r];
        } else if (OMODE == 8) {
          float* of = outF + (size_t)bz * Outbatch;
          const ushort_t* rp = resB + (size_t)bz * Resbatch;
          #pragma unroll
          for (int r = 0; r < 4; r++) {
            size_t o = (size_t)(mrow + r) * ldo + ncol;
            of[o] = a[r] + bias[mrow + r] + bu2f(rp[o]);
          }
        }
      }
    }
  }
}

// ---------------- single-pass spatial softmax (row of 16384 held in registers)
__global__ __launch_bounds__(256) void softmax_spatial2(ushort_t* __restrict__ p0,
                                                        ushort_t* __restrict__ p1) {
  int r = blockIdx.x;
  ushort_t* p = (r < B_ * KC_) ? (p0 + (size_t)r * N_) : (p1 + (size_t)(r - B_ * KC_) * N_);
  int tid = threadIdx.x;
  __shared__ float red[256];
  u16x8 v[8];
  #pragma unroll
  for (int j = 0; j < 8; j++) v[j] = *(const u16x8*)&p[tid * 8 + j * 2048];
  float mx = -1e30f;
  #pragma unroll
  for (int j = 0; j < 8; j++)
    #pragma unroll
    for (int e = 0; e < 8; e++) mx = fmaxf(mx, bu2f(v[j][e]));
  red[tid] = mx; __syncthreads();
  for (int s = 128; s > 0; s >>= 1) { if (tid < s) red[tid] = fmaxf(red[tid], red[tid + s]); __syncthreads(); }
  mx = red[0]; __syncthreads();
  float sum = 0.f;
  #pragma unroll
  for (int j = 0; j < 8; j++)
    #pragma unroll
    for (int e = 0; e < 8; e++) sum += __expf(bu2f(v[j][e]) - mx);
  red[tid] = sum; __syncthreads();
  for (int s = 128; s > 0; s >>= 1) { if (tid < s) red[tid] += red[tid + s]; __syncthreads(); }
  float inv = 1.f / red[0];
  #pragma unroll
  for (int j = 0; j < 8; j++) {
    u16x8 o;
    #pragma unroll
    for (int e = 0; e < 8; e++) o[e] = f2bu(__expf(bu2f(v[j][e]) - mx) * inv);
    *(u16x8*)&p[tid * 8 + j * 2048] = o;
  }
}

// ---------------- single-pass channel softmax: 8 lanes/row, 128-B coalesced segments
__global__ __launch_bounds__(256) void softmax_channel2(ushort_t* __restrict__ p0,
                                                        ushort_t* __restrict__ p1) {
  int tid = threadIdx.x;
  size_t rowg = (size_t)blockIdx.x * 32 + (tid >> 3);
  int part = tid & 7;
  ushort_t* q = (rowg < (size_t)B_ * N_) ? (p0 + rowg * KC_)
                                         : (p1 + (rowg - (size_t)B_ * N_) * KC_);
  u16x8 v[4];
  #pragma unroll
  for (int j = 0; j < 4; j++) v[j] = *(const u16x8*)&q[part * 8 + j * 64];
  float mx = -1e30f;
  #pragma unroll
  for (int j = 0; j < 4; j++)
    #pragma unroll
    for (int e = 0; e < 8; e++) mx = fmaxf(mx, bu2f(v[j][e]));
  mx = fmaxf(mx, __shfl_xor(mx, 1));
  mx = fmaxf(mx, __shfl_xor(mx, 2));
  mx = fmaxf(mx, __shfl_xor(mx, 4));
  float sum = 0.f;
  #pragma unroll
  for (int j = 0; j < 4; j++)
    #pragma unroll
    for (int e = 0; e < 8; e++) sum += __expf(bu2f(v[j][e]) - mx);
  sum += __shfl_xor(sum, 1);
  sum += __shfl_xor(sum, 2);
  sum += __shfl_xor(sum, 4);
  float inv = 1.f / sum;
  #pragma unroll
  for (int j = 0; j < 4; j++) {
    u16x8 o;
    #pragma unroll
    for (int e = 0; e < 8; e++) o[e] = f2bu(__expf(bu2f(v[j][e]) - mx) * inv);
    *(u16x8*)&q[part * 8 + j * 64] = o;
  }
}

// ---------------- amap: vectorized column sums, 4-way c-split, 512 n per block
__global__ __launch_bounds__(256) void amap2_kernel(const ushort_t* __restrict__ k0,
    const ushort_t* __restrict__ k1, float* __restrict__ amap) {
  __shared__ float red[256][8];
  int tid = threadIdx.x;
  int ngrp = tid & 63, part = tid >> 6;
  int nblock = blockIdx.x * 512;
  int b = nblock >> 14;
  int n = (nblock & 16383) + ngrp * 8;
  const ushort_t* b0 = k0 + (size_t)b * KC_ * N_ + n;
  const ushort_t* b1 = k1 + (size_t)b * KC_ * N_ + n;
  float s[8];
  #pragma unroll
  for (int j = 0; j < 8; j++) s[j] = 0.f;
  for (int c = part * 64; c < part * 64 + 64; ++c) {
    u16x8 a = *(const u16x8*)&b0[(size_t)c * N_];
    u16x8 d = *(const u16x8*)&b1[(size_t)c * N_];
    #pragma unroll
    for (int j = 0; j < 8; j++) s[j] += bu2f(a[j]) + bu2f(d[j]);
  }
  #pragma unroll
  for (int j = 0; j < 8; j++) red[tid][j] = s[j];
  __syncthreads();
  if (tid < 64) {
    float t[8];
    #pragma unroll
    for (int j = 0; j < 8; j++)
      t[j] = (red[tid][j] + red[tid + 64][j] + red[tid + 128][j] + red[tid + 192][j])
             * (1.f / (2.f * KC_));
    float* dst = amap + (size_t)nblock + tid * 8;
    *(float4*)dst = make_float4(t[0], t[1], t[2], t[3]);
    *(float4*)(dst + 4) = make_float4(t[4], t[5], t[6], t[7]);
  }
}

// ---------------- ctx split-K reduce: fp32 partials -> optional fp32 out + bf16 out
template<bool F32OUT>
__global__ __launch_bounds__(256) void ctx_reduce(const float* __restrict__ part,
                                                  float* __restrict__ outF,
                                                  ushort_t* __restrict__ outB, int split) {
  int idx = blockIdx.x * 256 + threadIdx.x;
  int b = idx >> 16;
  int r = idx & 65535;
  float s = 0.f;
  for (int k = 0; k < split; k++)
    s += part[((size_t)(b * split + k)) * KC_ * VC_ + r];
  if (F32OUT) outF[idx] = s;
  outB[idx] = f2bu(s);
}

__global__ __launch_bounds__(256) void dwgelu_t(const ushort_t* __restrict__ h1t,
    const float* __restrict__ wdwT, const float* __restrict__ bdw,
    ushort_t* __restrict__ actT) {
  int pix = blockIdx.x * 2 + (threadIdx.x >> 7);
  int c = (threadIdx.x & 127) * 8;
  int h = pix >> 7, w = pix & 127;
  float s[8];
  {
    float4 b0 = *(const float4*)&bdw[c];
    float4 b1 = *(const float4*)&bdw[c + 4];
    s[0]=b0.x; s[1]=b0.y; s[2]=b0.z; s[3]=b0.w;
    s[4]=b1.x; s[5]=b1.y; s[6]=b1.z; s[7]=b1.w;
  }
  #pragma unroll
  for (int di = -1; di <= 1; ++di) {
    int h2 = h + di;
    if ((unsigned)h2 >= H_) continue;
    #pragma unroll
    for (int dj = -1; dj <= 1; ++dj) {
      int w2 = w + dj;
      if ((unsigned)w2 >= W_) continue;
      int tap = (di + 1) * 3 + (dj + 1);
      u16x8 v = *(const u16x8*)&h1t[(size_t)(h2 * W_ + w2) * HID_ + c];
      const float* wp = &wdwT[tap * HID_ + c];
      float4 w0 = *(const float4*)wp, w1 = *(const float4*)(wp + 4);
      s[0] += w0.x * bu2f(v[0]); s[1] += w0.y * bu2f(v[1]);
      s[2] += w0.z * bu2f(v[2]); s[3] += w0.w * bu2f(v[3]);
      s[4] += w1.x * bu2f(v[4]); s[5] += w1.y * bu2f(v[5]);
      s[6] += w1.z * bu2f(v[6]); s[7] += w1.w * bu2f(v[7]);
    }
  }
  u16x8 o;
  #pragma unroll
  for (int j = 0; j < 8; j++) {
    float gl = 0.5f * s[j] * (1.f + erff(s[j] * 0.70710678118654752f));
    o[j] = f2bu(gl);
  }
  *(u16x8*)&actT[(size_t)pix * HID_ + c] = o;
}

extern "C" void kernel_launch(void* const* d_in, const int* in_sizes, int n_in,
                              void* d_out, int out_size, void* d_ws, size_t ws_size,
                              hipStream_t stream) {
  const float* x    = (const float*)d_in[0];
  const float* wk1  = (const float*)d_in[3];
  const float* bk1  = (const float*)d_in[4];
  const float* wk2  = (const float*)d_in[5];
  const float* bk2  = (const float*)d_in[6];
  const float* wq1  = (const float*)d_in[7];
  const float* bq1  = (const float*)d_in[8];
  const float* wq2  = (const float*)d_in[9];
  const float* bq2  = (const float*)d_in[10];
  const float* wv   = (const float*)d_in[11];
  const float* bv   = (const float*)d_in[12];
  const float* wr   = (const float*)d_in[13];
  const float* br   = (const float*)d_in[14];
  const float* g1   = (const float*)d_in[15];
  const float* b1   = (const float*)d_in[16];
  const float* g2   = (const float*)d_in[17];
  const float* b2   = (const float*)d_in[18];
  const float* wfc1 = (const float*)d_in[19];
  const float* bfc1 = (const float*)d_in[20];
  const float* wdw  = (const float*)d_in[21];
  const float* bdw  = (const float*)d_in[22];
  const float* wfc2 = (const float*)d_in[23];
  const float* bfc2 = (const float*)d_in[24];

  const size_t big = (size_t)B_ * C_ * N_;
  const long  CN  = (long)C_ * N_;
  const long  NC2 = (long)N_ * C_;
  const int   MC  = KC_ * C_;

  uint8_t* w8 = (uint8_t*)d_ws;
  size_t off = 0;
  ushort_t* xnt  = (ushort_t*)(w8 + off); off += 67108864;
  ushort_t* kq   = (ushort_t*)(w8 + off); off += 67108864;
  ushort_t* Mbuf = (ushort_t*)(w8 + off); off += (size_t)B_ * C_ * 512 * 2;
  ushort_t* wkkp = (ushort_t*)(w8 + off); off += 6 * MC * 2;
  ushort_t* wvp  = (ushort_t*)(w8 + off); off += MC * 2;       // contiguous after wkkp!
  ushort_t* wqqp = (ushort_t*)(w8 + off); off += 6 * MC * 2;
  ushort_t* wfc1p= (ushort_t*)(w8 + off); off += HID_ * C_ * 2;
  ushort_t* wfc2p= (ushort_t*)(w8 + off); off += C_ * HID_ * 2;
  float* wdwT    = (float*)(w8 + off);    off += 9 * HID_ * 4;
  float* bKV     = (float*)(w8 + off);    off += 768 * 4;
  float* bQ      = (float*)(w8 + off);    off += 512 * 4;
  ushort_t* wrp  = (ushort_t*)(w8 + off); off += C_ * 512 * 2;
  ushort_t* ctx0b= (ushort_t*)(w8 + off); off += (size_t)B_ * KC_ * VC_ * 2;
  ushort_t* ctx1b= (ushort_t*)(w8 + off); off += (size_t)B_ * KC_ * VC_ * 2;
  ushort_t* zbuf = (ushort_t*)(w8 + off); off += 1024;
  float* part    = (float*)(w8 + off);
  size_t need4 = off + (size_t)4 * B_ * KC_ * VC_ * 4;
  size_t need8 = off + (size_t)8 * B_ * KC_ * VC_ * 4;
  int csplit;
  if (ws_size >= need8) csplit = 8;
  else if (ws_size >= need4) csplit = 4;
  else return;
  const float* fzero = (const float*)zbuf;   // 256 fp32 zeros

  float* mx_out   = (float*)d_out;
  float* ctx_out  = mx_out + big;
  float* amap_out = ctx_out + (size_t)B_ * KC_ * VC_;

  ushort_t* mxlo = (ushort_t*)d_out;            // val -> q1
  ushort_t* mxhi = (ushort_t*)d_out + big;      // K1 -> tx

  ushort_t* txn  = xnt;
  ushort_t* h1t  = kq;
  ushort_t* actT = kq + (size_t)N_ * HID_;

  dim3 blk(256);

  pack_all<<<3881, blk, 0, stream>>>(wk1, wk2, wq1, wq2, wv, wfc1, wfc2, wdw,
                                     bk1, bk2, bq1, bq2, bv, wr,
                                     zbuf, bKV, bQ, wdwT,
                                     wvp, wfc1p, wfc2p, wrp, wkkp, wqqp);

  // LN1 fused
  ln1t_kernel<<<dim3(N_ / 64, 1, B_), blk, 0, stream>>>(x, g1, b1, xnt);

  // fused KKV: K0 -> kq, K1 -> mxhi, val -> mxlo  (one dispatch, shared xnt B-slab)
  mfma_gemm<3, 4, 1, 1, false><<<dim3(N_ / 128, 6, B_), blk, 0, stream>>>(
      wkkp, 0, C_, (long)MC, (long)3 * MC, xnt, nullptr, NC2, C_,
      bKV, nullptr, nullptr, 0,
      nullptr, kq, mxhi, mxlo, (long)KC_ * N_, N_, C_ / 64, zbuf);

  softmax_spatial2<<<2 * B_ * KC_, blk, 0, stream>>>(kq, mxhi);
  amap2_kernel<<<B_ * N_ / 512, blk, 0, stream>>>(kq, mxhi, amap_out);

  for (int d = 0; d < 2; ++d) {
    const ushort_t* Ksrc = d ? mxhi : kq;
    if (csplit == 8)
      mfma_gemm<1, 0, 6, 8, false><<<dim3(VC_ / 128, KC_ / 128, B_ * 8), blk, 0, stream>>>(
          Ksrc, (long)KC_ * N_, N_, 0, 0, mxlo, nullptr, (long)VC_ * N_, N_,
          nullptr, nullptr, nullptr, 0,
          part, nullptr, nullptr, nullptr, (long)KC_ * VC_, VC_, (N_ / 8) / 64, zbuf);
    else
      mfma_gemm<1, 0, 6, 4, false><<<dim3(VC_ / 128, KC_ / 128, B_ * 4), blk, 0, stream>>>(
          Ksrc, (long)KC_ * N_, N_, 0, 0, mxlo, nullptr, (long)VC_ * N_, N_,
          nullptr, nullptr, nullptr, 0,
          part, nullptr, nullptr, nullptr, (long)KC_ * VC_, VC_, (N_ / 4) / 64, zbuf);
    if (d == 0)
      ctx_reduce<false><<<B_ * KC_ * VC_ / 256, blk, 0, stream>>>(part, nullptr, ctx0b, csplit);
    else
      ctx_reduce<true><<<B_ * KC_ * VC_ / 256, blk, 0, stream>>>(part, ctx_out, ctx1b, csplit);
  }

  // fused QQ: q0 -> kq [n][kc], q1 -> mxlo
  mfma_gemm<3, 3, 2, 1, false><<<dim3(N_ / 128, 4, B_), blk, 0, stream>>>(
      wqqp, 0, C_, (long)MC, (long)3 * MC, xnt, nullptr, NC2, C_,
      bQ, nullptr, nullptr, 0,
      nullptr, kq, mxlo, nullptr, (long)N_ * KC_, KC_, C_ / 64, zbuf);

  softmax_channel2<<<2 * B_ * N_ / 32, blk, 0, stream>>>(kq, mxlo);

  // Mcat via MFMA: dir0 -> Mbuf[:, 0:256], dir1 -> Mbuf[:, 256:512]
  mfma_gemm<1, 0, 1, 1, false><<<dim3(KC_ / 128, C_ / 128, B_), blk, 0, stream>>>(
      wrp, 0, 512, 0, 0, ctx0b, nullptr, (long)KC_ * VC_, VC_, fzero, nullptr, nullptr, 0,
      nullptr, Mbuf, nullptr, nullptr, (long)C_ * 512, 512, VC_ / 64, zbuf);
  mfma_gemm<1, 0, 1, 1, false><<<dim3(KC_ / 128, C_ / 128, B_), blk, 0, stream>>>(
      wrp + 256, 0, 512, 0, 0, ctx1b, nullptr, (long)KC_ * VC_, VC_, fzero, nullptr, nullptr, 0,
      nullptr, Mbuf + 256, nullptr, nullptr, (long)C_ * 512, 512, VC_ / 64, zbuf);

  // fused attention -> tx bf16 @ mxhi
  mfma_gemm<1, 0, 7, 1, true><<<dim3(N_ / 128, C_ / 128, B_), blk, 0, stream>>>(
      Mbuf, (long)C_ * 512, 512, 0, 0, kq, mxlo, (long)N_ * KC_, KC_,
      br, x, nullptr, CN,
      nullptr, mxhi, nullptr, nullptr, CN, N_, 8, zbuf);

  // LN2 fused: tx -> txn
  ln2t_kernel<<<dim3(N_ / 64, 1, B_), blk, 0, stream>>>(mxhi, g2, b2, txn);

  // preserve tx batch 7 (fc2 b7 writes clobber it)
  hipMemcpyAsync(part, mxhi + (size_t)7 * CN, (size_t)CN * 2,
                 hipMemcpyDeviceToDevice, stream);

  for (int b = 0; b < B_; ++b) {
    mfma_gemm<1, 0, 2, 1, false><<<dim3(N_ / 128, HID_ / 128, 1), blk, 0, stream>>>(
        wfc1p, 0, C_, 0, 0, txn + (size_t)b * NC2, nullptr, 0, C_,
        bfc1, nullptr, nullptr, 0,
        nullptr, h1t, nullptr, nullptr, 0, HID_, C_ / 64, zbuf);
    dwgelu_t<<<N_ / 2, blk, 0, stream>>>(h1t, wdwT, bdw, actT);
    const ushort_t* txb = (b == 7) ? (const ushort_t*)part : (mxhi + (size_t)b * CN);
    mfma_gemm<1, 0, 8, 1, false><<<dim3(N_ / 128, C_ / 128, 1), blk, 0, stream>>>(
        wfc2p, 0, HID_, 0, 0, actT, nullptr, 0, HID_,
        bfc2, nullptr, txb, 0,
        mx_out + (size_t)b * CN, nullptr, nullptr, nullptr, 0, N_, HID_ / 64, zbuf);
  }
}

// Round 10
// 1333.996 us; speedup vs baseline: 9.4839x; 1.0774x over previous
//
#include <hip/hip_runtime.h>
#include <hip/hip_bf16.h>

#define B_ 8
#define C_ 256
#define H_ 128
#define W_ 128
#define N_ 16384
#define KC_ 256
#define VC_ 256
#define HID_ 1024

typedef unsigned short ushort_t;
typedef __bf16 bf16x8 __attribute__((ext_vector_type(8)));
typedef float f32x4 __attribute__((ext_vector_type(4)));
typedef ushort_t u16x8 __attribute__((ext_vector_type(8)));

static __device__ __forceinline__ ushort_t f2bu(float f) {
  __hip_bfloat16 h = __float2bfloat16(f);
  return *reinterpret_cast<ushort_t*>(&h);
}
static __device__ __forceinline__ float bu2f(ushort_t u) {
  __hip_bfloat16 h;
  *reinterpret_cast<ushort_t*>(&h) = u;
  return __bfloat162float(h);
}

#define GLD16(gp, lp) __builtin_amdgcn_global_load_lds( \
    (const __attribute__((address_space(1))) void*)(gp), \
    (__attribute__((address_space(3))) void*)(lp), 16, 0, 0)

// ---------------- one-shot weight/bias packing
__global__ __launch_bounds__(256) void pack_all(
    const float* __restrict__ wk1, const float* __restrict__ wk2,
    const float* __restrict__ wq1, const float* __restrict__ wq2,
    const float* __restrict__ wv, const float* __restrict__ wfc1,
    const float* __restrict__ wfc2, const float* __restrict__ wdw,
    const float* __restrict__ bk1, const float* __restrict__ bk2,
    const float* __restrict__ bq1, const float* __restrict__ bq2,
    const float* __restrict__ bv, const float* __restrict__ wr,
    ushort_t* __restrict__ zbuf,
    float* __restrict__ bKV, float* __restrict__ bQ, float* __restrict__ wdwT,
    ushort_t* __restrict__ wvp, ushort_t* __restrict__ wfc1p,
    ushort_t* __restrict__ wfc2p, ushort_t* __restrict__ wrp,
    ushort_t* __restrict__ wkkp, ushort_t* __restrict__ wqqp) {
  int idx = blockIdx.x * 256 + threadIdx.x;
  const int MC = KC_ * C_;
  if (idx < 512) {
    zbuf[idx] = 0;
    bQ[idx] = (idx < 256) ? bq1[idx] : bq2[idx - 256];
    return;
  }
  idx -= 512;
  if (idx < 768) {
    bKV[idx] = (idx < 256) ? bk1[idx] : (idx < 512 ? bk2[idx - 256] : bv[idx - 512]);
    return;
  }
  idx -= 768;
  if (idx < 9216) { int c = idx / 9, t = idx % 9; wdwT[t * HID_ + c] = wdw[idx]; return; }
  idx -= 9216;
  if (idx < VC_ * C_) { wvp[idx] = f2bu(wv[idx]); return; }
  idx -= VC_ * C_;
  if (idx < HID_ * C_) { wfc1p[idx] = f2bu(wfc1[idx]); return; }
  idx -= HID_ * C_;
  if (idx < C_ * HID_) { wfc2p[idx] = f2bu(wfc2[idx]); return; }
  idx -= C_ * HID_;
  if (idx < C_ * 512) { wrp[idx] = f2bu(wr[idx]); return; }
  idx -= C_ * 512;
  if (idx < MC) {
    #pragma unroll
    for (int t = 0; t < 3; ++t) wkkp[t * MC + idx] = f2bu(wk1[idx * 3 + t]);
    return;
  }
  idx -= MC;
  if (idx < MC) {
    #pragma unroll
    for (int t = 0; t < 3; ++t) wkkp[3 * MC + t * MC + idx] = f2bu(wk2[idx * 3 + t]);
    return;
  }
  idx -= MC;
  if (idx < MC) {
    #pragma unroll
    for (int t = 0; t < 3; ++t) wqqp[t * MC + idx] = f2bu(wq1[idx * 3 + t]);
    return;
  }
  idx -= MC;
  if (idx < MC) {
    #pragma unroll
    for (int t = 0; t < 3; ++t) wqqp[3 * MC + t * MC + idx] = f2bu(wq2[idx * 3 + t]);
    return;
  }
}

// ---------------- fused LN1: x fp32 [c][n] -> bf16 [n][c]
__global__ __launch_bounds__(256) void ln1t_kernel(const float* __restrict__ x,
    const float* __restrict__ g, const float* __restrict__ beta,
    ushort_t* __restrict__ out) {
  __shared__ float T[256][67];
  __shared__ float st[2][4][64];
  __shared__ float mr[64], rs[64];
  int z = blockIdx.z;
  int n0 = blockIdx.x * 64;
  int t = threadIdx.x;
  const float* xb = x + (size_t)z * C_ * N_;
  #pragma unroll
  for (int j = 0; j < 16; ++j) {
    int e = (j * 256 + t) * 4;
    int c = e >> 6, n = e & 63;
    float4 v = *(const float4*)&xb[(size_t)c * N_ + n0 + n];
    T[c][n] = v.x; T[c][n + 1] = v.y; T[c][n + 2] = v.z; T[c][n + 3] = v.w;
  }
  __syncthreads();
  {
    int n = t & 63, part = t >> 6;
    float s1 = 0.f, s2 = 0.f;
    for (int c = part * 64; c < part * 64 + 64; ++c) { float v = T[c][n]; s1 += v; s2 += v * v; }
    st[0][part][n] = s1; st[1][part][n] = s2;
  }
  __syncthreads();
  if (t < 64) {
    float s1 = st[0][0][t] + st[0][1][t] + st[0][2][t] + st[0][3][t];
    float s2 = st[1][0][t] + st[1][1][t] + st[1][2][t] + st[1][3][t];
    float m = s1 * (1.f / C_);
    float v = s2 * (1.f / C_) - m * m;
    mr[t] = m; rs[t] = rsqrtf(v + 1e-5f);
  }
  __syncthreads();
  {
    int n = t >> 2, cc = (t & 3) * 64;
    float m = mr[n], r = rs[n];
    ushort_t* po = out + (size_t)z * N_ * C_ + (size_t)(n0 + n) * C_ + cc;
    #pragma unroll
    for (int j0 = 0; j0 < 64; j0 += 8) {
      u16x8 o;
      #pragma unroll
      for (int j = 0; j < 8; ++j) {
        int c = cc + j0 + j;
        o[j] = f2bu((T[c][n] - m) * r * g[c] + beta[c]);
      }
      *(u16x8*)(po + j0) = o;
    }
  }
}

// ---------------- fused LN2: tx bf16 [c][n] -> bf16 [n][c]
__global__ __launch_bounds__(256) void ln2t_kernel(const ushort_t* __restrict__ x,
    const float* __restrict__ g, const float* __restrict__ beta,
    ushort_t* __restrict__ out) {
  __shared__ ushort_t T[256][72];
  __shared__ float st[2][4][64];
  __shared__ float mr[64], rs[64];
  int z = blockIdx.z;
  int n0 = blockIdx.x * 64;
  int t = threadIdx.x;
  const ushort_t* xb = x + (size_t)z * C_ * N_;
  #pragma unroll
  for (int j = 0; j < 8; ++j) {
    int e = (j * 256 + t) * 8;
    int c = e >> 6, n = e & 63;
    *(u16x8*)&T[c][n] = *(const u16x8*)&xb[(size_t)c * N_ + n0 + n];
  }
  __syncthreads();
  {
    int n = t & 63, part = t >> 6;
    float s1 = 0.f, s2 = 0.f;
    for (int c = part * 64; c < part * 64 + 64; ++c) { float v = bu2f(T[c][n]); s1 += v; s2 += v * v; }
    st[0][part][n] = s1; st[1][part][n] = s2;
  }
  __syncthreads();
  if (t < 64) {
    float s1 = st[0][0][t] + st[0][1][t] + st[0][2][t] + st[0][3][t];
    float s2 = st[1][0][t] + st[1][1][t] + st[1][2][t] + st[1][3][t];
    float m = s1 * (1.f / C_);
    float v = s2 * (1.f / C_) - m * m;
    mr[t] = m; rs[t] = rsqrtf(v + 1e-5f);
  }
  __syncthreads();
  {
    int n = t >> 2, cc = (t & 3) * 64;
    float m = mr[n], r = rs[n];
    ushort_t* po = out + (size_t)z * N_ * C_ + (size_t)(n0 + n) * C_ + cc;
    #pragma unroll
    for (int j0 = 0; j0 < 64; j0 += 8) {
      u16x8 o;
      #pragma unroll
      for (int j = 0; j < 8; ++j) {
        int c = cc + j0 + j;
        o[j] = f2bu((bu2f(T[c][n]) - m) * r * g[c] + beta[c]);
      }
      *(u16x8*)(po + j0) = o;
    }
  }
}

// ======================= MFMA GEMM template =======================
// DIMSEL: 0 none; 1 w-shift; 2 h-shift; 3 dual-dir; 4 triple (K0 w, K1 h, val)
// BSOFT: B-loader applies channel-softmax exp((x-mx)*inv) from qstats (BDUAL only)
template<int TAPS, int DIMSEL, int OMODE, int SPLIT, bool BDUAL, bool BSOFT>
__global__ __launch_bounds__(256) void mfma_gemm(
    const ushort_t* __restrict__ A, long Abatch, int lda, long Aplane, long Adirstride,
    const ushort_t* __restrict__ B, const ushort_t* __restrict__ B2, long Bbatch, int ldb,
    const float* __restrict__ bias,
    const float* __restrict__ resF, const ushort_t* __restrict__ resB, long Resbatch,
    float* __restrict__ outF, ushort_t* __restrict__ outB, ushort_t* __restrict__ outB2,
    ushort_t* __restrict__ outB3,
    long Outbatch, int ldo, int Ksteps, const ushort_t* __restrict__ zbuf,
    const float2* __restrict__ qstats) {
  __shared__ ushort_t sm[17408];
  int tid = threadIdx.x;
  int bx = blockIdx.x, by = blockIdx.y, bz = blockIdx.z;
  if (gridDim.x == 128) bx = ((bx & 7) << 4) | (bx >> 3);
  int b = bz / SPLIT, sK = bz % SPLIT;
  long koff = (long)sK * Ksteps * 64;
  int dsel = (DIMSEL == 3) ? (by < 2 ? 1 : 2)
           : (DIMSEL == 4) ? (by < 2 ? 1 : (by < 4 ? 2 : 0))
           : DIMSEL;
  int m0 = (DIMSEL == 3 || DIMSEL == 4) ? ((by & 1) * 128) : (by * 128);
  int bofs = (DIMSEL == 3 || DIMSEL == 4) ? ((by >> 1) * 256) : 0;
  const ushort_t* Ab = A + (size_t)b * Abatch + koff
      + ((DIMSEL == 3 || DIMSEL == 4) ? (long)(by >> 1) * Adirstride : 0L);
  const ushort_t* Bb = B + (size_t)b * Bbatch + (BDUAL ? 0 : koff);
  const ushort_t* B2b = BDUAL ? (B2 + (size_t)b * Bbatch) : nullptr;
  int n0 = bx * 128;
  int lane = tid & 63, wid = tid >> 6, wm = wid >> 1, wn = wid & 1;

  f32x4 acc[4][4];
  #pragma unroll
  for (int i = 0; i < 4; i++)
    #pragma unroll
    for (int j = 0; j < 4; j++) acc[i][j] = (f32x4)0.f;

  for (int t = 0; t < TAPS; ++t) {
    if (TAPS == 3 && dsel == 2) {
      if ((bx == 0 && t == 0) || (bx == H_ - 1 && t == 2)) continue;
    }
    if (DIMSEL == 4 && dsel == 0 && t != 1) continue;
    const ushort_t* At = Ab + ((DIMSEL == 4 && dsel == 0) ? 0L : (long)t * Aplane);
    for (int ks = 0; ks < Ksteps; ++ks) {
      int k0 = ks * 64;
      #pragma unroll
      for (int i = 0; i < 4; i++) {
        int s = tid + i * 256;
        int row = s >> 3, pc = s & 7;
        int lc = pc ^ (row & 7);
        const ushort_t* g = At + (long)(m0 + row) * lda + k0 + lc * 8;
        GLD16(g, &sm[s * 8]);
      }
      if (BDUAL && BSOFT) {
        int dir = (ks < Ksteps / 2) ? 0 : 1;
        const ushort_t* Bsel = dir ? B2b : Bb;
        int kb = (ks - dir * (Ksteps / 2)) * 64;
        #pragma unroll
        for (int i = 0; i < 4; i++) {
          int s = tid + i * 256;
          int row = s >> 3, pc = s & 7;
          int lc = pc ^ (row & 7);
          u16x8 e = *(const u16x8*)(Bsel + (long)(n0 + row) * ldb + kb + lc * 8);
          float2 st = qstats[(size_t)dir * B_ * N_ + (size_t)bz * N_ + n0 + row];
          u16x8 o;
          #pragma unroll
          for (int j = 0; j < 8; j++)
            o[j] = f2bu(__expf(bu2f(e[j]) - st.x) * st.y);
          *(u16x8*)&sm[8192 + s * 8] = o;
        }
      } else {
        #pragma unroll
        for (int i = 0; i < 4; i++) {
          int s = tid + i * 256;
          int row = s >> 3, pc = s & 7;
          int lc = pc ^ (row & 7);
          const ushort_t* g;
          if (BDUAL) {
            const ushort_t* Bsel = (ks < Ksteps / 2) ? Bb : B2b;
            int kb = ((ks < Ksteps / 2) ? ks : ks - Ksteps / 2) * 64;
            g = Bsel + (long)(n0 + row) * ldb + kb + lc * 8;
          } else if (TAPS == 3 && dsel == 1) {
            int wpos = row + (t - 1);
            if (0 <= wpos && wpos < W_)
              g = Bb + (long)(n0 + row + (t - 1)) * ldb + k0 + lc * 8;
            else
              g = zbuf;
          } else if (TAPS == 3 && dsel == 2) {
            g = Bb + (long)(n0 + row + (t - 1) * W_) * ldb + k0 + lc * 8;
          } else {
            g = Bb + (long)(n0 + row) * ldb + k0 + lc * 8;
          }
          GLD16(g, &sm[8192 + s * 8]);
        }
      }
      __syncthreads();
      #pragma unroll
      for (int kk = 0; kk < 2; kk++) {
        bf16x8 av[4], bv[4];
        int r16 = lane & 15;
        int sl = (lane >> 4) + kk * 4;
        #pragma unroll
        for (int fm = 0; fm < 4; fm++) {
          int row = wm * 64 + fm * 16 + r16;
          av[fm] = *(const bf16x8*)&sm[row * 64 + ((sl ^ (row & 7)) * 8)];
        }
        #pragma unroll
        for (int fn = 0; fn < 4; fn++) {
          int row = wn * 64 + fn * 16 + r16;
          bv[fn] = *(const bf16x8*)&sm[8192 + row * 64 + ((sl ^ (row & 7)) * 8)];
        }
        #pragma unroll
        for (int fm = 0; fm < 4; fm++)
          #pragma unroll
          for (int fn = 0; fn < 4; fn++)
            acc[fm][fn] = __builtin_amdgcn_mfma_f32_16x16x32_bf16(av[fm], bv[fn], acc[fm][fn], 0, 0, 0);
      }
      __syncthreads();
    }
  }

  int r16 = lane & 15, rq = lane >> 4;
  if (OMODE == 1 || OMODE == 2 || OMODE == 7) {
    ushort_t* obase;
    if (DIMSEL == 3 || DIMSEL == 4)
      obase = (blockIdx.y >= 4) ? outB3 : (blockIdx.y >= 2 ? outB2 : outB);
    else
      obase = outB;
    ushort_t* ob = obase + (size_t)bz * Outbatch;
    #pragma unroll
    for (int fm = 0; fm < 4; fm++) {
      #pragma unroll
      for (int fn = 0; fn < 4; fn++) {
        int lm = wm * 64 + fm * 16 + rq * 4;
        int ln = wn * 64 + fn * 16 + r16;
        f32x4 a = acc[fm][fn];
        if (OMODE == 2) {
          #pragma unroll
          for (int r = 0; r < 4; r++)
            sm[ln * 136 + lm + r] = f2bu(a[r] + bias[bofs + m0 + lm + r]);
        } else {
          #pragma unroll
          for (int r = 0; r < 4; r++)
            sm[(lm + r) * 136 + ln] = f2bu(a[r] + bias[bofs + m0 + lm + r]);
        }
      }
    }
    __syncthreads();
    int row = tid >> 1, half = (tid & 1) * 64;
    const ushort_t* src = &sm[row * 136 + half];
    if (OMODE == 7) {
      const float* xb = resF + (size_t)bz * Resbatch + (size_t)(m0 + row) * ldo + n0 + half;
      ushort_t* dst = &ob[(size_t)(m0 + row) * ldo + n0 + half];
      #pragma unroll
      for (int j = 0; j < 8; j++) {
        u16x8 v = *(const u16x8*)(src + j * 8);
        float4 x0 = *(const float4*)(xb + j * 8);
        float4 x1 = *(const float4*)(xb + j * 8 + 4);
        u16x8 o;
        o[0] = f2bu(bu2f(v[0]) + x0.x); o[1] = f2bu(bu2f(v[1]) + x0.y);
        o[2] = f2bu(bu2f(v[2]) + x0.z); o[3] = f2bu(bu2f(v[3]) + x0.w);
        o[4] = f2bu(bu2f(v[4]) + x1.x); o[5] = f2bu(bu2f(v[5]) + x1.y);
        o[6] = f2bu(bu2f(v[6]) + x1.z); o[7] = f2bu(bu2f(v[7]) + x1.w);
        *(u16x8*)(dst + j * 8) = o;
      }
    } else {
      ushort_t* dst;
      if (OMODE == 1) dst = &ob[(size_t)(m0 + row) * ldo + n0 + half];
      else            dst = &ob[(size_t)(n0 + row) * ldo + m0 + half];
      #pragma unroll
      for (int j = 0; j < 8; j++)
        *(u16x8*)(dst + j * 8) = *(const u16x8*)(src + j * 8);
    }
  } else {
    #pragma unroll
    for (int fm = 0; fm < 4; fm++) {
      #pragma unroll
      for (int fn = 0; fn < 4; fn++) {
        int mrow = m0 + wm * 64 + fm * 16 + rq * 4;
        int ncol = n0 + wn * 64 + fn * 16 + r16;
        f32x4 a = acc[fm][fn];
        if (OMODE == 6) {
          float* of = outF + (size_t)bz * Outbatch;
          #pragma unroll
          for (int r = 0; r < 4; r++)
            of[(size_t)(mrow + r) * ldo + ncol] = a[r];
        } else if (OMODE == 8) {
          float* of = outF + (size_t)bz * Outbatch;
          const ushort_t* rp = resB + (size_t)bz * Resbatch;
          #pragma unroll
          for (int r = 0; r < 4; r++) {
            size_t o = (size_t)(mrow + r) * ldo + ncol;
            of[o] = a[r] + bias[mrow + r] + bu2f(rp[o]);
          }
        }
      }
    }
  }
}

// ---------------- single-pass spatial softmax (row of 16384 held in registers)
__global__ __launch_bounds__(256) void softmax_spatial2(ushort_t* __restrict__ p0,
                                                        ushort_t* __restrict__ p1) {
  int r = blockIdx.x;
  ushort_t* p = (r < B_ * KC_) ? (p0 + (size_t)r * N_) : (p1 + (size_t)(r - B_ * KC_) * N_);
  int tid = threadIdx.x;
  __shared__ float red[256];
  u16x8 v[8];
  #pragma unroll
  for (int j = 0; j < 8; j++) v[j] = *(const u16x8*)&p[tid * 8 + j * 2048];
  float mx = -1e30f;
  #pragma unroll
  for (int j = 0; j < 8; j++)
    #pragma unroll
    for (int e = 0; e < 8; e++) mx = fmaxf(mx, bu2f(v[j][e]));
  red[tid] = mx; __syncthreads();
  for (int s = 128; s > 0; s >>= 1) { if (tid < s) red[tid] = fmaxf(red[tid], red[tid + s]); __syncthreads(); }
  mx = red[0]; __syncthreads();
  float sum = 0.f;
  #pragma unroll
  for (int j = 0; j < 8; j++)
    #pragma unroll
    for (int e = 0; e < 8; e++) sum += __expf(bu2f(v[j][e]) - mx);
  red[tid] = sum; __syncthreads();
  for (int s = 128; s > 0; s >>= 1) { if (tid < s) red[tid] += red[tid + s]; __syncthreads(); }
  float inv = 1.f / red[0];
  #pragma unroll
  for (int j = 0; j < 8; j++) {
    u16x8 o;
    #pragma unroll
    for (int e = 0; e < 8; e++) o[e] = f2bu(__expf(bu2f(v[j][e]) - mx) * inv);
    *(u16x8*)&p[tid * 8 + j * 2048] = o;
  }
}

// ---------------- channel-softmax STATS only: per [n][256] row -> {max, 1/sum}
__global__ __launch_bounds__(256) void chstats_kernel(const ushort_t* __restrict__ p0,
                                                      const ushort_t* __restrict__ p1,
                                                      float2* __restrict__ qstats) {
  int tid = threadIdx.x;
  size_t rowg = (size_t)blockIdx.x * 32 + (tid >> 3);
  int part = tid & 7;
  const ushort_t* q = (rowg < (size_t)B_ * N_) ? (p0 + rowg * KC_)
                                               : (p1 + (rowg - (size_t)B_ * N_) * KC_);
  u16x8 v[4];
  #pragma unroll
  for (int j = 0; j < 4; j++) v[j] = *(const u16x8*)&q[part * 8 + j * 64];
  float mx = -1e30f;
  #pragma unroll
  for (int j = 0; j < 4; j++)
    #pragma unroll
    for (int e = 0; e < 8; e++) mx = fmaxf(mx, bu2f(v[j][e]));
  mx = fmaxf(mx, __shfl_xor(mx, 1));
  mx = fmaxf(mx, __shfl_xor(mx, 2));
  mx = fmaxf(mx, __shfl_xor(mx, 4));
  float sum = 0.f;
  #pragma unroll
  for (int j = 0; j < 4; j++)
    #pragma unroll
    for (int e = 0; e < 8; e++) sum += __expf(bu2f(v[j][e]) - mx);
  sum += __shfl_xor(sum, 1);
  sum += __shfl_xor(sum, 2);
  sum += __shfl_xor(sum, 4);
  if (part == 0) qstats[rowg] = make_float2(mx, 1.f / sum);
}

// ---------------- amap: vectorized column sums, 4-way c-split, 512 n per block
__global__ __launch_bounds__(256) void amap2_kernel(const ushort_t* __restrict__ k0,
    const ushort_t* __restrict__ k1, float* __restrict__ amap) {
  __shared__ float red[256][8];
  int tid = threadIdx.x;
  int ngrp = tid & 63, part = tid >> 6;
  int nblock = blockIdx.x * 512;
  int b = nblock >> 14;
  int n = (nblock & 16383) + ngrp * 8;
  const ushort_t* b0 = k0 + (size_t)b * KC_ * N_ + n;
  const ushort_t* b1 = k1 + (size_t)b * KC_ * N_ + n;
  float s[8];
  #pragma unroll
  for (int j = 0; j < 8; j++) s[j] = 0.f;
  for (int c = part * 64; c < part * 64 + 64; ++c) {
    u16x8 a = *(const u16x8*)&b0[(size_t)c * N_];
    u16x8 d = *(const u16x8*)&b1[(size_t)c * N_];
    #pragma unroll
    for (int j = 0; j < 8; j++) s[j] += bu2f(a[j]) + bu2f(d[j]);
  }
  #pragma unroll
  for (int j = 0; j < 8; j++) red[tid][j] = s[j];
  __syncthreads();
  if (tid < 64) {
    float t[8];
    #pragma unroll
    for (int j = 0; j < 8; j++)
      t[j] = (red[tid][j] + red[tid + 64][j] + red[tid + 128][j] + red[tid + 192][j])
             * (1.f / (2.f * KC_));
    float* dst = amap + (size_t)nblock + tid * 8;
    *(float4*)dst = make_float4(t[0], t[1], t[2], t[3]);
    *(float4*)(dst + 4) = make_float4(t[4], t[5], t[6], t[7]);
  }
}

// ---------------- ctx split-K reduce: fp32 partials -> optional fp32 out + bf16 out
template<bool F32OUT>
__global__ __launch_bounds__(256) void ctx_reduce(const float* __restrict__ part,
                                                  float* __restrict__ outF,
                                                  ushort_t* __restrict__ outB, int split) {
  int idx = blockIdx.x * 256 + threadIdx.x;
  int b = idx >> 16;
  int r = idx & 65535;
  float s = 0.f;
  for (int k = 0; k < split; k++)
    s += part[((size_t)(b * split + k)) * KC_ * VC_ + r];
  if (F32OUT) outF[idx] = s;
  outB[idx] = f2bu(s);
}

// ---------------- depthwise 3x3 + exact GELU in [n][hid]; blockIdx.y = batch-in-group
__global__ __launch_bounds__(256) void dwgelu_t(const ushort_t* __restrict__ h1t,
    const float* __restrict__ wdwT, const float* __restrict__ bdw,
    ushort_t* __restrict__ actT) {
  const ushort_t* h1 = h1t + (size_t)blockIdx.y * N_ * HID_;
  ushort_t* act = actT + (size_t)blockIdx.y * N_ * HID_;
  int pix = blockIdx.x * 2 + (threadIdx.x >> 7);
  int c = (threadIdx.x & 127) * 8;
  int h = pix >> 7, w = pix & 127;
  float s[8];
  {
    float4 b0 = *(const float4*)&bdw[c];
    float4 b1 = *(const float4*)&bdw[c + 4];
    s[0]=b0.x; s[1]=b0.y; s[2]=b0.z; s[3]=b0.w;
    s[4]=b1.x; s[5]=b1.y; s[6]=b1.z; s[7]=b1.w;
  }
  #pragma unroll
  for (int di = -1; di <= 1; ++di) {
    int h2 = h + di;
    if ((unsigned)h2 >= H_) continue;
    #pragma unroll
    for (int dj = -1; dj <= 1; ++dj) {
      int w2 = w + dj;
      if ((unsigned)w2 >= W_) continue;
      int tap = (di + 1) * 3 + (dj + 1);
      u16x8 v = *(const u16x8*)&h1[(size_t)(h2 * W_ + w2) * HID_ + c];
      const float* wp = &wdwT[tap * HID_ + c];
      float4 w0 = *(const float4*)wp, w1 = *(const float4*)(wp + 4);
      s[0] += w0.x * bu2f(v[0]); s[1] += w0.y * bu2f(v[1]);
      s[2] += w0.z * bu2f(v[2]); s[3] += w0.w * bu2f(v[3]);
      s[4] += w1.x * bu2f(v[4]); s[5] += w1.y * bu2f(v[5]);
      s[6] += w1.z * bu2f(v[6]); s[7] += w1.w * bu2f(v[7]);
    }
  }
  u16x8 o;
  #pragma unroll
  for (int j = 0; j < 8; j++) {
    float gl = 0.5f * s[j] * (1.f + erff(s[j] * 0.70710678118654752f));
    o[j] = f2bu(gl);
  }
  *(u16x8*)&act[(size_t)pix * HID_ + c] = o;
}

extern "C" void kernel_launch(void* const* d_in, const int* in_sizes, int n_in,
                              void* d_out, int out_size, void* d_ws, size_t ws_size,
                              hipStream_t stream) {
  const float* x    = (const float*)d_in[0];
  const float* wk1  = (const float*)d_in[3];
  const float* bk1  = (const float*)d_in[4];
  const float* wk2  = (const float*)d_in[5];
  const float* bk2  = (const float*)d_in[6];
  const float* wq1  = (const float*)d_in[7];
  const float* bq1  = (const float*)d_in[8];
  const float* wq2  = (const float*)d_in[9];
  const float* bq2  = (const float*)d_in[10];
  const float* wv   = (const float*)d_in[11];
  const float* bv   = (const float*)d_in[12];
  const float* wr   = (const float*)d_in[13];
  const float* br   = (const float*)d_in[14];
  const float* g1   = (const float*)d_in[15];
  const float* b1   = (const float*)d_in[16];
  const float* g2   = (const float*)d_in[17];
  const float* b2   = (const float*)d_in[18];
  const float* wfc1 = (const float*)d_in[19];
  const float* bfc1 = (const float*)d_in[20];
  const float* wdw  = (const float*)d_in[21];
  const float* bdw  = (const float*)d_in[22];
  const float* wfc2 = (const float*)d_in[23];
  const float* bfc2 = (const float*)d_in[24];

  const size_t big = (size_t)B_ * C_ * N_;
  const long  CN  = (long)C_ * N_;
  const long  NC2 = (long)N_ * C_;
  const long  NH  = (long)N_ * HID_;
  const int   MC  = KC_ * C_;

  uint8_t* w8 = (uint8_t*)d_ws;
  size_t off = 0;
  ushort_t* xnt  = (ushort_t*)(w8 + off); off += 67108864;
  ushort_t* kq   = (ushort_t*)(w8 + off); off += 67108864;
  ushort_t* Mbuf = (ushort_t*)(w8 + off); off += (size_t)B_ * C_ * 512 * 2;
  ushort_t* wkkp = (ushort_t*)(w8 + off); off += 6 * MC * 2;
  ushort_t* wvp  = (ushort_t*)(w8 + off); off += MC * 2;       // contiguous after wkkp
  ushort_t* wqqp = (ushort_t*)(w8 + off); off += 6 * MC * 2;
  ushort_t* wfc1p= (ushort_t*)(w8 + off); off += HID_ * C_ * 2;
  ushort_t* wfc2p= (ushort_t*)(w8 + off); off += C_ * HID_ * 2;
  float* wdwT    = (float*)(w8 + off);    off += 9 * HID_ * 4;
  float* bKV     = (float*)(w8 + off);    off += 768 * 4;
  float* bQ      = (float*)(w8 + off);    off += 512 * 4;
  ushort_t* wrp  = (ushort_t*)(w8 + off); off += C_ * 512 * 2;
  ushort_t* ctx0b= (ushort_t*)(w8 + off); off += (size_t)B_ * KC_ * VC_ * 2;
  ushort_t* ctx1b= (ushort_t*)(w8 + off); off += (size_t)B_ * KC_ * VC_ * 2;
  float2* qstats = (float2*)(w8 + off);   off += (size_t)2 * B_ * N_ * 8;
  ushort_t* zbuf = (ushort_t*)(w8 + off); off += 1024;
  const size_t partBytes = (size_t)8 * B_ * KC_ * VC_ * 4;   // 16.78 MB
  // pair mode: [actX 67.1MB][part]; fallback: [part]
  size_t need_pair = off + 67108864 + partBytes;
  size_t need8 = off + partBytes;
  size_t need4 = off + partBytes / 2;
  int csplit; bool pairFFN = false;
  ushort_t* actX = nullptr;
  float* part;
  if (ws_size >= need_pair) {
    pairFFN = true; csplit = 8;
    actX = (ushort_t*)(w8 + off);
    part = (float*)(w8 + off + 67108864);
  } else if (ws_size >= need8) {
    csplit = 8; part = (float*)(w8 + off);
  } else if (ws_size >= need4) {
    csplit = 4; part = (float*)(w8 + off);
  } else return;
  const float* fzero = (const float*)zbuf;

  float* mx_out   = (float*)d_out;
  float* ctx_out  = mx_out + big;
  float* amap_out = ctx_out + (size_t)B_ * KC_ * VC_;

  ushort_t* mxlo = (ushort_t*)d_out;            // val -> q1
  ushort_t* mxhi = (ushort_t*)d_out + big;      // K1 -> tx

  ushort_t* txn  = xnt;

  dim3 blk(256);

  pack_all<<<3881, blk, 0, stream>>>(wk1, wk2, wq1, wq2, wv, wfc1, wfc2, wdw,
                                     bk1, bk2, bq1, bq2, bv, wr,
                                     zbuf, bKV, bQ, wdwT,
                                     wvp, wfc1p, wfc2p, wrp, wkkp, wqqp);

  // LN1 fused
  ln1t_kernel<<<dim3(N_ / 64, 1, B_), blk, 0, stream>>>(x, g1, b1, xnt);

  // fused KKV: K0 -> kq, K1 -> mxhi, val -> mxlo
  mfma_gemm<3, 4, 1, 1, false, false><<<dim3(N_ / 128, 6, B_), blk, 0, stream>>>(
      wkkp, 0, C_, (long)MC, (long)3 * MC, xnt, nullptr, NC2, C_,
      bKV, nullptr, nullptr, 0,
      nullptr, kq, mxhi, mxlo, (long)KC_ * N_, N_, C_ / 64, zbuf, nullptr);

  softmax_spatial2<<<2 * B_ * KC_, blk, 0, stream>>>(kq, mxhi);
  amap2_kernel<<<B_ * N_ / 512, blk, 0, stream>>>(kq, mxhi, amap_out);

  for (int d = 0; d < 2; ++d) {
    const ushort_t* Ksrc = d ? mxhi : kq;
    if (csplit == 8)
      mfma_gemm<1, 0, 6, 8, false, false><<<dim3(VC_ / 128, KC_ / 128, B_ * 8), blk, 0, stream>>>(
          Ksrc, (long)KC_ * N_, N_, 0, 0, mxlo, nullptr, (long)VC_ * N_, N_,
          nullptr, nullptr, nullptr, 0,
          part, nullptr, nullptr, nullptr, (long)KC_ * VC_, VC_, (N_ / 8) / 64, zbuf, nullptr);
    else
      mfma_gemm<1, 0, 6, 4, false, false><<<dim3(VC_ / 128, KC_ / 128, B_ * 4), blk, 0, stream>>>(
          Ksrc, (long)KC_ * N_, N_, 0, 0, mxlo, nullptr, (long)VC_ * N_, N_,
          nullptr, nullptr, nullptr, 0,
          part, nullptr, nullptr, nullptr, (long)KC_ * VC_, VC_, (N_ / 4) / 64, zbuf, nullptr);
    if (d == 0)
      ctx_reduce<false><<<B_ * KC_ * VC_ / 256, blk, 0, stream>>>(part, nullptr, ctx0b, csplit);
    else
      ctx_reduce<true><<<B_ * KC_ * VC_ / 256, blk, 0, stream>>>(part, ctx_out, ctx1b, csplit);
  }

  // fused QQ: q0 -> kq [n][kc], q1 -> mxlo (RAW, softmax fused into attn)
  mfma_gemm<3, 3, 2, 1, false, false><<<dim3(N_ / 128, 4, B_), blk, 0, stream>>>(
      wqqp, 0, C_, (long)MC, (long)3 * MC, xnt, nullptr, NC2, C_,
      bQ, nullptr, nullptr, 0,
      nullptr, kq, mxlo, nullptr, (long)N_ * KC_, KC_, C_ / 64, zbuf, nullptr);

  // channel-softmax stats only
  chstats_kernel<<<2 * B_ * N_ / 32, blk, 0, stream>>>(kq, mxlo, qstats);

  // Mcat via MFMA
  mfma_gemm<1, 0, 1, 1, false, false><<<dim3(KC_ / 128, C_ / 128, B_), blk, 0, stream>>>(
      wrp, 0, 512, 0, 0, ctx0b, nullptr, (long)KC_ * VC_, VC_, fzero, nullptr, nullptr, 0,
      nullptr, Mbuf, nullptr, nullptr, (long)C_ * 512, 512, VC_ / 64, zbuf, nullptr);
  mfma_gemm<1, 0, 1, 1, false, false><<<dim3(KC_ / 128, C_ / 128, B_), blk, 0, stream>>>(
      wrp + 256, 0, 512, 0, 0, ctx1b, nullptr, (long)KC_ * VC_, VC_, fzero, nullptr, nullptr, 0,
      nullptr, Mbuf + 256, nullptr, nullptr, (long)C_ * 512, 512, VC_ / 64, zbuf, nullptr);

  // fused attention (softmax-in-loader) -> tx bf16 @ mxhi
  mfma_gemm<1, 0, 7, 1, true, true><<<dim3(N_ / 128, C_ / 128, B_), blk, 0, stream>>>(
      Mbuf, (long)C_ * 512, 512, 0, 0, kq, mxlo, (long)N_ * KC_, KC_,
      br, x, nullptr, CN,
      nullptr, mxhi, nullptr, nullptr, CN, N_, 8, zbuf, qstats);

  // LN2 fused: tx -> txn
  ln2t_kernel<<<dim3(N_ / 64, 1, B_), blk, 0, stream>>>(mxhi, g2, b2, txn);

  if (pairFFN) {
    // copy tx b6,b7 (fc2 pair-3 writes clobber them); exact fit in part
    hipMemcpyAsync(part, mxhi + (size_t)6 * CN, (size_t)2 * CN * 2,
                   hipMemcpyDeviceToDevice, stream);
    ushort_t* h1t2 = kq;           // 2 batches [N][HID]
    for (int g = 0; g < 4; ++g) {
      mfma_gemm<1, 0, 2, 1, false, false><<<dim3(N_ / 128, HID_ / 128, 2), blk, 0, stream>>>(
          wfc1p, 0, C_, 0, 0, txn + (size_t)g * 2 * NC2, nullptr, NC2, C_,
          bfc1, nullptr, nullptr, 0,
          nullptr, h1t2, nullptr, nullptr, NH, HID_, C_ / 64, zbuf, nullptr);
      dwgelu_t<<<dim3(N_ / 2, 2), blk, 0, stream>>>(h1t2, wdwT, bdw, actX);
      const ushort_t* txb = (g == 3) ? (const ushort_t*)part : (mxhi + (size_t)g * 2 * CN);
      mfma_gemm<1, 0, 8, 1, false, false><<<dim3(N_ / 128, C_ / 128, 2), blk, 0, stream>>>(
          wfc2p, 0, HID_, 0, 0, actX, nullptr, NH, HID_,
          bfc2, nullptr, txb, CN,
          mx_out + (size_t)g * 2 * CN, nullptr, nullptr, nullptr, CN, N_, HID_ / 64, zbuf, nullptr);
    }
  } else {
    ushort_t* h1t  = kq;
    ushort_t* actT = kq + NH;
    // preserve tx batch 7 (fc2 b7 writes clobber it)
    hipMemcpyAsync(part, mxhi + (size_t)7 * CN, (size_t)CN * 2,
                   hipMemcpyDeviceToDevice, stream);
    for (int b = 0; b < B_; ++b) {
      mfma_gemm<1, 0, 2, 1, false, false><<<dim3(N_ / 128, HID_ / 128, 1), blk, 0, stream>>>(
          wfc1p, 0, C_, 0, 0, txn + (size_t)b * NC2, nullptr, 0, C_,
          bfc1, nullptr, nullptr, 0,
          nullptr, h1t, nullptr, nullptr, 0, HID_, C_ / 64, zbuf, nullptr);
      dwgelu_t<<<dim3(N_ / 2, 1), blk, 0, stream>>>(h1t, wdwT, bdw, actT);
      const ushort_t* txb = (b == 7) ? (const ushort_t*)part : (mxhi + (size_t)b * CN);
      mfma_gemm<1, 0, 8, 1, false, false><<<dim3(N_ / 128, C_ / 128, 1), blk, 0, stream>>>(
          wfc2p, 0, HID_, 0, 0, actT, nullptr, 0, HID_,
          bfc2, nullptr, txb, 0,
          mx_out + (size_t)b * CN, nullptr, nullptr, nullptr, 0, N_, HID_ / 64, zbuf, nullptr);
    }
  }
}

// Round 11
// 1287.221 us; speedup vs baseline: 9.8285x; 1.0363x over previous
//
#include <hip/hip_runtime.h>
#include <hip/hip_bf16.h>

#define B_ 8
#define C_ 256
#define H_ 128
#define W_ 128
#define N_ 16384
#define KC_ 256
#define VC_ 256
#define HID_ 1024

typedef unsigned short ushort_t;
typedef __bf16 bf16x8 __attribute__((ext_vector_type(8)));
typedef float f32x4 __attribute__((ext_vector_type(4)));
typedef ushort_t u16x8 __attribute__((ext_vector_type(8)));

static __device__ __forceinline__ ushort_t f2bu(float f) {
  __hip_bfloat16 h = __float2bfloat16(f);
  return *reinterpret_cast<ushort_t*>(&h);
}
static __device__ __forceinline__ float bu2f(ushort_t u) {
  __hip_bfloat16 h;
  *reinterpret_cast<ushort_t*>(&h) = u;
  return __bfloat162float(h);
}

#define GLD16(gp, lp) __builtin_amdgcn_global_load_lds( \
    (const __attribute__((address_space(1))) void*)(gp), \
    (__attribute__((address_space(3))) void*)(lp), 16, 0, 0)

// ---------------- one-shot weight/bias packing
__global__ __launch_bounds__(256) void pack_all(
    const float* __restrict__ wk1, const float* __restrict__ wk2,
    const float* __restrict__ wq1, const float* __restrict__ wq2,
    const float* __restrict__ wv, const float* __restrict__ wfc1,
    const float* __restrict__ wfc2, const float* __restrict__ wdw,
    const float* __restrict__ bk1, const float* __restrict__ bk2,
    const float* __restrict__ bq1, const float* __restrict__ bq2,
    const float* __restrict__ bv, const float* __restrict__ wr,
    ushort_t* __restrict__ zbuf,
    float* __restrict__ bKV, float* __restrict__ bQ, float* __restrict__ wdwT,
    ushort_t* __restrict__ wvp, ushort_t* __restrict__ wfc1p,
    ushort_t* __restrict__ wfc2p, ushort_t* __restrict__ wrp,
    ushort_t* __restrict__ wkkp, ushort_t* __restrict__ wqqp) {
  int idx = blockIdx.x * 256 + threadIdx.x;
  const int MC = KC_ * C_;
  if (idx < 512) {
    zbuf[idx] = 0;
    bQ[idx] = (idx < 256) ? bq1[idx] : bq2[idx - 256];
    return;
  }
  idx -= 512;
  if (idx < 768) {
    bKV[idx] = (idx < 256) ? bk1[idx] : (idx < 512 ? bk2[idx - 256] : bv[idx - 512]);
    return;
  }
  idx -= 768;
  if (idx < 9216) { int c = idx / 9, t = idx % 9; wdwT[t * HID_ + c] = wdw[idx]; return; }
  idx -= 9216;
  if (idx < VC_ * C_) { wvp[idx] = f2bu(wv[idx]); return; }
  idx -= VC_ * C_;
  if (idx < HID_ * C_) { wfc1p[idx] = f2bu(wfc1[idx]); return; }
  idx -= HID_ * C_;
  if (idx < C_ * HID_) { wfc2p[idx] = f2bu(wfc2[idx]); return; }
  idx -= C_ * HID_;
  if (idx < C_ * 512) { wrp[idx] = f2bu(wr[idx]); return; }
  idx -= C_ * 512;
  if (idx < MC) {
    #pragma unroll
    for (int t = 0; t < 3; ++t) wkkp[t * MC + idx] = f2bu(wk1[idx * 3 + t]);
    return;
  }
  idx -= MC;
  if (idx < MC) {
    #pragma unroll
    for (int t = 0; t < 3; ++t) wkkp[3 * MC + t * MC + idx] = f2bu(wk2[idx * 3 + t]);
    return;
  }
  idx -= MC;
  if (idx < MC) {
    #pragma unroll
    for (int t = 0; t < 3; ++t) wqqp[t * MC + idx] = f2bu(wq1[idx * 3 + t]);
    return;
  }
  idx -= MC;
  if (idx < MC) {
    #pragma unroll
    for (int t = 0; t < 3; ++t) wqqp[3 * MC + t * MC + idx] = f2bu(wq2[idx * 3 + t]);
    return;
  }
}

// ---------------- fused LN1: x fp32 [c][n] -> bf16 [n][c]
__global__ __launch_bounds__(256) void ln1t_kernel(const float* __restrict__ x,
    const float* __restrict__ g, const float* __restrict__ beta,
    ushort_t* __restrict__ out) {
  __shared__ float T[256][67];
  __shared__ float st[2][4][64];
  __shared__ float mr[64], rs[64];
  int z = blockIdx.z;
  int n0 = blockIdx.x * 64;
  int t = threadIdx.x;
  const float* xb = x + (size_t)z * C_ * N_;
  #pragma unroll
  for (int j = 0; j < 16; ++j) {
    int e = (j * 256 + t) * 4;
    int c = e >> 6, n = e & 63;
    float4 v = *(const float4*)&xb[(size_t)c * N_ + n0 + n];
    T[c][n] = v.x; T[c][n + 1] = v.y; T[c][n + 2] = v.z; T[c][n + 3] = v.w;
  }
  __syncthreads();
  {
    int n = t & 63, part = t >> 6;
    float s1 = 0.f, s2 = 0.f;
    for (int c = part * 64; c < part * 64 + 64; ++c) { float v = T[c][n]; s1 += v; s2 += v * v; }
    st[0][part][n] = s1; st[1][part][n] = s2;
  }
  __syncthreads();
  if (t < 64) {
    float s1 = st[0][0][t] + st[0][1][t] + st[0][2][t] + st[0][3][t];
    float s2 = st[1][0][t] + st[1][1][t] + st[1][2][t] + st[1][3][t];
    float m = s1 * (1.f / C_);
    float v = s2 * (1.f / C_) - m * m;
    mr[t] = m; rs[t] = rsqrtf(v + 1e-5f);
  }
  __syncthreads();
  {
    int n = t >> 2, cc = (t & 3) * 64;
    float m = mr[n], r = rs[n];
    ushort_t* po = out + (size_t)z * N_ * C_ + (size_t)(n0 + n) * C_ + cc;
    #pragma unroll
    for (int j0 = 0; j0 < 64; j0 += 8) {
      u16x8 o;
      #pragma unroll
      for (int j = 0; j < 8; ++j) {
        int c = cc + j0 + j;
        o[j] = f2bu((T[c][n] - m) * r * g[c] + beta[c]);
      }
      *(u16x8*)(po + j0) = o;
    }
  }
}

// ---------------- fused LN2: tx bf16 [c][n] -> bf16 [n][c]
__global__ __launch_bounds__(256) void ln2t_kernel(const ushort_t* __restrict__ x,
    const float* __restrict__ g, const float* __restrict__ beta,
    ushort_t* __restrict__ out) {
  __shared__ ushort_t T[256][72];
  __shared__ float st[2][4][64];
  __shared__ float mr[64], rs[64];
  int z = blockIdx.z;
  int n0 = blockIdx.x * 64;
  int t = threadIdx.x;
  const ushort_t* xb = x + (size_t)z * C_ * N_;
  #pragma unroll
  for (int j = 0; j < 8; ++j) {
    int e = (j * 256 + t) * 8;
    int c = e >> 6, n = e & 63;
    *(u16x8*)&T[c][n] = *(const u16x8*)&xb[(size_t)c * N_ + n0 + n];
  }
  __syncthreads();
  {
    int n = t & 63, part = t >> 6;
    float s1 = 0.f, s2 = 0.f;
    for (int c = part * 64; c < part * 64 + 64; ++c) { float v = bu2f(T[c][n]); s1 += v; s2 += v * v; }
    st[0][part][n] = s1; st[1][part][n] = s2;
  }
  __syncthreads();
  if (t < 64) {
    float s1 = st[0][0][t] + st[0][1][t] + st[0][2][t] + st[0][3][t];
    float s2 = st[1][0][t] + st[1][1][t] + st[1][2][t] + st[1][3][t];
    float m = s1 * (1.f / C_);
    float v = s2 * (1.f / C_) - m * m;
    mr[t] = m; rs[t] = rsqrtf(v + 1e-5f);
  }
  __syncthreads();
  {
    int n = t >> 2, cc = (t & 3) * 64;
    float m = mr[n], r = rs[n];
    ushort_t* po = out + (size_t)z * N_ * C_ + (size_t)(n0 + n) * C_ + cc;
    #pragma unroll
    for (int j0 = 0; j0 < 64; j0 += 8) {
      u16x8 o;
      #pragma unroll
      for (int j = 0; j < 8; ++j) {
        int c = cc + j0 + j;
        o[j] = f2bu((bu2f(T[c][n]) - m) * r * g[c] + beta[c]);
      }
      *(u16x8*)(po + j0) = o;
    }
  }
}

// ======================= MFMA GEMM template =======================
// DIMSEL: 0 none; 1 w-shift; 2 h-shift; 3 dual-dir; 4 triple (K0 w, K1 h, val)
// BSOFT: B-loader applies channel-softmax from qstats (BDUAL only)
// ADUAL: z >= adualH selects A2/B2 operand bases and outB2 (merged dual-direction)
// BSTATS: OMODE2 epilogue emits per-row partial softmax stats (QQ)
template<int TAPS, int DIMSEL, int OMODE, int SPLIT, bool BDUAL, bool BSOFT, bool ADUAL, bool BSTATS>
__global__ __launch_bounds__(256) void mfma_gemm(
    const ushort_t* __restrict__ A, const ushort_t* __restrict__ A2,
    long Abatch, int lda, long Aplane, long Adirstride,
    const ushort_t* __restrict__ B, const ushort_t* __restrict__ B2, long Bbatch, int ldb,
    const float* __restrict__ bias,
    const float* __restrict__ resF, const ushort_t* __restrict__ resB, long Resbatch,
    float* __restrict__ outF, ushort_t* __restrict__ outB, ushort_t* __restrict__ outB2,
    ushort_t* __restrict__ outB3,
    long Outbatch, int ldo, int Ksteps, const ushort_t* __restrict__ zbuf,
    const float2* __restrict__ qstats, float2* __restrict__ pstats, int adualH) {
  __shared__ ushort_t sm[17408];
  int tid = threadIdx.x;
  int bx = blockIdx.x, by = blockIdx.y;
  int bzfull = blockIdx.z;
  bool adhi = ADUAL && (bzfull >= adualH);
  int bz = adhi ? bzfull - adualH : bzfull;
  if (gridDim.x == 128) bx = ((bx & 7) << 4) | (bx >> 3);
  int b = bz / SPLIT, sK = bz % SPLIT;
  long koff = (long)sK * Ksteps * 64;
  int dsel = (DIMSEL == 3) ? (by < 2 ? 1 : 2)
           : (DIMSEL == 4) ? (by < 2 ? 1 : (by < 4 ? 2 : 0))
           : DIMSEL;
  int m0 = (DIMSEL == 3 || DIMSEL == 4) ? ((by & 1) * 128) : (by * 128);
  int bofs = (DIMSEL == 3 || DIMSEL == 4) ? ((by >> 1) * 256) : 0;
  const ushort_t* Aroot = adhi ? A2 : A;
  const ushort_t* Broot = (!BDUAL && adhi) ? B2 : B;
  const ushort_t* Ab = Aroot + (size_t)b * Abatch + koff
      + ((DIMSEL == 3 || DIMSEL == 4) ? (long)(by >> 1) * Adirstride : 0L);
  const ushort_t* Bb = Broot + (size_t)b * Bbatch + (BDUAL ? 0 : koff);
  const ushort_t* B2b = BDUAL ? (B2 + (size_t)b * Bbatch) : nullptr;
  int n0 = bx * 128;
  int lane = tid & 63, wid = tid >> 6, wm = wid >> 1, wn = wid & 1;

  f32x4 acc[4][4];
  #pragma unroll
  for (int i = 0; i < 4; i++)
    #pragma unroll
    for (int j = 0; j < 4; j++) acc[i][j] = (f32x4)0.f;

  for (int t = 0; t < TAPS; ++t) {
    if (TAPS == 3 && dsel == 2) {
      if ((bx == 0 && t == 0) || (bx == H_ - 1 && t == 2)) continue;
    }
    if (DIMSEL == 4 && dsel == 0 && t != 1) continue;
    const ushort_t* At = Ab + ((DIMSEL == 4 && dsel == 0) ? 0L : (long)t * Aplane);
    for (int ks = 0; ks < Ksteps; ++ks) {
      int k0 = ks * 64;
      #pragma unroll
      for (int i = 0; i < 4; i++) {
        int s = tid + i * 256;
        int row = s >> 3, pc = s & 7;
        int lc = pc ^ (row & 7);
        const ushort_t* g = At + (long)(m0 + row) * lda + k0 + lc * 8;
        GLD16(g, &sm[s * 8]);
      }
      if (BDUAL && BSOFT) {
        int dir = (ks < Ksteps / 2) ? 0 : 1;
        const ushort_t* Bsel = dir ? B2b : Bb;
        int kb = (ks - dir * (Ksteps / 2)) * 64;
        #pragma unroll
        for (int i = 0; i < 4; i++) {
          int s = tid + i * 256;
          int row = s >> 3, pc = s & 7;
          int lc = pc ^ (row & 7);
          u16x8 e = *(const u16x8*)(Bsel + (long)(n0 + row) * ldb + kb + lc * 8);
          float2 st = qstats[(size_t)dir * B_ * N_ + (size_t)bz * N_ + n0 + row];
          u16x8 o;
          #pragma unroll
          for (int j = 0; j < 8; j++)
            o[j] = f2bu(__expf(bu2f(e[j]) - st.x) * st.y);
          *(u16x8*)&sm[8192 + s * 8] = o;
        }
      } else {
        #pragma unroll
        for (int i = 0; i < 4; i++) {
          int s = tid + i * 256;
          int row = s >> 3, pc = s & 7;
          int lc = pc ^ (row & 7);
          const ushort_t* g;
          if (BDUAL) {
            const ushort_t* Bsel = (ks < Ksteps / 2) ? Bb : B2b;
            int kb = ((ks < Ksteps / 2) ? ks : ks - Ksteps / 2) * 64;
            g = Bsel + (long)(n0 + row) * ldb + kb + lc * 8;
          } else if (TAPS == 3 && dsel == 1) {
            int wpos = row + (t - 1);
            if (0 <= wpos && wpos < W_)
              g = Bb + (long)(n0 + row + (t - 1)) * ldb + k0 + lc * 8;
            else
              g = zbuf;
          } else if (TAPS == 3 && dsel == 2) {
            g = Bb + (long)(n0 + row + (t - 1) * W_) * ldb + k0 + lc * 8;
          } else {
            g = Bb + (long)(n0 + row) * ldb + k0 + lc * 8;
          }
          GLD16(g, &sm[8192 + s * 8]);
        }
      }
      __syncthreads();
      #pragma unroll
      for (int kk = 0; kk < 2; kk++) {
        bf16x8 av[4], bv[4];
        int r16 = lane & 15;
        int sl = (lane >> 4) + kk * 4;
        #pragma unroll
        for (int fm = 0; fm < 4; fm++) {
          int row = wm * 64 + fm * 16 + r16;
          av[fm] = *(const bf16x8*)&sm[row * 64 + ((sl ^ (row & 7)) * 8)];
        }
        #pragma unroll
        for (int fn = 0; fn < 4; fn++) {
          int row = wn * 64 + fn * 16 + r16;
          bv[fn] = *(const bf16x8*)&sm[8192 + row * 64 + ((sl ^ (row & 7)) * 8)];
        }
        #pragma unroll
        for (int fm = 0; fm < 4; fm++)
          #pragma unroll
          for (int fn = 0; fn < 4; fn++)
            acc[fm][fn] = __builtin_amdgcn_mfma_f32_16x16x32_bf16(av[fm], bv[fn], acc[fm][fn], 0, 0, 0);
      }
      __syncthreads();
    }
  }

  int r16 = lane & 15, rq = lane >> 4;
  if (OMODE == 1 || OMODE == 2 || OMODE == 7) {
    ushort_t* obase;
    if (DIMSEL == 3 || DIMSEL == 4)
      obase = (blockIdx.y >= 4) ? outB3 : (blockIdx.y >= 2 ? outB2 : outB);
    else
      obase = adhi ? outB2 : outB;
    ushort_t* ob = obase + (size_t)bz * Outbatch;
    #pragma unroll
    for (int fm = 0; fm < 4; fm++) {
      #pragma unroll
      for (int fn = 0; fn < 4; fn++) {
        int lm = wm * 64 + fm * 16 + rq * 4;
        int ln = wn * 64 + fn * 16 + r16;
        f32x4 a = acc[fm][fn];
        if (OMODE == 2) {
          #pragma unroll
          for (int r = 0; r < 4; r++)
            sm[ln * 136 + lm + r] = f2bu(a[r] + bias[bofs + m0 + lm + r]);
        } else {
          #pragma unroll
          for (int r = 0; r < 4; r++)
            sm[(lm + r) * 136 + ln] = f2bu(a[r] + bias[bofs + m0 + lm + r]);
        }
      }
    }
    __syncthreads();
    int row = tid >> 1, half = (tid & 1) * 64;
    const ushort_t* src = &sm[row * 136 + half];
    if (OMODE == 7) {
      const float* xb = resF + (size_t)bz * Resbatch + (size_t)(m0 + row) * ldo + n0 + half;
      ushort_t* dst = &ob[(size_t)(m0 + row) * ldo + n0 + half];
      #pragma unroll
      for (int j = 0; j < 8; j++) {
        u16x8 v = *(const u16x8*)(src + j * 8);
        float4 x0 = *(const float4*)(xb + j * 8);
        float4 x1 = *(const float4*)(xb + j * 8 + 4);
        u16x8 o;
        o[0] = f2bu(bu2f(v[0]) + x0.x); o[1] = f2bu(bu2f(v[1]) + x0.y);
        o[2] = f2bu(bu2f(v[2]) + x0.z); o[3] = f2bu(bu2f(v[3]) + x0.w);
        o[4] = f2bu(bu2f(v[4]) + x1.x); o[5] = f2bu(bu2f(v[5]) + x1.y);
        o[6] = f2bu(bu2f(v[6]) + x1.z); o[7] = f2bu(bu2f(v[7]) + x1.w);
        *(u16x8*)(dst + j * 8) = o;
      }
    } else {
      ushort_t* dst;
      if (OMODE == 1) dst = &ob[(size_t)(m0 + row) * ldo + n0 + half];
      else            dst = &ob[(size_t)(n0 + row) * ldo + m0 + half];
      #pragma unroll
      for (int j = 0; j < 8; j++)
        *(u16x8*)(dst + j * 8) = *(const u16x8*)(src + j * 8);
    }
    if (OMODE == 2 && BSTATS) {
      // per-n-row partial channel-softmax stats over this kc-half (tile still in LDS)
      int colb = (tid & 1) * 64;
      const ushort_t* rp = &sm[row * 136 + colb];
      float mxl = -1e30f;
      for (int j = 0; j < 64; ++j) mxl = fmaxf(mxl, bu2f(rp[j]));
      float mxh = fmaxf(mxl, __shfl_xor(mxl, 1));
      float s = 0.f;
      for (int j = 0; j < 64; ++j) s += __expf(bu2f(rp[j]) - mxh);
      s += __shfl_xor(s, 1);
      if ((tid & 1) == 0) {
        int dir = by >> 1, hlf = by & 1;
        pstats[(((size_t)dir * B_ + bz) * N_ + n0 + row) * 2 + hlf] = make_float2(mxh, s);
      }
    }
  } else {
    #pragma unroll
    for (int fm = 0; fm < 4; fm++) {
      #pragma unroll
      for (int fn = 0; fn < 4; fn++) {
        int mrow = m0 + wm * 64 + fm * 16 + rq * 4;
        int ncol = n0 + wn * 64 + fn * 16 + r16;
        f32x4 a = acc[fm][fn];
        if (OMODE == 6) {
          float* of = outF + (size_t)bzfull * Outbatch;
          #pragma unroll
          for (int r = 0; r < 4; r++)
            of[(size_t)(mrow + r) * ldo + ncol] = a[r];
        } else if (OMODE == 8) {
          float* of = outF + (size_t)bz * Outbatch;
          const ushort_t* rp = resB + (size_t)bz * Resbatch;
          #pragma unroll
          for (int r = 0; r < 4; r++) {
            size_t o = (size_t)(mrow + r) * ldo + ncol;
            of[o] = a[r] + bias[mrow + r] + bu2f(rp[o]);
          }
        }
      }
    }
  }
}

// ---------------- single-pass spatial softmax, exp cached in registers
__global__ __launch_bounds__(256) void softmax_spatial2(ushort_t* __restrict__ p0,
                                                        ushort_t* __restrict__ p1) {
  int r = blockIdx.x;
  ushort_t* p = (r < B_ * KC_) ? (p0 + (size_t)r * N_) : (p1 + (size_t)(r - B_ * KC_) * N_);
  int tid = threadIdx.x;
  __shared__ float red[256];
  u16x8 v[8];
  #pragma unroll
  for (int j = 0; j < 8; j++) v[j] = *(const u16x8*)&p[tid * 8 + j * 2048];
  float mx = -1e30f;
  #pragma unroll
  for (int j = 0; j < 8; j++)
    #pragma unroll
    for (int e = 0; e < 8; e++) mx = fmaxf(mx, bu2f(v[j][e]));
  red[tid] = mx; __syncthreads();
  for (int s = 128; s > 0; s >>= 1) { if (tid < s) red[tid] = fmaxf(red[tid], red[tid + s]); __syncthreads(); }
  mx = red[0]; __syncthreads();
  float ef[8][8];
  float sum = 0.f;
  #pragma unroll
  for (int j = 0; j < 8; j++)
    #pragma unroll
    for (int e = 0; e < 8; e++) { ef[j][e] = __expf(bu2f(v[j][e]) - mx); sum += ef[j][e]; }
  red[tid] = sum; __syncthreads();
  for (int s = 128; s > 0; s >>= 1) { if (tid < s) red[tid] += red[tid + s]; __syncthreads(); }
  float inv = 1.f / red[0];
  #pragma unroll
  for (int j = 0; j < 8; j++) {
    u16x8 o;
    #pragma unroll
    for (int e = 0; e < 8; e++) o[e] = f2bu(ef[j][e] * inv);
    *(u16x8*)&p[tid * 8 + j * 2048] = o;
  }
}

// ---------------- combine per-half partial stats -> qstats {max, 1/sum}
__global__ __launch_bounds__(256) void pcomb_kernel(const float2* __restrict__ pstats,
                                                    float2* __restrict__ qstats) {
  size_t idx = (size_t)blockIdx.x * 256 + threadIdx.x;   // 2*B*N rows
  float2 a = pstats[idx * 2 + 0];
  float2 b = pstats[idx * 2 + 1];
  float mx = fmaxf(a.x, b.x);
  float s = a.y * __expf(a.x - mx) + b.y * __expf(b.x - mx);
  qstats[idx] = make_float2(mx, 1.f / s);
}

// ---------------- amap: vectorized column sums, 4-way c-split, 512 n per block
__global__ __launch_bounds__(256) void amap2_kernel(const ushort_t* __restrict__ k0,
    const ushort_t* __restrict__ k1, float* __restrict__ amap) {
  __shared__ float red[256][8];
  int tid = threadIdx.x;
  int ngrp = tid & 63, part = tid >> 6;
  int nblock = blockIdx.x * 512;
  int b = nblock >> 14;
  int n = (nblock & 16383) + ngrp * 8;
  const ushort_t* b0 = k0 + (size_t)b * KC_ * N_ + n;
  const ushort_t* b1 = k1 + (size_t)b * KC_ * N_ + n;
  float s[8];
  #pragma unroll
  for (int j = 0; j < 8; j++) s[j] = 0.f;
  for (int c = part * 64; c < part * 64 + 64; ++c) {
    u16x8 a = *(const u16x8*)&b0[(size_t)c * N_];
    u16x8 d = *(const u16x8*)&b1[(size_t)c * N_];
    #pragma unroll
    for (int j = 0; j < 8; j++) s[j] += bu2f(a[j]) + bu2f(d[j]);
  }
  #pragma unroll
  for (int j = 0; j < 8; j++) red[tid][j] = s[j];
  __syncthreads();
  if (tid < 64) {
    float t[8];
    #pragma unroll
    for (int j = 0; j < 8; j++)
      t[j] = (red[tid][j] + red[tid + 64][j] + red[tid + 128][j] + red[tid + 192][j])
             * (1.f / (2.f * KC_));
    float* dst = amap + (size_t)nblock + tid * 8;
    *(float4*)dst = make_float4(t[0], t[1], t[2], t[3]);
    *(float4*)(dst + 4) = make_float4(t[4], t[5], t[6], t[7]);
  }
}

// ---------------- merged ctx split-K reduce (both dirs)
__global__ __launch_bounds__(256) void ctx_reduce2(const float* __restrict__ part,
                                                   float* __restrict__ ctxF,
                                                   ushort_t* __restrict__ c0b,
                                                   ushort_t* __restrict__ c1b) {
  int idx = blockIdx.x * 256 + threadIdx.x;     // 2 * B * 65536
  int dir = idx >> 19;
  int rem = idx & 524287;
  int b = rem >> 16;
  const float* p = part + ((size_t)(dir * 64 + b * 8)) * 65536 + (rem & 65535);
  float s = 0.f;
  #pragma unroll
  for (int k = 0; k < 8; k++) s += p[(size_t)k * 65536];
  if (dir == 0) c0b[rem] = f2bu(s);
  else { ctxF[rem] = s; c1b[rem] = f2bu(s); }
}

// ---------------- depthwise 3x3 + exact GELU in [n][hid]; blockIdx.y = batch-in-group
__global__ __launch_bounds__(256) void dwgelu_t(const ushort_t* __restrict__ h1t,
    const float* __restrict__ wdwT, const float* __restrict__ bdw,
    ushort_t* __restrict__ actT) {
  const ushort_t* h1 = h1t + (size_t)blockIdx.y * N_ * HID_;
  ushort_t* act = actT + (size_t)blockIdx.y * N_ * HID_;
  int pix = blockIdx.x * 2 + (threadIdx.x >> 7);
  int c = (threadIdx.x & 127) * 8;
  int h = pix >> 7, w = pix & 127;
  float s[8];
  {
    float4 b0 = *(const float4*)&bdw[c];
    float4 b1 = *(const float4*)&bdw[c + 4];
    s[0]=b0.x; s[1]=b0.y; s[2]=b0.z; s[3]=b0.w;
    s[4]=b1.x; s[5]=b1.y; s[6]=b1.z; s[7]=b1.w;
  }
  #pragma unroll
  for (int di = -1; di <= 1; ++di) {
    int h2 = h + di;
    if ((unsigned)h2 >= H_) continue;
    #pragma unroll
    for (int dj = -1; dj <= 1; ++dj) {
      int w2 = w + dj;
      if ((unsigned)w2 >= W_) continue;
      int tap = (di + 1) * 3 + (dj + 1);
      u16x8 v = *(const u16x8*)&h1[(size_t)(h2 * W_ + w2) * HID_ + c];
      const float* wp = &wdwT[tap * HID_ + c];
      float4 w0 = *(const float4*)wp, w1 = *(const float4*)(wp + 4);
      s[0] += w0.x * bu2f(v[0]); s[1] += w0.y * bu2f(v[1]);
      s[2] += w0.z * bu2f(v[2]); s[3] += w0.w * bu2f(v[3]);
      s[4] += w1.x * bu2f(v[4]); s[5] += w1.y * bu2f(v[5]);
      s[6] += w1.z * bu2f(v[6]); s[7] += w1.w * bu2f(v[7]);
    }
  }
  u16x8 o;
  #pragma unroll
  for (int j = 0; j < 8; j++) {
    float gl = 0.5f * s[j] * (1.f + erff(s[j] * 0.70710678118654752f));
    o[j] = f2bu(gl);
  }
  *(u16x8*)&act[(size_t)pix * HID_ + c] = o;
}

extern "C" void kernel_launch(void* const* d_in, const int* in_sizes, int n_in,
                              void* d_out, int out_size, void* d_ws, size_t ws_size,
                              hipStream_t stream) {
  const float* x    = (const float*)d_in[0];
  const float* wk1  = (const float*)d_in[3];
  const float* bk1  = (const float*)d_in[4];
  const float* wk2  = (const float*)d_in[5];
  const float* bk2  = (const float*)d_in[6];
  const float* wq1  = (const float*)d_in[7];
  const float* bq1  = (const float*)d_in[8];
  const float* wq2  = (const float*)d_in[9];
  const float* bq2  = (const float*)d_in[10];
  const float* wv   = (const float*)d_in[11];
  const float* bv   = (const float*)d_in[12];
  const float* wr   = (const float*)d_in[13];
  const float* br   = (const float*)d_in[14];
  const float* g1   = (const float*)d_in[15];
  const float* b1   = (const float*)d_in[16];
  const float* g2   = (const float*)d_in[17];
  const float* b2   = (const float*)d_in[18];
  const float* wfc1 = (const float*)d_in[19];
  const float* bfc1 = (const float*)d_in[20];
  const float* wdw  = (const float*)d_in[21];
  const float* bdw  = (const float*)d_in[22];
  const float* wfc2 = (const float*)d_in[23];
  const float* bfc2 = (const float*)d_in[24];

  const size_t big = (size_t)B_ * C_ * N_;
  const long  CN  = (long)C_ * N_;
  const long  NC2 = (long)N_ * C_;
  const long  NH  = (long)N_ * HID_;
  const int   MC  = KC_ * C_;

  uint8_t* w8 = (uint8_t*)d_ws;
  size_t off = 0;
  ushort_t* xnt  = (ushort_t*)(w8 + off); off += 67108864;
  ushort_t* kq   = (ushort_t*)(w8 + off); off += 67108864;
  ushort_t* Mbuf = (ushort_t*)(w8 + off); off += (size_t)B_ * C_ * 512 * 2;
  ushort_t* wkkp = (ushort_t*)(w8 + off); off += 6 * MC * 2;
  ushort_t* wvp  = (ushort_t*)(w8 + off); off += MC * 2;       // contiguous after wkkp
  ushort_t* wqqp = (ushort_t*)(w8 + off); off += 6 * MC * 2;
  ushort_t* wfc1p= (ushort_t*)(w8 + off); off += HID_ * C_ * 2;
  ushort_t* wfc2p= (ushort_t*)(w8 + off); off += C_ * HID_ * 2;
  float* wdwT    = (float*)(w8 + off);    off += 9 * HID_ * 4;
  float* bKV     = (float*)(w8 + off);    off += 768 * 4;
  float* bQ      = (float*)(w8 + off);    off += 512 * 4;
  ushort_t* wrp  = (ushort_t*)(w8 + off); off += C_ * 512 * 2;
  ushort_t* ctx0b= (ushort_t*)(w8 + off); off += (size_t)B_ * KC_ * VC_ * 2;
  ushort_t* ctx1b= (ushort_t*)(w8 + off); off += (size_t)B_ * KC_ * VC_ * 2;  // contiguous
  float2* qstats = (float2*)(w8 + off);   off += (size_t)2 * B_ * N_ * 8;
  float2* pstats = (float2*)(w8 + off);   off += (size_t)2 * B_ * N_ * 2 * 8;
  ushort_t* zbuf = (ushort_t*)(w8 + off); off += 2048;
  const size_t ctxpartBytes = (size_t)128 * KC_ * VC_ * 4;     // 33.55 MB
  const size_t txcopyBytes  = (size_t)2 * CN * 2;              // 16.78 MB
  size_t need_pair = off + 67108864 + txcopyBytes;
  size_t need_np   = off + ctxpartBytes;
  bool pairFFN;
  ushort_t* actX = nullptr;
  float* ctxpart;
  ushort_t* txcopy;
  if (ws_size >= need_pair) {
    pairFFN = true;
    actX = (ushort_t*)(w8 + off);
    ctxpart = (float*)(w8 + off);                     // aliases actX (disjoint in time)
    txcopy = (ushort_t*)(w8 + off + 67108864);
  } else if (ws_size >= need_np) {
    pairFFN = false;
    ctxpart = (float*)(w8 + off);
    txcopy = (ushort_t*)(w8 + off);                   // aliases ctxpart (disjoint in time)
  } else return;
  const float* fzero = (const float*)zbuf;

  float* mx_out   = (float*)d_out;
  float* ctx_out  = mx_out + big;
  float* amap_out = ctx_out + (size_t)B_ * KC_ * VC_;

  ushort_t* mxlo = (ushort_t*)d_out;            // val -> q1
  ushort_t* mxhi = (ushort_t*)d_out + big;      // K1 -> tx

  ushort_t* txn  = xnt;

  dim3 blk(256);

  pack_all<<<3881, blk, 0, stream>>>(wk1, wk2, wq1, wq2, wv, wfc1, wfc2, wdw,
                                     bk1, bk2, bq1, bq2, bv, wr,
                                     zbuf, bKV, bQ, wdwT,
                                     wvp, wfc1p, wfc2p, wrp, wkkp, wqqp);

  // LN1 fused
  ln1t_kernel<<<dim3(N_ / 64, 1, B_), blk, 0, stream>>>(x, g1, b1, xnt);

  // fused KKV: K0 -> kq, K1 -> mxhi, val -> mxlo
  mfma_gemm<3, 4, 1, 1, false, false, false, false><<<dim3(N_ / 128, 6, B_), blk, 0, stream>>>(
      wkkp, nullptr, 0, C_, (long)MC, (long)3 * MC, xnt, nullptr, NC2, C_,
      bKV, nullptr, nullptr, 0,
      nullptr, kq, mxhi, mxlo, (long)KC_ * N_, N_, C_ / 64, zbuf, nullptr, nullptr, 0);

  softmax_spatial2<<<2 * B_ * KC_, blk, 0, stream>>>(kq, mxhi);
  amap2_kernel<<<B_ * N_ / 512, blk, 0, stream>>>(kq, mxhi, amap_out);

  // merged ctx (both dirs, split-8): z in [0,64) dir0 (A=kq), [64,128) dir1 (A=mxhi)
  mfma_gemm<1, 0, 6, 8, false, false, true, false><<<dim3(VC_ / 128, KC_ / 128, 128), blk, 0, stream>>>(
      kq, mxhi, (long)KC_ * N_, N_, 0, 0, mxlo, mxlo, (long)VC_ * N_, N_,
      nullptr, nullptr, nullptr, 0,
      ctxpart, nullptr, nullptr, nullptr, (long)KC_ * VC_, VC_, (N_ / 8) / 64, zbuf,
      nullptr, nullptr, 64);
  ctx_reduce2<<<2 * B_ * KC_ * VC_ / 256, blk, 0, stream>>>(ctxpart, ctx_out, ctx0b, ctx1b);

  // fused QQ: q0 -> kq [n][kc], q1 -> mxlo; epilogue emits partial channel-softmax stats
  mfma_gemm<3, 3, 2, 1, false, false, false, true><<<dim3(N_ / 128, 4, B_), blk, 0, stream>>>(
      wqqp, nullptr, 0, C_, (long)MC, (long)3 * MC, xnt, nullptr, NC2, C_,
      bQ, nullptr, nullptr, 0,
      nullptr, kq, mxlo, nullptr, (long)N_ * KC_, KC_, C_ / 64, zbuf, nullptr, pstats, 0);

  pcomb_kernel<<<2 * B_ * N_ / 256, blk, 0, stream>>>(pstats, qstats);

  // merged Mcat: A=ctx (dir-switched), B=wr half (dir-switched), out [c][dir*256+kc]
  mfma_gemm<1, 0, 2, 1, false, false, true, false><<<dim3(C_ / 128, KC_ / 128, 16), blk, 0, stream>>>(
      ctx0b, ctx1b, (long)KC_ * VC_, VC_, 0, 0, wrp, wrp + 256, 0, 512,
      fzero, nullptr, nullptr, 0,
      nullptr, Mbuf, Mbuf + 256, nullptr, (long)C_ * 512, 512, VC_ / 64, zbuf,
      nullptr, nullptr, 8);

  // fused attention (softmax-in-loader) -> tx bf16 @ mxhi
  mfma_gemm<1, 0, 7, 1, true, true, false, false><<<dim3(N_ / 128, C_ / 128, B_), blk, 0, stream>>>(
      Mbuf, nullptr, (long)C_ * 512, 512, 0, 0, kq, mxlo, (long)N_ * KC_, KC_,
      br, x, nullptr, CN,
      nullptr, mxhi, nullptr, nullptr, CN, N_, 8, zbuf, qstats, nullptr, 0);

  // LN2 fused: tx -> txn
  ln2t_kernel<<<dim3(N_ / 64, 1, B_), blk, 0, stream>>>(mxhi, g2, b2, txn);

  if (pairFFN) {
    // copy tx b6,b7 (fc2 pair-3 writes clobber them)
    hipMemcpyAsync(txcopy, mxhi + (size_t)6 * CN, (size_t)2 * CN * 2,
                   hipMemcpyDeviceToDevice, stream);
    ushort_t* h1t2 = kq;           // 2 batches [N][HID]
    for (int g = 0; g < 4; ++g) {
      mfma_gemm<1, 0, 2, 1, false, false, false, false><<<dim3(N_ / 128, HID_ / 128, 2), blk, 0, stream>>>(
          wfc1p, nullptr, 0, C_, 0, 0, txn + (size_t)g * 2 * NC2, nullptr, NC2, C_,
          bfc1, nullptr, nullptr, 0,
          nullptr, h1t2, nullptr, nullptr, NH, HID_, C_ / 64, zbuf, nullptr, nullptr, 0);
      dwgelu_t<<<dim3(N_ / 2, 2), blk, 0, stream>>>(h1t2, wdwT, bdw, actX);
      const ushort_t* txb = (g == 3) ? (const ushort_t*)txcopy : (mxhi + (size_t)g * 2 * CN);
      mfma_gemm<1, 0, 8, 1, false, false, false, false><<<dim3(N_ / 128, C_ / 128, 2), blk, 0, stream>>>(
          wfc2p, nullptr, 0, HID_, 0, 0, actX, nullptr, NH, HID_,
          bfc2, nullptr, txb, CN,
          mx_out + (size_t)g * 2 * CN, nullptr, nullptr, nullptr, CN, N_, HID_ / 64, zbuf,
          nullptr, nullptr, 0);
    }
  } else {
    ushort_t* h1t  = kq;
    ushort_t* actT = kq + NH;
    hipMemcpyAsync(txcopy, mxhi + (size_t)7 * CN, (size_t)CN * 2,
                   hipMemcpyDeviceToDevice, stream);
    for (int b = 0; b < B_; ++b) {
      mfma_gemm<1, 0, 2, 1, false, false, false, false><<<dim3(N_ / 128, HID_ / 128, 1), blk, 0, stream>>>(
          wfc1p, nullptr, 0, C_, 0, 0, txn + (size_t)b * NC2, nullptr, 0, C_,
          bfc1, nullptr, nullptr, 0,
          nullptr, h1t, nullptr, nullptr, 0, HID_, C_ / 64, zbuf, nullptr, nullptr, 0);
      dwgelu_t<<<dim3(N_ / 2, 1), blk, 0, stream>>>(h1t, wdwT, bdw, actT);
      const ushort_t* txb = (b == 7) ? (const ushort_t*)txcopy : (mxhi + (size_t)b * CN);
      mfma_gemm<1, 0, 8, 1, false, false, false, false><<<dim3(N_ / 128, C_ / 128, 1), blk, 0, stream>>>(
          wfc2p, nullptr, 0, HID_, 0, 0, actT, nullptr, 0, HID_,
          bfc2, nullptr, txb, 0,
          mx_out + (size_t)b * CN, nullptr, nullptr, nullptr, 0, N_, HID_ / 64, zbuf,
          nullptr, nullptr, 0);
    }
  }
}